// Round 1
// baseline (1295.914 us; speedup 1.0000x reference)
//
#include <hip/hip_runtime.h>

#define NPIX 4096
#define CDIM 128
#define BATCH 8
#define EPSN 1e-5f

__device__ __forceinline__ float sigmoidf_(float x) { return 1.f / (1.f + __expf(-x)); }

// ---------------- per-(b,c) mean over HW ----------------
__global__ __launch_bounds__(256) void mean_bc_kernel(const float* __restrict__ x,
                                                      float* __restrict__ mean) {
    __shared__ float sb[4];
    int bc = blockIdx.x;
    const float* p = x + (size_t)bc * NPIX;
    float s = 0.f;
    for (int i = threadIdx.x; i < NPIX; i += 256) s += p[i];
#pragma unroll
    for (int off = 32; off > 0; off >>= 1) s += __shfl_down(s, off, 64);
    if ((threadIdx.x & 63) == 0) sb[threadIdx.x >> 6] = s;
    __syncthreads();
    if (threadIdx.x == 0) mean[bc] = (sb[0] + sb[1] + sb[2] + sb[3]) * (1.f / (float)NPIX);
}

// ---------------- ECA gate: conv1d(k=5,pad=2) over channel dim + sigmoid ----------------
__global__ void eca_gate_kernel(const float* __restrict__ mean, const float* __restrict__ w5,
                                float* __restrict__ gate) {
    int b = blockIdx.x, c = threadIdx.x;
    float s = 0.f;
#pragma unroll
    for (int k = 0; k < 5; ++k) {
        int cc = c + k - 2;
        if (cc >= 0 && cc < CDIM) s += w5[k] * mean[b * CDIM + cc];
    }
    gate[b * CDIM + c] = sigmoidf_(s);
}

// ---------------- ESA + ECA combine: out = x * (gate[b,c] + sig(max)*a + sig(min)*(1-a)) ----------------
__global__ __launch_bounds__(256) void esa_kernel(const float* __restrict__ x,
                                                  const float* __restrict__ mean,
                                                  const float* __restrict__ gate,
                                                  const float* __restrict__ alpha_p,
                                                  float* __restrict__ out) {
    int b = blockIdx.y;
    int p = blockIdx.x * 256 + threadIdx.x;
    const float* xb = x + (size_t)b * CDIM * NPIX;
    const float* mb = mean + b * CDIM;
    float mx = -1e30f, mn = 1e30f;
    for (int c = 0; c < CDIM; ++c) {
        float v = xb[(size_t)c * NPIX + p] - mb[c];
        mx = fmaxf(mx, v);
        mn = fminf(mn, v);
    }
    float a = alpha_p[0];
    float s = sigmoidf_(mx) * a + sigmoidf_(mn) * (1.f - a);
    float* ob = out + (size_t)b * CDIM * NPIX;
    const float* gb = gate + b * CDIM;
    for (int c = 0; c < CDIM; ++c) {
        size_t i = (size_t)c * NPIX + p;
        ob[i] = xb[i] * (gb[c] + s);
    }
}

// ---------------- depthwise 3x3 conv (+bias), generic ----------------
// mode 0: out = conv ; mode 1: out = in + conv ; mode 2: out += conv
// input channel index = cmul*c + coff, input batch stride in_bstride
__global__ __launch_bounds__(256) void dwconv3_kernel(const float* __restrict__ in,
                                                      const float* __restrict__ wc,
                                                      const float* __restrict__ bias,
                                                      float* __restrict__ out,
                                                      int cmul, int coff, int in_bstride,
                                                      int mode, int relu) {
    int c = blockIdx.y, b = blockIdx.z;
    int tx = threadIdx.x;
    int wd = tx & 63;
    int h = blockIdx.x * 4 + (tx >> 6);
    const float* inp = in + (size_t)b * in_bstride + (size_t)(cmul * c + coff) * NPIX;
    float wr[9];
#pragma unroll
    for (int k = 0; k < 9; ++k) wr[k] = wc[c * 9 + k];
    float acc = bias[c];
#pragma unroll
    for (int dy = -1; dy <= 1; ++dy) {
        int hh = h + dy;
        if (hh < 0 || hh >= 64) continue;
#pragma unroll
        for (int dx = -1; dx <= 1; ++dx) {
            int ww = wd + dx;
            if (ww < 0 || ww >= 64) continue;
            acc += wr[(dy + 1) * 3 + (dx + 1)] * inp[hh * 64 + ww];
        }
    }
    float v = acc;
    if (mode == 1) v += inp[h * 64 + wd];
    if (relu) v = fmaxf(v, 0.f);
    size_t oidx = ((size_t)b * CDIM + c) * NPIX + h * 64 + wd;
    if (mode == 2) out[oidx] += v;
    else out[oidx] = v;
}

// ---------------- GroupNorm(1 group) stats: sum & sumsq per b via atomics ----------------
__global__ __launch_bounds__(256) void gn_stats_kernel(const float* __restrict__ xx,
                                                       float* __restrict__ stats) {
    __shared__ float sb[8];
    int b = blockIdx.y;
    const float* p = xx + (size_t)b * (CDIM * NPIX) + (size_t)blockIdx.x * 16384;
    float s = 0.f, s2 = 0.f;
    for (int i = threadIdx.x; i < 16384; i += 256) {
        float v = p[i];
        s += v; s2 += v * v;
    }
#pragma unroll
    for (int off = 32; off > 0; off >>= 1) {
        s += __shfl_down(s, off, 64);
        s2 += __shfl_down(s2, off, 64);
    }
    int wv = threadIdx.x >> 6;
    if ((threadIdx.x & 63) == 0) { sb[wv] = s; sb[4 + wv] = s2; }
    __syncthreads();
    if (threadIdx.x == 0) {
        atomicAdd(&stats[b * 2], sb[0] + sb[1] + sb[2] + sb[3]);
        atomicAdd(&stats[b * 2 + 1], sb[4] + sb[5] + sb[6] + sb[7]);
    }
}

__global__ __launch_bounds__(256) void gn_apply_kernel(const float* __restrict__ in,
                                                       const float* __restrict__ stats,
                                                       const float* __restrict__ g,
                                                       const float* __restrict__ bta,
                                                       float* __restrict__ out) {
    int b = blockIdx.y;
    int i = blockIdx.x * 256 + threadIdx.x;  // 0 .. 524287
    int c = i >> 12;
    const float n = 1.f / (float)(CDIM * NPIX);
    float mu = stats[b * 2] * n;
    float var = stats[b * 2 + 1] * n - mu * mu;
    float r = rsqrtf(var + EPSN);
    size_t idx = (size_t)b * (CDIM * NPIX) + i;
    out[idx] = (in[idx] - mu) * r * g[c] + bta[c];
}

// ---------------- conv1x1 (channel GEMM), f32, LDS tiled ----------------
// out[b,o,p] = act(bias[o] + sum_c w[o,c]*in[b,c,p]*(mult?mult:1)) + (res?res[b,o,p]:0)
// grid: (NPIX/64, Cout/32, B), block 256. Cout derived from gridDim.y.
__global__ __launch_bounds__(256) void conv1x1_kernel(const float* __restrict__ in,
                                                      const float* __restrict__ mult,
                                                      const float* __restrict__ w,
                                                      const float* __restrict__ bias,
                                                      const float* __restrict__ res,
                                                      float* __restrict__ out,
                                                      int Cin, int relu) {
    __shared__ float in_s[32][64];
    __shared__ float w_s[32][32];
    int Cout = gridDim.y * 32;
    int b = blockIdx.z;
    int p0 = blockIdx.x * 64;
    int o0 = blockIdx.y * 32;
    int tx = threadIdx.x;
    int pl = tx & 63;
    int og = tx >> 6;  // 0..3
    const float* inb = in + (size_t)b * Cin * NPIX;
    const float* multb = mult ? mult + (size_t)b * Cin * NPIX : nullptr;
    float acc[8];
#pragma unroll
    for (int k = 0; k < 8; ++k) acc[k] = bias[o0 + og * 8 + k];
    for (int c0 = 0; c0 < Cin; c0 += 32) {
        if (multb) {
#pragma unroll
            for (int j = 0; j < 8; ++j) {
                int i = tx + j * 256;
                int cc = i >> 6, pp = i & 63;
                size_t gi = (size_t)(c0 + cc) * NPIX + p0 + pp;
                in_s[cc][pp] = inb[gi] * multb[gi];
            }
        } else {
#pragma unroll
            for (int j = 0; j < 8; ++j) {
                int i = tx + j * 256;
                int cc = i >> 6, pp = i & 63;
                in_s[cc][pp] = inb[(size_t)(c0 + cc) * NPIX + p0 + pp];
            }
        }
#pragma unroll
        for (int j = 0; j < 4; ++j) {
            int i = tx + j * 256;
            int oo = i >> 5, cc = i & 31;
            w_s[oo][cc] = w[(size_t)(o0 + oo) * Cin + c0 + cc];
        }
        __syncthreads();
#pragma unroll
        for (int cc = 0; cc < 32; ++cc) {
            float iv = in_s[cc][pl];
#pragma unroll
            for (int k = 0; k < 8; ++k) acc[k] += w_s[og * 8 + k][cc] * iv;
        }
        __syncthreads();
    }
    float* outb = out + (size_t)b * Cout * NPIX;
    const float* resb = res ? res + (size_t)b * Cout * NPIX : nullptr;
#pragma unroll
    for (int k = 0; k < 8; ++k) {
        int o = o0 + og * 8 + k;
        float v = acc[k];
        if (relu) v = fmaxf(v, 0.f);
        if (resb) v += resb[(size_t)o * NPIX + p0 + pl];
        outb[(size_t)o * NPIX + p0 + pl] = v;
    }
}

// ---------------- window attention ----------------
// t: (B, 640, 4096); q channel = 5c+qoff, k = 5c+koff, v = 5c+2, c = head*16+d
// mode 0: windows 64x4 (wi over width), token l: h=l/4, wl=l%4, p=h*64+wi*4+wl
// mode 1: windows 4x64 (wi over height), token l: hl=l/64, w=l%64, p=(wi*4+hl)*64+w
// One wave per (window, head); thread handles rows tx, tx+64, tx+128, tx+192.
// Single-pass softmax without max subtraction (logits are tiny for this module).
__global__ __launch_bounds__(64) void attn_kernel(const float* __restrict__ t,
                                                  int qoff, int koff, int mode,
                                                  float* __restrict__ out, int accumulate) {
    __shared__ __align__(16) float k_s[256][20];
    __shared__ __align__(16) float v_s[256][20];
    int wi = blockIdx.x, head = blockIdx.y, b = blockIdx.z;
    int tx = threadIdx.x;
    const float* tb = t + (size_t)b * 640 * NPIX;
    float q[4][16];
    int pix[4];
#pragma unroll
    for (int r = 0; r < 4; ++r) {
        int i = tx + 64 * r;
        int p_i = (mode == 0) ? ((i >> 2) * 64 + wi * 4 + (i & 3))
                              : ((wi * 4 + (i >> 6)) * 64 + (i & 63));
        pix[r] = p_i;
#pragma unroll
        for (int d = 0; d < 16; ++d) {
            int c = head * 16 + d;
            q[r][d] = tb[(size_t)(5 * c + qoff) * NPIX + p_i];
            k_s[i][d] = tb[(size_t)(5 * c + koff) * NPIX + p_i];
            v_s[i][d] = tb[(size_t)(5 * c + 2) * NPIX + p_i];
        }
    }
    __syncthreads();
    float l[4] = {0.f, 0.f, 0.f, 0.f};
    float o[4][16];
#pragma unroll
    for (int r = 0; r < 4; ++r)
#pragma unroll
        for (int d = 0; d < 16; ++d) o[r][d] = 0.f;

    for (int j = 0; j < 256; ++j) {
        float4 ka = *(const float4*)&k_s[j][0];
        float4 kb = *(const float4*)&k_s[j][4];
        float4 kc = *(const float4*)&k_s[j][8];
        float4 kd = *(const float4*)&k_s[j][12];
        float4 va = *(const float4*)&v_s[j][0];
        float4 vb = *(const float4*)&v_s[j][4];
        float4 vc = *(const float4*)&v_s[j][8];
        float4 vd = *(const float4*)&v_s[j][12];
#pragma unroll
        for (int r = 0; r < 4; ++r) {
            float s = q[r][0] * ka.x + q[r][1] * ka.y + q[r][2] * ka.z + q[r][3] * ka.w
                    + q[r][4] * kb.x + q[r][5] * kb.y + q[r][6] * kb.z + q[r][7] * kb.w
                    + q[r][8] * kc.x + q[r][9] * kc.y + q[r][10] * kc.z + q[r][11] * kc.w
                    + q[r][12] * kd.x + q[r][13] * kd.y + q[r][14] * kd.z + q[r][15] * kd.w;
            float e = __expf(s);
            l[r] += e;
            o[r][0] += e * va.x;  o[r][1] += e * va.y;  o[r][2] += e * va.z;  o[r][3] += e * va.w;
            o[r][4] += e * vb.x;  o[r][5] += e * vb.y;  o[r][6] += e * vb.z;  o[r][7] += e * vb.w;
            o[r][8] += e * vc.x;  o[r][9] += e * vc.y;  o[r][10] += e * vc.z; o[r][11] += e * vc.w;
            o[r][12] += e * vd.x; o[r][13] += e * vd.y; o[r][14] += e * vd.z; o[r][15] += e * vd.w;
        }
    }
    float* ob = out + (size_t)b * CDIM * NPIX;
#pragma unroll
    for (int r = 0; r < 4; ++r) {
        float rl = 1.f / l[r];
#pragma unroll
        for (int d = 0; d < 16; ++d) {
            size_t idx = (size_t)(head * 16 + d) * NPIX + pix[r];
            float val = o[r][d] * rl;
            if (accumulate) ob[idx] += val;
            else ob[idx] = val;
        }
    }
}

extern "C" void kernel_launch(void* const* d_in, const int* in_sizes, int n_in,
                              void* d_out, int out_size, void* d_ws, size_t ws_size,
                              hipStream_t stream) {
    const float* x       = (const float*)d_in[0];
    const float* eca_w   = (const float*)d_in[1];
    const float* esa_al  = (const float*)d_in[2];
    const float* cpe1_w  = (const float*)d_in[3];  const float* cpe1_b = (const float*)d_in[4];
    const float* g1      = (const float*)d_in[5];  const float* b1     = (const float*)d_in[6];
    const float* actp_w  = (const float*)d_in[7];  const float* actp_b = (const float*)d_in[8];
    const float* inp_w   = (const float*)d_in[9];  const float* inp_b  = (const float*)d_in[10];
    const float* dwc_w   = (const float*)d_in[11]; const float* dwc_b  = (const float*)d_in[12];
    const float* qkv_w   = (const float*)d_in[13]; const float* qkv_b  = (const float*)d_in[14];
    const float* eaax_w  = (const float*)d_in[15]; const float* eaax_b = (const float*)d_in[16];
    const float* eaay_w  = (const float*)d_in[17]; const float* eaay_b = (const float*)d_in[18];
    const float* outp_w  = (const float*)d_in[19]; const float* outp_b = (const float*)d_in[20];
    const float* cpe2_w  = (const float*)d_in[21]; const float* cpe2_b = (const float*)d_in[22];
    const float* g2      = (const float*)d_in[23]; const float* b2     = (const float*)d_in[24];
    const float* mlp1_w  = (const float*)d_in[25]; const float* mlp1_b = (const float*)d_in[26];
    const float* mlp2_w  = (const float*)d_in[27]; const float* mlp2_b = (const float*)d_in[28];

    float* ws = (float*)d_ws;
    const size_t E = (size_t)BATCH * CDIM * NPIX;  // 4,194,304
    float* buf0 = ws;
    float* buf1 = ws + E;
    float* buf2 = ws + 2 * E;
    float* buf3 = ws + 3 * E;
    float* buf4 = ws + 4 * E;
    float* buf5 = ws + 5 * E;  // 5E for qkv / 4E for mlp hidden
    float* meanb = ws + 10 * E;       // 1024
    float* gateb = meanb + 1024;      // 1024
    float* gstats = gateb + 1024;     // 32 (gn1: [0,16), gn2: [16,32))

    hipMemsetAsync(gstats, 0, 32 * sizeof(float), stream);

    // 1) ECA + ESA fused
    mean_bc_kernel<<<BATCH * CDIM, 256, 0, stream>>>(x, meanb);
    eca_gate_kernel<<<BATCH, CDIM, 0, stream>>>(meanb, eca_w, gateb);
    esa_kernel<<<dim3(16, BATCH), 256, 0, stream>>>(x, meanb, gateb, esa_al, buf0);
    // 2) x += cpe1 dwconv  -> shortcut (buf1)
    dwconv3_kernel<<<dim3(16, CDIM, BATCH), 256, 0, stream>>>(buf0, cpe1_w, cpe1_b, buf1,
                                                              1, 0, CDIM * NPIX, 1, 0);
    // 3) GroupNorm1 -> buf0 (xn)
    gn_stats_kernel<<<dim3(32, BATCH), 256, 0, stream>>>(buf1, gstats);
    gn_apply_kernel<<<dim3(2048, BATCH), 256, 0, stream>>>(buf1, gstats, g1, b1, buf0);
    // 4) act_res = relu(actp(xn)) -> buf2
    conv1x1_kernel<<<dim3(64, 4, BATCH), 256, 0, stream>>>(buf0, nullptr, actp_w, actp_b,
                                                           nullptr, buf2, CDIM, 1);
    // 5) t = relu(dwc(inp(xn)))  buf0->buf3->buf4
    conv1x1_kernel<<<dim3(64, 4, BATCH), 256, 0, stream>>>(buf0, nullptr, inp_w, inp_b,
                                                           nullptr, buf3, CDIM, 0);
    dwconv3_kernel<<<dim3(16, CDIM, BATCH), 256, 0, stream>>>(buf3, dwc_w, dwc_b, buf4,
                                                              1, 0, CDIM * NPIX, 0, 1);
    // 6) qkv conv (Cout=640) -> buf5
    conv1x1_kernel<<<dim3(64, 20, BATCH), 256, 0, stream>>>(buf4, nullptr, qkv_w, qkv_b,
                                                            nullptr, buf5, CDIM, 0);
    // 7) a = eaa(q0,k0,v0, 64x4) + eaa(q1,k1,v0, 4x64)  -> buf0
    attn_kernel<<<dim3(16, 8, BATCH), 64, 0, stream>>>(buf5, 0, 1, 0, buf0, 0);
    dwconv3_kernel<<<dim3(16, CDIM, BATCH), 256, 0, stream>>>(buf5, eaax_w, eaax_b, buf0,
                                                              5, 2, 640 * NPIX, 2, 0);
    attn_kernel<<<dim3(16, 8, BATCH), 64, 0, stream>>>(buf5, 3, 4, 1, buf0, 1);
    dwconv3_kernel<<<dim3(16, CDIM, BATCH), 256, 0, stream>>>(buf5, eaay_w, eaay_b, buf0,
                                                              5, 2, 640 * NPIX, 2, 0);
    // 8) out = outp(a * act_res) + shortcut -> buf3
    conv1x1_kernel<<<dim3(64, 4, BATCH), 256, 0, stream>>>(buf0, buf2, outp_w, outp_b,
                                                           buf1, buf3, CDIM, 0);
    // 9) out += cpe2 dwconv -> buf4 (out2)
    dwconv3_kernel<<<dim3(16, CDIM, BATCH), 256, 0, stream>>>(buf3, cpe2_w, cpe2_b, buf4,
                                                              1, 0, CDIM * NPIX, 1, 0);
    // 10) GroupNorm2 -> buf0
    gn_stats_kernel<<<dim3(32, BATCH), 256, 0, stream>>>(buf4, gstats + 16);
    gn_apply_kernel<<<dim3(2048, BATCH), 256, 0, stream>>>(buf4, gstats + 16, g2, b2, buf0);
    // 11) mlp: relu(mlp1(gn2)) -> buf5 ; mlp2(...) + out2 -> d_out
    conv1x1_kernel<<<dim3(64, 16, BATCH), 256, 0, stream>>>(buf0, nullptr, mlp1_w, mlp1_b,
                                                            nullptr, buf5, CDIM, 1);
    conv1x1_kernel<<<dim3(64, 4, BATCH), 256, 0, stream>>>(buf5, nullptr, mlp2_w, mlp2_b,
                                                           buf4, (float*)d_out, 4 * CDIM, 0);
}

// Round 2
// 713.207 us; speedup vs baseline: 1.8170x; 1.8170x over previous
//
#include <hip/hip_runtime.h>

#define NPIX 4096
#define CDIM 128
#define BATCH 8
#define EPSN 1e-5f

typedef __attribute__((ext_vector_type(8))) short short8;
typedef __attribute__((ext_vector_type(4))) float f32x4;

__device__ __forceinline__ float sigmoidf_(float x) { return 1.f / (1.f + __expf(-x)); }

__device__ __forceinline__ unsigned short f2b(float f) {
    unsigned int u = __float_as_uint(f);
    unsigned int r = (u + 0x7FFF + ((u >> 16) & 1)) >> 16;  // RNE
    return (unsigned short)r;
}

// ---------------- weight f32 -> bf16 conversion (all weights, one kernel) ----------------
__global__ __launch_bounds__(256) void convert_w_kernel(const float* __restrict__ qkv_w,
                                                        const float* __restrict__ mlp1_w,
                                                        const float* __restrict__ mlp2_w,
                                                        const float* __restrict__ actp_w,
                                                        const float* __restrict__ inp_w,
                                                        const float* __restrict__ outp_w,
                                                        unsigned short* __restrict__ dst) {
    int i = blockIdx.x * 256 + threadIdx.x;  // 0..262143
    const float* s; int off;
    if (i < 81920)       { s = qkv_w;  off = i; }
    else if (i < 147456) { s = mlp1_w; off = i - 81920; }
    else if (i < 212992) { s = mlp2_w; off = i - 147456; }
    else if (i < 229376) { s = actp_w; off = i - 212992; }
    else if (i < 245760) { s = inp_w;  off = i - 229376; }
    else                 { s = outp_w; off = i - 245760; }
    dst[i] = f2b(s[off]);
}

// ---------------- per-(b,c) mean over HW ----------------
__global__ __launch_bounds__(256) void mean_bc_kernel(const float* __restrict__ x,
                                                      float* __restrict__ mean) {
    __shared__ float sb[4];
    int bc = blockIdx.x;
    const float* p = x + (size_t)bc * NPIX;
    float s = 0.f;
    for (int i = threadIdx.x; i < NPIX; i += 256) s += p[i];
#pragma unroll
    for (int off = 32; off > 0; off >>= 1) s += __shfl_down(s, off, 64);
    if ((threadIdx.x & 63) == 0) sb[threadIdx.x >> 6] = s;
    __syncthreads();
    if (threadIdx.x == 0) mean[bc] = (sb[0] + sb[1] + sb[2] + sb[3]) * (1.f / (float)NPIX);
}

// ---------------- ECA gate ----------------
__global__ void eca_gate_kernel(const float* __restrict__ mean, const float* __restrict__ w5,
                                float* __restrict__ gate) {
    int b = blockIdx.x, c = threadIdx.x;
    float s = 0.f;
#pragma unroll
    for (int k = 0; k < 5; ++k) {
        int cc = c + k - 2;
        if (cc >= 0 && cc < CDIM) s += w5[k] * mean[b * CDIM + cc];
    }
    gate[b * CDIM + c] = sigmoidf_(s);
}

// ---------------- ESA + ECA combine ----------------
__global__ __launch_bounds__(256) void esa_kernel(const float* __restrict__ x,
                                                  const float* __restrict__ mean,
                                                  const float* __restrict__ gate,
                                                  const float* __restrict__ alpha_p,
                                                  float* __restrict__ out) {
    int b = blockIdx.y;
    int p = blockIdx.x * 256 + threadIdx.x;
    const float* xb = x + (size_t)b * CDIM * NPIX;
    const float* mb = mean + b * CDIM;
    float mx = -1e30f, mn = 1e30f;
    for (int c = 0; c < CDIM; ++c) {
        float v = xb[(size_t)c * NPIX + p] - mb[c];
        mx = fmaxf(mx, v);
        mn = fminf(mn, v);
    }
    float a = alpha_p[0];
    float s = sigmoidf_(mx) * a + sigmoidf_(mn) * (1.f - a);
    float* ob = out + (size_t)b * CDIM * NPIX;
    const float* gb = gate + b * CDIM;
    for (int c = 0; c < CDIM; ++c) {
        size_t i = (size_t)c * NPIX + p;
        ob[i] = xb[i] * (gb[c] + s);
    }
}

// ---------------- depthwise 3x3 conv ----------------
// mode 0: out = conv ; mode 1: out = in + conv ; mode 2: out += conv
__global__ __launch_bounds__(256) void dwconv3_kernel(const float* __restrict__ in,
                                                      const float* __restrict__ wc,
                                                      const float* __restrict__ bias,
                                                      float* __restrict__ out,
                                                      int cmul, int coff, int in_bstride,
                                                      int mode, int relu) {
    int c = blockIdx.y, b = blockIdx.z;
    int tx = threadIdx.x;
    int wd = tx & 63;
    int h = blockIdx.x * 4 + (tx >> 6);
    const float* inp = in + (size_t)b * in_bstride + (size_t)(cmul * c + coff) * NPIX;
    float wr[9];
#pragma unroll
    for (int k = 0; k < 9; ++k) wr[k] = wc[c * 9 + k];
    float acc = bias[c];
#pragma unroll
    for (int dy = -1; dy <= 1; ++dy) {
        int hh = h + dy;
        if (hh < 0 || hh >= 64) continue;
#pragma unroll
        for (int dx = -1; dx <= 1; ++dx) {
            int ww = wd + dx;
            if (ww < 0 || ww >= 64) continue;
            acc += wr[(dy + 1) * 3 + (dx + 1)] * inp[hh * 64 + ww];
        }
    }
    float v = acc;
    if (mode == 1) v += inp[h * 64 + wd];
    if (relu) v = fmaxf(v, 0.f);
    size_t oidx = ((size_t)b * CDIM + c) * NPIX + h * 64 + wd;
    if (mode == 2) out[oidx] += v;
    else out[oidx] = v;
}

// ---------------- GroupNorm(1 group) stats ----------------
__global__ __launch_bounds__(256) void gn_stats_kernel(const float* __restrict__ xx,
                                                       float* __restrict__ stats) {
    __shared__ float sb[8];
    int b = blockIdx.y;
    const float* p = xx + (size_t)b * (CDIM * NPIX) + (size_t)blockIdx.x * 16384;
    float s = 0.f, s2 = 0.f;
    for (int i = threadIdx.x; i < 16384; i += 256) {
        float v = p[i];
        s += v; s2 += v * v;
    }
#pragma unroll
    for (int off = 32; off > 0; off >>= 1) {
        s += __shfl_down(s, off, 64);
        s2 += __shfl_down(s2, off, 64);
    }
    int wv = threadIdx.x >> 6;
    if ((threadIdx.x & 63) == 0) { sb[wv] = s; sb[4 + wv] = s2; }
    __syncthreads();
    if (threadIdx.x == 0) {
        atomicAdd(&stats[b * 2], sb[0] + sb[1] + sb[2] + sb[3]);
        atomicAdd(&stats[b * 2 + 1], sb[4] + sb[5] + sb[6] + sb[7]);
    }
}

// ---------------- NCHW f32 -> NHWC bf16 (optionally fused multiply or groupnorm) ----------------
// mode 0: dst = bf16(src); mode 1: dst = bf16(src*src2); mode 2: dst = bf16(gn(src))
__global__ __launch_bounds__(256) void to_nhwc_kernel(const float* __restrict__ src,
                                                      const float* __restrict__ src2,
                                                      const float* __restrict__ stats,
                                                      const float* __restrict__ g,
                                                      const float* __restrict__ bta,
                                                      unsigned short* __restrict__ dst,
                                                      int mode) {
    __shared__ unsigned short tile[64][130];
    int b = blockIdx.y, p0 = blockIdx.x * 64;
    int tx = threadIdx.x, pl = tx & 63, cg = tx >> 6;
    float mu = 0.f, r = 1.f;
    if (mode == 2) {
        const float n = 1.f / (float)(CDIM * NPIX);
        mu = stats[b * 2] * n;
        float var = stats[b * 2 + 1] * n - mu * mu;
        r = rsqrtf(var + EPSN);
    }
    const float* sb = src + (size_t)b * CDIM * NPIX;
    const float* s2b = (mode == 1) ? src2 + (size_t)b * CDIM * NPIX : nullptr;
    for (int c = cg; c < CDIM; c += 4) {
        size_t gi = (size_t)c * NPIX + p0 + pl;
        float v = sb[gi];
        if (mode == 1) v *= s2b[gi];
        if (mode == 2) v = (v - mu) * r * g[c] + bta[c];
        tile[pl][c] = f2b(v);
    }
    __syncthreads();
    int c2 = tx & 127, pr = tx >> 7;
    unsigned short* db = dst + ((size_t)b * NPIX + p0) * CDIM;
    for (int p = pr; p < 64; p += 2)
        db[(size_t)p * CDIM + c2] = tile[p][c2];
}

// ---------------- conv1x1 via bf16 MFMA ----------------
// in_t: bf16 NHWC (B*NPIX, Cin); w: bf16 (Cout, Cin); grid (NPIX/128, Cout/128, B), block 256
// out!=null: f32 NCHW write (+res) ; out_t!=null: bf16 NHWC write
__global__ __launch_bounds__(256) void conv_mfma_kernel(const unsigned short* __restrict__ in_t,
                                                        const unsigned short* __restrict__ w,
                                                        const float* __restrict__ bias,
                                                        const float* __restrict__ res,
                                                        float* __restrict__ out,
                                                        unsigned short* __restrict__ out_t,
                                                        int Cin, int Cout, int relu) {
    __shared__ __align__(16) unsigned short A_s[128][136];
    __shared__ __align__(16) unsigned short B_s[128][136];
    int b = blockIdx.z, p0 = blockIdx.x * 128, o0 = blockIdx.y * 128;
    int tx = threadIdx.x;
    int wave = tx >> 6, lane = tx & 63;
    int wm = wave & 1, wn = wave >> 1;
    int quad = lane >> 4, l16 = lane & 15;

    f32x4 acc[4][4];
#pragma unroll
    for (int mt = 0; mt < 4; ++mt) {
#pragma unroll
        for (int r = 0; r < 4; ++r) {
            float bv = bias[o0 + wm * 64 + mt * 16 + quad * 4 + r];
#pragma unroll
            for (int nt = 0; nt < 4; ++nt) acc[mt][nt][r] = bv;
        }
    }

    for (int k0 = 0; k0 < Cin; k0 += 128) {
        // stage A (weights) and B (pixels), 16B chunks
#pragma unroll
        for (int j = 0; j < 8; ++j) {
            int idx = tx + 256 * j;
            int row = idx >> 4, c16 = idx & 15;
            *(uint4*)&A_s[row][c16 * 8] =
                *(const uint4*)&w[(size_t)(o0 + row) * Cin + k0 + c16 * 8];
            *(uint4*)&B_s[row][c16 * 8] =
                *(const uint4*)&in_t[((size_t)b * NPIX + p0 + row) * Cin + k0 + c16 * 8];
        }
        __syncthreads();
#pragma unroll
        for (int ks = 0; ks < 128; ks += 32) {
            short8 af[4], bf[4];
#pragma unroll
            for (int mt = 0; mt < 4; ++mt)
                af[mt] = *(const short8*)&A_s[wm * 64 + mt * 16 + l16][ks + quad * 8];
#pragma unroll
            for (int nt = 0; nt < 4; ++nt)
                bf[nt] = *(const short8*)&B_s[wn * 64 + nt * 16 + l16][ks + quad * 8];
#pragma unroll
            for (int mt = 0; mt < 4; ++mt)
#pragma unroll
                for (int nt = 0; nt < 4; ++nt)
                    acc[mt][nt] = __builtin_amdgcn_mfma_f32_16x16x32_bf16(
                        af[mt], bf[nt], acc[mt][nt], 0, 0, 0);
        }
        __syncthreads();
    }

    if (out_t) {
#pragma unroll
        for (int mt = 0; mt < 4; ++mt) {
#pragma unroll
            for (int nt = 0; nt < 4; ++nt) {
                int p = p0 + wn * 64 + nt * 16 + l16;
                int ob = o0 + wm * 64 + mt * 16 + quad * 4;
                ushort4 u;
                float v0 = acc[mt][nt][0], v1 = acc[mt][nt][1];
                float v2 = acc[mt][nt][2], v3 = acc[mt][nt][3];
                if (relu) { v0 = fmaxf(v0, 0.f); v1 = fmaxf(v1, 0.f);
                            v2 = fmaxf(v2, 0.f); v3 = fmaxf(v3, 0.f); }
                u.x = f2b(v0); u.y = f2b(v1); u.z = f2b(v2); u.w = f2b(v3);
                *(ushort4*)&out_t[((size_t)b * NPIX + p) * Cout + ob] = u;
            }
        }
    } else {
        const float* resb = res ? res + (size_t)b * Cout * NPIX : nullptr;
        float* outb = out + (size_t)b * Cout * NPIX;
#pragma unroll
        for (int mt = 0; mt < 4; ++mt) {
#pragma unroll
            for (int nt = 0; nt < 4; ++nt) {
                int p = p0 + wn * 64 + nt * 16 + l16;
#pragma unroll
                for (int r = 0; r < 4; ++r) {
                    int o = o0 + wm * 64 + mt * 16 + quad * 4 + r;
                    float v = acc[mt][nt][r];
                    if (relu) v = fmaxf(v, 0.f);
                    if (resb) v += resb[(size_t)o * NPIX + p];
                    outb[(size_t)o * NPIX + p] = v;
                }
            }
        }
    }
}

// ---------------- window attention (unchanged, f32) ----------------
__global__ __launch_bounds__(64) void attn_kernel(const float* __restrict__ t,
                                                  int qoff, int koff, int mode,
                                                  float* __restrict__ out, int accumulate) {
    __shared__ __align__(16) float k_s[256][20];
    __shared__ __align__(16) float v_s[256][20];
    int wi = blockIdx.x, head = blockIdx.y, b = blockIdx.z;
    int tx = threadIdx.x;
    const float* tb = t + (size_t)b * 640 * NPIX;
    float q[4][16];
    int pix[4];
#pragma unroll
    for (int r = 0; r < 4; ++r) {
        int i = tx + 64 * r;
        int p_i = (mode == 0) ? ((i >> 2) * 64 + wi * 4 + (i & 3))
                              : ((wi * 4 + (i >> 6)) * 64 + (i & 63));
        pix[r] = p_i;
#pragma unroll
        for (int d = 0; d < 16; ++d) {
            int c = head * 16 + d;
            q[r][d] = tb[(size_t)(5 * c + qoff) * NPIX + p_i];
            k_s[i][d] = tb[(size_t)(5 * c + koff) * NPIX + p_i];
            v_s[i][d] = tb[(size_t)(5 * c + 2) * NPIX + p_i];
        }
    }
    __syncthreads();
    float l[4] = {0.f, 0.f, 0.f, 0.f};
    float o[4][16];
#pragma unroll
    for (int r = 0; r < 4; ++r)
#pragma unroll
        for (int d = 0; d < 16; ++d) o[r][d] = 0.f;

    for (int j = 0; j < 256; ++j) {
        float4 ka = *(const float4*)&k_s[j][0];
        float4 kb = *(const float4*)&k_s[j][4];
        float4 kc = *(const float4*)&k_s[j][8];
        float4 kd = *(const float4*)&k_s[j][12];
        float4 va = *(const float4*)&v_s[j][0];
        float4 vb = *(const float4*)&v_s[j][4];
        float4 vc = *(const float4*)&v_s[j][8];
        float4 vd = *(const float4*)&v_s[j][12];
#pragma unroll
        for (int r = 0; r < 4; ++r) {
            float s = q[r][0] * ka.x + q[r][1] * ka.y + q[r][2] * ka.z + q[r][3] * ka.w
                    + q[r][4] * kb.x + q[r][5] * kb.y + q[r][6] * kb.z + q[r][7] * kb.w
                    + q[r][8] * kc.x + q[r][9] * kc.y + q[r][10] * kc.z + q[r][11] * kc.w
                    + q[r][12] * kd.x + q[r][13] * kd.y + q[r][14] * kd.z + q[r][15] * kd.w;
            float e = __expf(s);
            l[r] += e;
            o[r][0] += e * va.x;  o[r][1] += e * va.y;  o[r][2] += e * va.z;  o[r][3] += e * va.w;
            o[r][4] += e * vb.x;  o[r][5] += e * vb.y;  o[r][6] += e * vb.z;  o[r][7] += e * vb.w;
            o[r][8] += e * vc.x;  o[r][9] += e * vc.y;  o[r][10] += e * vc.z; o[r][11] += e * vc.w;
            o[r][12] += e * vd.x; o[r][13] += e * vd.y; o[r][14] += e * vd.z; o[r][15] += e * vd.w;
        }
    }
    float* ob = out + (size_t)b * CDIM * NPIX;
#pragma unroll
    for (int r = 0; r < 4; ++r) {
        float rl = 1.f / l[r];
#pragma unroll
        for (int d = 0; d < 16; ++d) {
            size_t idx = (size_t)(head * 16 + d) * NPIX + pix[r];
            float val = o[r][d] * rl;
            if (accumulate) ob[idx] += val;
            else ob[idx] = val;
        }
    }
}

extern "C" void kernel_launch(void* const* d_in, const int* in_sizes, int n_in,
                              void* d_out, int out_size, void* d_ws, size_t ws_size,
                              hipStream_t stream) {
    const float* x       = (const float*)d_in[0];
    const float* eca_w   = (const float*)d_in[1];
    const float* esa_al  = (const float*)d_in[2];
    const float* cpe1_w  = (const float*)d_in[3];  const float* cpe1_b = (const float*)d_in[4];
    const float* g1      = (const float*)d_in[5];  const float* b1     = (const float*)d_in[6];
    const float* actp_w  = (const float*)d_in[7];  const float* actp_b = (const float*)d_in[8];
    const float* inp_w   = (const float*)d_in[9];  const float* inp_b  = (const float*)d_in[10];
    const float* dwc_w   = (const float*)d_in[11]; const float* dwc_b  = (const float*)d_in[12];
    const float* qkv_w   = (const float*)d_in[13]; const float* qkv_b  = (const float*)d_in[14];
    const float* eaax_w  = (const float*)d_in[15]; const float* eaax_b = (const float*)d_in[16];
    const float* eaay_w  = (const float*)d_in[17]; const float* eaay_b = (const float*)d_in[18];
    const float* outp_w  = (const float*)d_in[19]; const float* outp_b = (const float*)d_in[20];
    const float* cpe2_w  = (const float*)d_in[21]; const float* cpe2_b = (const float*)d_in[22];
    const float* g2      = (const float*)d_in[23]; const float* b2     = (const float*)d_in[24];
    const float* mlp1_w  = (const float*)d_in[25]; const float* mlp1_b = (const float*)d_in[26];
    const float* mlp2_w  = (const float*)d_in[27]; const float* mlp2_b = (const float*)d_in[28];

    float* ws = (float*)d_ws;
    const size_t E = (size_t)BATCH * CDIM * NPIX;  // 4,194,304
    float* buf0 = ws;
    float* buf1 = ws + E;
    float* buf2 = ws + 2 * E;
    float* buf3 = ws + 3 * E;
    float* buf4 = ws + 4 * E;
    float* buf5 = ws + 5 * E;  // 5E region, free after attention stage
    // bf16 overlays (lifetimes disjoint from the f32 region they share):
    unsigned short* xt    = (unsigned short*)buf0;          // xn_t / t_t (buf0 dead steps 3-8)
    unsigned short* m_t   = (unsigned short*)buf5;          // a*act_res  (buf5 dead after attn)
    unsigned short* g2_t  = (unsigned short*)(ws + 5 * E + E / 2);
    unsigned short* hid_t = (unsigned short*)(ws + 6 * E);  // 4E bf16 = [6E, 8E) f32
    unsigned short* wpool = (unsigned short*)(ws + 10 * E); // 262144 bf16 = 131072 f32
    unsigned short* wq = wpool;
    unsigned short* wm1 = wpool + 81920;
    unsigned short* wm2 = wpool + 147456;
    unsigned short* wa = wpool + 212992;
    unsigned short* wi = wpool + 229376;
    unsigned short* wo = wpool + 245760;
    float* meanb = ws + 10 * E + 131072;   // 1024
    float* gateb = meanb + 1024;           // 1024
    float* gstats = gateb + 1024;          // 32 (gn1: [0,16), gn2: [16,32))

    hipMemsetAsync(gstats, 0, 32 * sizeof(float), stream);
    convert_w_kernel<<<1024, 256, 0, stream>>>(qkv_w, mlp1_w, mlp2_w, actp_w, inp_w, outp_w, wpool);

    // 1) ECA + ESA fused
    mean_bc_kernel<<<BATCH * CDIM, 256, 0, stream>>>(x, meanb);
    eca_gate_kernel<<<BATCH, CDIM, 0, stream>>>(meanb, eca_w, gateb);
    esa_kernel<<<dim3(16, BATCH), 256, 0, stream>>>(x, meanb, gateb, esa_al, buf0);
    // 2) x += cpe1 dwconv  -> shortcut (buf1)
    dwconv3_kernel<<<dim3(16, CDIM, BATCH), 256, 0, stream>>>(buf0, cpe1_w, cpe1_b, buf1,
                                                              1, 0, CDIM * NPIX, 1, 0);
    // 3) GroupNorm1 -> xt (bf16 NHWC)
    gn_stats_kernel<<<dim3(32, BATCH), 256, 0, stream>>>(buf1, gstats);
    to_nhwc_kernel<<<dim3(64, BATCH), 256, 0, stream>>>(buf1, nullptr, gstats, g1, b1, xt, 2);
    // 4) act_res = relu(actp(xn)) -> buf2
    conv_mfma_kernel<<<dim3(32, 1, BATCH), 256, 0, stream>>>(xt, wa, actp_b, nullptr, buf2,
                                                             nullptr, 128, 128, 1);
    // 5) t = relu(dwc(inp(xn)))  xt->buf3->buf4, then -> xt (bf16 NHWC)
    conv_mfma_kernel<<<dim3(32, 1, BATCH), 256, 0, stream>>>(xt, wi, inp_b, nullptr, buf3,
                                                             nullptr, 128, 128, 0);
    dwconv3_kernel<<<dim3(16, CDIM, BATCH), 256, 0, stream>>>(buf3, dwc_w, dwc_b, buf4,
                                                              1, 0, CDIM * NPIX, 0, 1);
    to_nhwc_kernel<<<dim3(64, BATCH), 256, 0, stream>>>(buf4, nullptr, nullptr, nullptr, nullptr, xt, 0);
    // 6) qkv conv (Cout=640) -> buf5 (f32 NCHW)
    conv_mfma_kernel<<<dim3(32, 5, BATCH), 256, 0, stream>>>(xt, wq, qkv_b, nullptr, buf5,
                                                             nullptr, 128, 640, 0);
    // 7) a = eaa(q0,k0,v0, 64x4) + eaa(q1,k1,v0, 4x64)  -> buf0
    attn_kernel<<<dim3(16, 8, BATCH), 64, 0, stream>>>(buf5, 0, 1, 0, buf0, 0);
    dwconv3_kernel<<<dim3(16, CDIM, BATCH), 256, 0, stream>>>(buf5, eaax_w, eaax_b, buf0,
                                                              5, 2, 640 * NPIX, 2, 0);
    attn_kernel<<<dim3(16, 8, BATCH), 64, 0, stream>>>(buf5, 3, 4, 1, buf0, 1);
    dwconv3_kernel<<<dim3(16, CDIM, BATCH), 256, 0, stream>>>(buf5, eaay_w, eaay_b, buf0,
                                                              5, 2, 640 * NPIX, 2, 0);
    // 8) m_t = bf16(a * act_res); out = outp(m) + shortcut -> buf3
    to_nhwc_kernel<<<dim3(64, BATCH), 256, 0, stream>>>(buf0, buf2, nullptr, nullptr, nullptr, m_t, 1);
    conv_mfma_kernel<<<dim3(32, 1, BATCH), 256, 0, stream>>>(m_t, wo, outp_b, buf1, buf3,
                                                             nullptr, 128, 128, 0);
    // 9) out += cpe2 dwconv -> buf4 (out2)
    dwconv3_kernel<<<dim3(16, CDIM, BATCH), 256, 0, stream>>>(buf3, cpe2_w, cpe2_b, buf4,
                                                              1, 0, CDIM * NPIX, 1, 0);
    // 10) GroupNorm2 -> g2_t (bf16 NHWC)
    gn_stats_kernel<<<dim3(32, BATCH), 256, 0, stream>>>(buf4, gstats + 16);
    to_nhwc_kernel<<<dim3(64, BATCH), 256, 0, stream>>>(buf4, nullptr, gstats + 16, g2, b2, g2_t, 2);
    // 11) mlp: relu(mlp1(gn2)) -> hid_t (bf16 NHWC) ; mlp2(...) + out2 -> d_out
    conv_mfma_kernel<<<dim3(32, 4, BATCH), 256, 0, stream>>>(g2_t, wm1, mlp1_b, nullptr, nullptr,
                                                             hid_t, 128, 512, 1);
    conv_mfma_kernel<<<dim3(32, 1, BATCH), 256, 0, stream>>>(hid_t, wm2, mlp2_b, buf4,
                                                             (float*)d_out, nullptr, 512, 128, 0);
}

// Round 3
// 533.314 us; speedup vs baseline: 2.4299x; 1.3373x over previous
//
#include <hip/hip_runtime.h>

#define NPIX 4096
#define CDIM 128
#define BATCH 8
#define EPSN 1e-5f

typedef __attribute__((ext_vector_type(8))) short short8;
typedef __attribute__((ext_vector_type(4))) float f32x4;
typedef __attribute__((ext_vector_type(16))) float f32x16;

__device__ __forceinline__ float sigmoidf_(float x) { return 1.f / (1.f + __expf(-x)); }

__device__ __forceinline__ unsigned short f2b(float f) {
    unsigned int u = __float_as_uint(f);
    unsigned int r = (u + 0x7FFF + ((u >> 16) & 1)) >> 16;  // RNE
    return (unsigned short)r;
}
__device__ __forceinline__ float b2f(unsigned short u) {
    return __uint_as_float((unsigned int)u << 16);
}

// window token -> pixel index
__device__ __forceinline__ int tok2pix(int mode, int wi, int l) {
    return (mode == 0) ? ((l >> 2) * 64 + wi * 4 + (l & 3))
                       : ((wi * 4 + (l >> 6)) * 64 + (l & 63));
}

// ---------------- weight conversion + qkv reorder + combined cpe weights ----------------
__global__ __launch_bounds__(256) void convert_w_kernel(const float* __restrict__ qkv_w,
                                                        const float* __restrict__ mlp1_w,
                                                        const float* __restrict__ mlp2_w,
                                                        const float* __restrict__ actp_w,
                                                        const float* __restrict__ inp_w,
                                                        const float* __restrict__ outp_w,
                                                        const float* __restrict__ qkv_b,
                                                        const float* __restrict__ eaax_w,
                                                        const float* __restrict__ eaax_b,
                                                        const float* __restrict__ eaay_w,
                                                        const float* __restrict__ eaay_b,
                                                        unsigned short* __restrict__ dst,
                                                        float* __restrict__ qb_r,
                                                        float* __restrict__ wsT,
                                                        float* __restrict__ bsum) {
    int i = blockIdx.x * 256 + threadIdx.x;
    if (i >= 264064) return;
    if (i < 262144) {
        float v;
        if (i < 81920) {
            int o = i >> 7, c = i & 127;              // reordered: o_new = g*128+cc
            v = qkv_w[(size_t)(5 * (o & 127) + (o >> 7)) * 128 + c];
        } else if (i < 147456) v = mlp1_w[i - 81920];
        else if (i < 212992)   v = mlp2_w[i - 147456];
        else if (i < 229376)   v = actp_w[i - 212992];
        else if (i < 245760)   v = inp_w[i - 229376];
        else                   v = outp_w[i - 245760];
        dst[i] = f2b(v);
    } else {
        int j = i - 262144;
        if (j < 640) qb_r[j] = qkv_b[5 * (j & 127) + (j >> 7)];
        else if (j < 1792) {
            int k = (j - 640) >> 7, c = (j - 640) & 127;
            wsT[j - 640] = eaax_w[c * 9 + k] + eaay_w[c * 9 + k];
        } else bsum[j - 1792] = eaax_b[j - 1792] + eaay_b[j - 1792];
    }
}

// ---------------- per-(b,c) mean over HW ----------------
__global__ __launch_bounds__(256) void mean_bc_kernel(const float* __restrict__ x,
                                                      float* __restrict__ mean) {
    __shared__ float sb[4];
    int bc = blockIdx.x;
    const float* p = x + (size_t)bc * NPIX;
    float s = 0.f;
    for (int i = threadIdx.x; i < NPIX; i += 256) s += p[i];
#pragma unroll
    for (int off = 32; off > 0; off >>= 1) s += __shfl_down(s, off, 64);
    if ((threadIdx.x & 63) == 0) sb[threadIdx.x >> 6] = s;
    __syncthreads();
    if (threadIdx.x == 0) mean[bc] = (sb[0] + sb[1] + sb[2] + sb[3]) * (1.f / (float)NPIX);
}

// ---------------- ECA gate ----------------
__global__ void eca_gate_kernel(const float* __restrict__ mean, const float* __restrict__ w5,
                                float* __restrict__ gate) {
    int b = blockIdx.x, c = threadIdx.x;
    float s = 0.f;
#pragma unroll
    for (int k = 0; k < 5; ++k) {
        int cc = c + k - 2;
        if (cc >= 0 && cc < CDIM) s += w5[k] * mean[b * CDIM + cc];
    }
    gate[b * CDIM + c] = sigmoidf_(s);
}

// ---------------- ESA + ECA combine ----------------
__global__ __launch_bounds__(256) void esa_kernel(const float* __restrict__ x,
                                                  const float* __restrict__ mean,
                                                  const float* __restrict__ gate,
                                                  const float* __restrict__ alpha_p,
                                                  float* __restrict__ out) {
    int b = blockIdx.y;
    int p = blockIdx.x * 256 + threadIdx.x;
    const float* xb = x + (size_t)b * CDIM * NPIX;
    const float* mb = mean + b * CDIM;
    float mx = -1e30f, mn = 1e30f;
    for (int c = 0; c < CDIM; ++c) {
        float v = xb[(size_t)c * NPIX + p] - mb[c];
        mx = fmaxf(mx, v);
        mn = fminf(mn, v);
    }
    float a = alpha_p[0];
    float s = sigmoidf_(mx) * a + sigmoidf_(mn) * (1.f - a);
    float* ob = out + (size_t)b * CDIM * NPIX;
    const float* gb = gate + b * CDIM;
    for (int c = 0; c < CDIM; ++c) {
        size_t i = (size_t)c * NPIX + p;
        ob[i] = xb[i] * (gb[c] + s);
    }
}

// ---------------- depthwise 3x3 conv (NCHW f32) ----------------
// mode 0: out = conv ; mode 1: out = in + conv
__global__ __launch_bounds__(256) void dwconv3_kernel(const float* __restrict__ in,
                                                      const float* __restrict__ wc,
                                                      const float* __restrict__ bias,
                                                      float* __restrict__ out,
                                                      int mode, int relu) {
    int c = blockIdx.y, b = blockIdx.z;
    int tx = threadIdx.x;
    int wd = tx & 63;
    int h = blockIdx.x * 4 + (tx >> 6);
    const float* inp = in + ((size_t)b * CDIM + c) * NPIX;
    float wr[9];
#pragma unroll
    for (int k = 0; k < 9; ++k) wr[k] = wc[c * 9 + k];
    float acc = bias[c];
#pragma unroll
    for (int dy = -1; dy <= 1; ++dy) {
        int hh = h + dy;
        if (hh < 0 || hh >= 64) continue;
#pragma unroll
        for (int dx = -1; dx <= 1; ++dx) {
            int ww = wd + dx;
            if (ww < 0 || ww >= 64) continue;
            acc += wr[(dy + 1) * 3 + (dx + 1)] * inp[hh * 64 + ww];
        }
    }
    float v = acc;
    if (mode == 1) v += inp[h * 64 + wd];
    if (relu) v = fmaxf(v, 0.f);
    out[((size_t)b * CDIM + c) * NPIX + h * 64 + wd] = v;
}

// ---------------- GroupNorm(1 group) stats ----------------
__global__ __launch_bounds__(256) void gn_stats_kernel(const float* __restrict__ xx,
                                                       float* __restrict__ stats) {
    __shared__ float sb[8];
    int b = blockIdx.y;
    const float* p = xx + (size_t)b * (CDIM * NPIX) + (size_t)blockIdx.x * 16384;
    float s = 0.f, s2 = 0.f;
    for (int i = threadIdx.x; i < 16384; i += 256) {
        float v = p[i];
        s += v; s2 += v * v;
    }
#pragma unroll
    for (int off = 32; off > 0; off >>= 1) {
        s += __shfl_down(s, off, 64);
        s2 += __shfl_down(s2, off, 64);
    }
    int wv = threadIdx.x >> 6;
    if ((threadIdx.x & 63) == 0) { sb[wv] = s; sb[4 + wv] = s2; }
    __syncthreads();
    if (threadIdx.x == 0) {
        atomicAdd(&stats[b * 2], sb[0] + sb[1] + sb[2] + sb[3]);
        atomicAdd(&stats[b * 2 + 1], sb[4] + sb[5] + sb[6] + sb[7]);
    }
}

// ---------------- NCHW f32 -> NHWC bf16 (mode 0: plain, mode 2: fused groupnorm) ----------------
__global__ __launch_bounds__(256) void to_nhwc_kernel(const float* __restrict__ src,
                                                      const float* __restrict__ stats,
                                                      const float* __restrict__ g,
                                                      const float* __restrict__ bta,
                                                      unsigned short* __restrict__ dst,
                                                      int mode) {
    __shared__ unsigned short tile[64][130];
    int b = blockIdx.y, p0 = blockIdx.x * 64;
    int tx = threadIdx.x, pl = tx & 63, cg = tx >> 6;
    float mu = 0.f, r = 1.f;
    if (mode == 2) {
        const float n = 1.f / (float)(CDIM * NPIX);
        mu = stats[b * 2] * n;
        float var = stats[b * 2 + 1] * n - mu * mu;
        r = rsqrtf(var + EPSN);
    }
    const float* sb = src + (size_t)b * CDIM * NPIX;
    for (int c = cg; c < CDIM; c += 4) {
        float v = sb[(size_t)c * NPIX + p0 + pl];
        if (mode == 2) v = (v - mu) * r * g[c] + bta[c];
        tile[pl][c] = f2b(v);
    }
    __syncthreads();
    int c2 = tx & 127, pr = tx >> 7;
    unsigned short* db = dst + ((size_t)b * NPIX + p0) * CDIM;
    for (int p = pr; p < 64; p += 2)
        db[(size_t)p * CDIM + c2] = tile[p][c2];
}

// ---------------- conv1x1 via bf16 MFMA ----------------
__global__ __launch_bounds__(256) void conv_mfma_kernel(const unsigned short* __restrict__ in_t,
                                                        const unsigned short* __restrict__ w,
                                                        const float* __restrict__ bias,
                                                        const float* __restrict__ res,
                                                        float* __restrict__ out,
                                                        unsigned short* __restrict__ out_t,
                                                        int Cin, int Cout, int relu) {
    __shared__ __align__(16) unsigned short A_s[128][136];
    __shared__ __align__(16) unsigned short B_s[128][136];
    int b = blockIdx.z, p0 = blockIdx.x * 128, o0 = blockIdx.y * 128;
    int tx = threadIdx.x;
    int wave = tx >> 6, lane = tx & 63;
    int wm = wave & 1, wn = wave >> 1;
    int quad = lane >> 4, l16 = lane & 15;

    f32x4 acc[4][4];
#pragma unroll
    for (int mt = 0; mt < 4; ++mt) {
#pragma unroll
        for (int r = 0; r < 4; ++r) {
            float bv = bias[o0 + wm * 64 + mt * 16 + quad * 4 + r];
#pragma unroll
            for (int nt = 0; nt < 4; ++nt) acc[mt][nt][r] = bv;
        }
    }

    for (int k0 = 0; k0 < Cin; k0 += 128) {
#pragma unroll
        for (int j = 0; j < 8; ++j) {
            int idx = tx + 256 * j;
            int row = idx >> 4, c16 = idx & 15;
            *(uint4*)&A_s[row][c16 * 8] =
                *(const uint4*)&w[(size_t)(o0 + row) * Cin + k0 + c16 * 8];
            *(uint4*)&B_s[row][c16 * 8] =
                *(const uint4*)&in_t[((size_t)b * NPIX + p0 + row) * Cin + k0 + c16 * 8];
        }
        __syncthreads();
#pragma unroll
        for (int ks = 0; ks < 128; ks += 32) {
            short8 af[4], bf[4];
#pragma unroll
            for (int mt = 0; mt < 4; ++mt)
                af[mt] = *(const short8*)&A_s[wm * 64 + mt * 16 + l16][ks + quad * 8];
#pragma unroll
            for (int nt = 0; nt < 4; ++nt)
                bf[nt] = *(const short8*)&B_s[wn * 64 + nt * 16 + l16][ks + quad * 8];
#pragma unroll
            for (int mt = 0; mt < 4; ++mt)
#pragma unroll
                for (int nt = 0; nt < 4; ++nt)
                    acc[mt][nt] = __builtin_amdgcn_mfma_f32_16x16x32_bf16(
                        af[mt], bf[nt], acc[mt][nt], 0, 0, 0);
        }
        __syncthreads();
    }

    if (out_t) {
#pragma unroll
        for (int mt = 0; mt < 4; ++mt) {
#pragma unroll
            for (int nt = 0; nt < 4; ++nt) {
                int p = p0 + wn * 64 + nt * 16 + l16;
                int ob = o0 + wm * 64 + mt * 16 + quad * 4;
                ushort4 u;
                float v0 = acc[mt][nt][0], v1 = acc[mt][nt][1];
                float v2 = acc[mt][nt][2], v3 = acc[mt][nt][3];
                if (relu) { v0 = fmaxf(v0, 0.f); v1 = fmaxf(v1, 0.f);
                            v2 = fmaxf(v2, 0.f); v3 = fmaxf(v3, 0.f); }
                u.x = f2b(v0); u.y = f2b(v1); u.z = f2b(v2); u.w = f2b(v3);
                *(ushort4*)&out_t[((size_t)b * NPIX + p) * Cout + ob] = u;
            }
        }
    } else {
        const float* resb = res ? res + (size_t)b * Cout * NPIX : nullptr;
        float* outb = out + (size_t)b * Cout * NPIX;
#pragma unroll
        for (int mt = 0; mt < 4; ++mt) {
#pragma unroll
            for (int nt = 0; nt < 4; ++nt) {
                int p = p0 + wn * 64 + nt * 16 + l16;
#pragma unroll
                for (int r = 0; r < 4; ++r) {
                    int o = o0 + wm * 64 + mt * 16 + quad * 4 + r;
                    float v = acc[mt][nt][r];
                    if (relu) v = fmaxf(v, 0.f);
                    if (resb) v += resb[(size_t)o * NPIX + p];
                    outb[(size_t)o * NPIX + p] = v;
                }
            }
        }
    }
}

// ---------------- MFMA window attention ----------------
// t_t: bf16 NHWC 640ch grouped [q0|k0|v0|q1|k1]; one wave per (window, head).
// a_out: f32 NHWC (B*NPIX, 128). accumulate=1 -> +=
__global__ __launch_bounds__(64) void attn_mfma_kernel(const unsigned short* __restrict__ t_t,
                                                       float* __restrict__ a_out,
                                                       int qoff, int koff, int mode,
                                                       int accumulate) {
    __shared__ __align__(16) unsigned short Vt[16][264];
    __shared__ __align__(16) unsigned short Pl[32][264];
    int wi = blockIdx.x, head = blockIdx.y, b = blockIdx.z;
    int l = threadIdx.x;
    int l32 = l & 31, half = l >> 5, l16 = l & 15, quad = l >> 4;
    const size_t base = (size_t)b * NPIX;
    const int hc = head * 16;

    // K fragments (B-operand of 32x32x16: [n=l32][k=half*8+j])
    short8 kf[8];
#pragma unroll
    for (int nt = 0; nt < 8; ++nt) {
        int p = tok2pix(mode, wi, nt * 32 + l32);
        kf[nt] = *(const short8*)&t_t[(base + p) * 640 + koff + hc + half * 8];
    }
    // V: stage transposed into LDS, then B-frags for 16x16x32 ([n=l16][k=quad*8+j])
#pragma unroll
    for (int it = 0; it < 4; ++it) {
        int tkn = it * 64 + l;
        int p = tok2pix(mode, wi, tkn);
        const unsigned short* vp = &t_t[(base + p) * 640 + 256 + hc];
        unsigned short tmp[16];
        *(uint4*)&tmp[0] = *(const uint4*)vp;
        *(uint4*)&tmp[8] = *(const uint4*)(vp + 8);
#pragma unroll
        for (int d = 0; d < 16; ++d) Vt[d][tkn] = tmp[d];
    }
    __syncthreads();
    short8 vf[8];
#pragma unroll
    for (int kc = 0; kc < 8; ++kc)
        vf[kc] = *(const short8*)&Vt[l16][kc * 32 + quad * 8];

    for (int st = 0; st < 8; ++st) {
        // Q fragment for this 32-row strip (A-operand of 32x32x16)
        int qp = tok2pix(mode, wi, st * 32 + l32);
        short8 qf = *(const short8*)&t_t[(base + qp) * 640 + qoff + hc + half * 8];
        f32x16 sacc[8];
#pragma unroll
        for (int nt = 0; nt < 8; ++nt) {
            f32x16 z;
#pragma unroll
            for (int r = 0; r < 16; ++r) z[r] = 0.f;
            sacc[nt] = __builtin_amdgcn_mfma_f32_32x32x16_bf16(qf, kf[nt], z, 0, 0, 0);
        }
        // exp (no max-subtraction: logits are small for this module)
#pragma unroll
        for (int nt = 0; nt < 8; ++nt)
#pragma unroll
            for (int r = 0; r < 16; ++r) sacc[nt][r] = __expf(sacc[nt][r]);
        // row sums: each lane owns rows (r&3)+8*(r>>2)+4*half; reduce over 32 lanes of the half
        float rinv[16];
#pragma unroll
        for (int r = 0; r < 16; ++r) {
            float s = 0.f;
#pragma unroll
            for (int nt = 0; nt < 8; ++nt) s += sacc[nt][r];
            s += __shfl_xor(s, 1);
            s += __shfl_xor(s, 2);
            s += __shfl_xor(s, 4);
            s += __shfl_xor(s, 8);
            s += __shfl_xor(s, 16);
            rinv[r] = 1.f / s;
        }
        // write normalized P to LDS (bank-conflict-free b16 pattern)
#pragma unroll
        for (int r = 0; r < 16; ++r) {
            int row = (r & 3) + 8 * (r >> 2) + 4 * half;
#pragma unroll
            for (int nt = 0; nt < 8; ++nt)
                Pl[row][nt * 32 + l32] = f2b(sacc[nt][r] * rinv[r]);
        }
        __syncthreads();
        // O strip = P(32x256) @ V(256x16) via 16x16x32
        f32x4 o0, o1;
#pragma unroll
        for (int r = 0; r < 4; ++r) { o0[r] = 0.f; o1[r] = 0.f; }
#pragma unroll
        for (int kc = 0; kc < 8; ++kc) {
            short8 pa0 = *(const short8*)&Pl[l16][kc * 32 + quad * 8];
            short8 pa1 = *(const short8*)&Pl[16 + l16][kc * 32 + quad * 8];
            o0 = __builtin_amdgcn_mfma_f32_16x16x32_bf16(pa0, vf[kc], o0, 0, 0, 0);
            o1 = __builtin_amdgcn_mfma_f32_16x16x32_bf16(pa1, vf[kc], o1, 0, 0, 0);
        }
        // store (f32 NHWC): row = quad*4+r, col = l16
#pragma unroll
        for (int r = 0; r < 4; ++r) {
            int q0r = st * 32 + quad * 4 + r;
            float* d0 = a_out + (base + tok2pix(mode, wi, q0r)) * 128 + hc + l16;
            float* d1 = a_out + (base + tok2pix(mode, wi, q0r + 16)) * 128 + hc + l16;
            if (accumulate) { *d0 += o0[r]; *d1 += o1[r]; }
            else { *d0 = o0[r]; *d1 = o1[r]; }
        }
        __syncthreads();
    }
}

// ---------------- combined cpe dwconv (NHWC bf16 in, f32 NHWC accumulate) ----------------
__global__ __launch_bounds__(256) void cpe_nhwc_kernel(const unsigned short* __restrict__ t_t,
                                                       const float* __restrict__ wT,
                                                       const float* __restrict__ bsum,
                                                       float* __restrict__ a_out) {
    int b = blockIdx.y;
    int tx = threadIdx.x;
    int cg = tx & 15, pp = tx >> 4;
    int p = blockIdx.x * 16 + pp;
    int xx = p & 63, yy = p >> 6;
    int c0 = cg * 8;
    float acc[8];
#pragma unroll
    for (int j = 0; j < 8; ++j) acc[j] = bsum[c0 + j];
#pragma unroll
    for (int dy = -1; dy <= 1; ++dy) {
        int y2 = yy + dy;
        if (y2 < 0 || y2 >= 64) continue;
#pragma unroll
        for (int dx = -1; dx <= 1; ++dx) {
            int x2 = xx + dx;
            if (x2 < 0 || x2 >= 64) continue;
            int pn = y2 * 64 + x2;
            unsigned short v[8];
            *(uint4*)v = *(const uint4*)&t_t[((size_t)b * NPIX + pn) * 640 + 256 + c0];
            const float* wr = wT + ((dy + 1) * 3 + dx + 1) * 128 + c0;
#pragma unroll
            for (int j = 0; j < 8; ++j) acc[j] += b2f(v[j]) * wr[j];
        }
    }
    float* dst = a_out + ((size_t)b * NPIX + p) * 128 + c0;
#pragma unroll
    for (int j = 0; j < 8; ++j) dst[j] += acc[j];
}

// ---------------- m_t = bf16(a * act_res)  (both NHWC) ----------------
__global__ __launch_bounds__(256) void mul_to_bf16_kernel(const float* __restrict__ a,
                                                          const unsigned short* __restrict__ act,
                                                          unsigned short* __restrict__ dst) {
    size_t i = ((size_t)blockIdx.x * 256 + threadIdx.x) * 8;
    float4 a0 = *(const float4*)&a[i];
    float4 a1 = *(const float4*)&a[i + 4];
    unsigned short t[8];
    *(uint4*)t = *(const uint4*)&act[i];
    unsigned short r[8];
    r[0] = f2b(a0.x * b2f(t[0])); r[1] = f2b(a0.y * b2f(t[1]));
    r[2] = f2b(a0.z * b2f(t[2])); r[3] = f2b(a0.w * b2f(t[3]));
    r[4] = f2b(a1.x * b2f(t[4])); r[5] = f2b(a1.y * b2f(t[5]));
    r[6] = f2b(a1.z * b2f(t[6])); r[7] = f2b(a1.w * b2f(t[7]));
    *(uint4*)&dst[i] = *(uint4*)r;
}

extern "C" void kernel_launch(void* const* d_in, const int* in_sizes, int n_in,
                              void* d_out, int out_size, void* d_ws, size_t ws_size,
                              hipStream_t stream) {
    const float* x       = (const float*)d_in[0];
    const float* eca_w   = (const float*)d_in[1];
    const float* esa_al  = (const float*)d_in[2];
    const float* cpe1_w  = (const float*)d_in[3];  const float* cpe1_b = (const float*)d_in[4];
    const float* g1      = (const float*)d_in[5];  const float* b1     = (const float*)d_in[6];
    const float* actp_w  = (const float*)d_in[7];  const float* actp_b = (const float*)d_in[8];
    const float* inp_w   = (const float*)d_in[9];  const float* inp_b  = (const float*)d_in[10];
    const float* dwc_w   = (const float*)d_in[11]; const float* dwc_b  = (const float*)d_in[12];
    const float* qkv_w   = (const float*)d_in[13]; const float* qkv_b  = (const float*)d_in[14];
    const float* eaax_w  = (const float*)d_in[15]; const float* eaax_b = (const float*)d_in[16];
    const float* eaay_w  = (const float*)d_in[17]; const float* eaay_b = (const float*)d_in[18];
    const float* outp_w  = (const float*)d_in[19]; const float* outp_b = (const float*)d_in[20];
    const float* cpe2_w  = (const float*)d_in[21]; const float* cpe2_b = (const float*)d_in[22];
    const float* g2      = (const float*)d_in[23]; const float* b2     = (const float*)d_in[24];
    const float* mlp1_w  = (const float*)d_in[25]; const float* mlp1_b = (const float*)d_in[26];
    const float* mlp2_w  = (const float*)d_in[27]; const float* mlp2_b = (const float*)d_in[28];

    float* ws = (float*)d_ws;
    const size_t E = (size_t)BATCH * CDIM * NPIX;  // 4,194,304
    float* buf0 = ws;            // esa out (NCHW) / xt overlay
    float* buf1 = ws + E;        // shortcut (NCHW)
    float* buf3 = ws + 3 * E;    // inp-out / a_f32 (NHWC) / outp-out
    float* buf4 = ws + 4 * E;    // dwc-out / out2
    unsigned short* xt    = (unsigned short*)buf0;            // xn_t, later t_t input
    unsigned short* act_t = (unsigned short*)(ws + 2 * E);    // [2E, 2.5E)
    unsigned short* m_t   = (unsigned short*)(ws + 2 * E + E / 2);  // [2.5E, 3E)
    unsigned short* t_t   = (unsigned short*)(ws + 5 * E);    // [5E, 7.5E) qkv NHWC bf16
    unsigned short* hid_t = (unsigned short*)(ws + 5 * E);    // reuse after t_t dead
    unsigned short* g2_t  = (unsigned short*)(ws + 8 * E);    // [8E, 8.5E)
    unsigned short* wpool = (unsigned short*)(ws + 10 * E);   // 262144 bf16
    unsigned short* wq  = wpool;
    unsigned short* wm1 = wpool + 81920;
    unsigned short* wm2 = wpool + 147456;
    unsigned short* wa  = wpool + 212992;
    unsigned short* wi_ = wpool + 229376;
    unsigned short* wo  = wpool + 245760;
    float* meanb  = ws + 10 * E + 131072;
    float* gateb  = meanb + 1024;
    float* gstats = gateb + 1024;   // 32
    float* qb_r   = gstats + 32;    // 640
    float* wsT    = qb_r + 640;     // 1152
    float* bsum   = wsT + 1152;     // 128

    hipMemsetAsync(gstats, 0, 32 * sizeof(float), stream);
    convert_w_kernel<<<1032, 256, 0, stream>>>(qkv_w, mlp1_w, mlp2_w, actp_w, inp_w, outp_w,
                                               qkv_b, eaax_w, eaax_b, eaay_w, eaay_b,
                                               wpool, qb_r, wsT, bsum);

    // 1) ECA + ESA
    mean_bc_kernel<<<BATCH * CDIM, 256, 0, stream>>>(x, meanb);
    eca_gate_kernel<<<BATCH, CDIM, 0, stream>>>(meanb, eca_w, gateb);
    esa_kernel<<<dim3(16, BATCH), 256, 0, stream>>>(x, meanb, gateb, esa_al, buf0);
    // 2) shortcut = x + cpe1
    dwconv3_kernel<<<dim3(16, CDIM, BATCH), 256, 0, stream>>>(buf0, cpe1_w, cpe1_b, buf1, 1, 0);
    // 3) GroupNorm1 -> xt (bf16 NHWC)
    gn_stats_kernel<<<dim3(32, BATCH), 256, 0, stream>>>(buf1, gstats);
    to_nhwc_kernel<<<dim3(64, BATCH), 256, 0, stream>>>(buf1, gstats, g1, b1, xt, 2);
    // 4) act_res = relu(actp(xn)) -> act_t (bf16 NHWC)
    conv_mfma_kernel<<<dim3(32, 1, BATCH), 256, 0, stream>>>(xt, wa, actp_b, nullptr, nullptr,
                                                             act_t, 128, 128, 1);
    // 5) t = relu(dwc(inp(xn)))
    conv_mfma_kernel<<<dim3(32, 1, BATCH), 256, 0, stream>>>(xt, wi_, inp_b, nullptr, buf3,
                                                             nullptr, 128, 128, 0);
    dwconv3_kernel<<<dim3(16, CDIM, BATCH), 256, 0, stream>>>(buf3, dwc_w, dwc_b, buf4, 0, 1);
    to_nhwc_kernel<<<dim3(64, BATCH), 256, 0, stream>>>(buf4, nullptr, nullptr, nullptr, xt, 0);
    // 6) qkv (reordered channels) -> t_t (bf16 NHWC, 640)
    conv_mfma_kernel<<<dim3(32, 5, BATCH), 256, 0, stream>>>(xt, wq, qb_r, nullptr, nullptr,
                                                             t_t, 128, 640, 0);
    // 7) a = attn0 + attn1 + combined cpe(v0)  -> buf3 (f32 NHWC)
    attn_mfma_kernel<<<dim3(16, 8, BATCH), 64, 0, stream>>>(t_t, buf3, 0, 128, 0, 0);
    attn_mfma_kernel<<<dim3(16, 8, BATCH), 64, 0, stream>>>(t_t, buf3, 384, 512, 1, 1);
    cpe_nhwc_kernel<<<dim3(256, BATCH), 256, 0, stream>>>(t_t, wsT, bsum, buf3);
    // 8) m_t = bf16(a * act_res); out = outp(m) + shortcut -> buf3 (NCHW f32)
    mul_to_bf16_kernel<<<2048, 256, 0, stream>>>(buf3, act_t, m_t);
    conv_mfma_kernel<<<dim3(32, 1, BATCH), 256, 0, stream>>>(m_t, wo, outp_b, buf1, buf3,
                                                             nullptr, 128, 128, 0);
    // 9) out2 = out + cpe2 -> buf4
    dwconv3_kernel<<<dim3(16, CDIM, BATCH), 256, 0, stream>>>(buf3, cpe2_w, cpe2_b, buf4, 1, 0);
    // 10) GroupNorm2 -> g2_t
    gn_stats_kernel<<<dim3(32, BATCH), 256, 0, stream>>>(buf4, gstats + 16);
    to_nhwc_kernel<<<dim3(64, BATCH), 256, 0, stream>>>(buf4, gstats + 16, g2, b2, g2_t, 2);
    // 11) mlp
    conv_mfma_kernel<<<dim3(32, 4, BATCH), 256, 0, stream>>>(g2_t, wm1, mlp1_b, nullptr, nullptr,
                                                             hid_t, 128, 512, 1);
    conv_mfma_kernel<<<dim3(32, 1, BATCH), 256, 0, stream>>>(hid_t, wm2, mlp2_b, buf4,
                                                             (float*)d_out, nullptr, 512, 128, 0);
}

// Round 4
// 484.601 us; speedup vs baseline: 2.6742x; 1.1005x over previous
//
#include <hip/hip_runtime.h>

#define NPIX 4096
#define CDIM 128
#define BATCH 8
#define EPSN 1e-5f

typedef __attribute__((ext_vector_type(8))) short short8;
typedef __attribute__((ext_vector_type(4))) float f32x4;
typedef __attribute__((ext_vector_type(16))) float f32x16;

__device__ __forceinline__ float sigmoidf_(float x) { return 1.f / (1.f + __expf(-x)); }

__device__ __forceinline__ unsigned short f2b(float f) {
    unsigned int u = __float_as_uint(f);
    unsigned int r = (u + 0x7FFF + ((u >> 16) & 1)) >> 16;  // RNE
    return (unsigned short)r;
}
__device__ __forceinline__ float b2f(unsigned short u) {
    return __uint_as_float((unsigned int)u << 16);
}

// window token -> pixel index
__device__ __forceinline__ int tok2pix(int mode, int wi, int l) {
    return (mode == 0) ? ((l >> 2) * 64 + wi * 4 + (l & 3))
                       : ((wi * 4 + (l >> 6)) * 64 + (l & 63));
}

// ---------------- weight conversion + qkv reorder + combined cpe weights ----------------
__global__ __launch_bounds__(256) void convert_w_kernel(const float* __restrict__ qkv_w,
                                                        const float* __restrict__ mlp1_w,
                                                        const float* __restrict__ mlp2_w,
                                                        const float* __restrict__ actp_w,
                                                        const float* __restrict__ inp_w,
                                                        const float* __restrict__ outp_w,
                                                        const float* __restrict__ qkv_b,
                                                        const float* __restrict__ eaax_w,
                                                        const float* __restrict__ eaax_b,
                                                        const float* __restrict__ eaay_w,
                                                        const float* __restrict__ eaay_b,
                                                        unsigned short* __restrict__ dst,
                                                        float* __restrict__ qb_r,
                                                        float* __restrict__ wsT,
                                                        float* __restrict__ bsum) {
    int i = blockIdx.x * 256 + threadIdx.x;
    if (i >= 264064) return;
    if (i < 262144) {
        float v;
        if (i < 81920) {
            int o = i >> 7, c = i & 127;              // reordered: o_new = g*128+cc
            v = qkv_w[(size_t)(5 * (o & 127) + (o >> 7)) * 128 + c];
        } else if (i < 147456) v = mlp1_w[i - 81920];
        else if (i < 212992)   v = mlp2_w[i - 147456];
        else if (i < 229376)   v = actp_w[i - 212992];
        else if (i < 245760)   v = inp_w[i - 229376];
        else                   v = outp_w[i - 245760];
        dst[i] = f2b(v);
    } else {
        int j = i - 262144;
        if (j < 640) qb_r[j] = qkv_b[5 * (j & 127) + (j >> 7)];
        else if (j < 1792) {
            int k = (j - 640) >> 7, c = (j - 640) & 127;
            wsT[j - 640] = eaax_w[c * 9 + k] + eaay_w[c * 9 + k];
        } else bsum[j - 1792] = eaax_b[j - 1792] + eaay_b[j - 1792];
    }
}

// ---------------- per-(b,c) mean over HW ----------------
__global__ __launch_bounds__(256) void mean_bc_kernel(const float* __restrict__ x,
                                                      float* __restrict__ mean) {
    __shared__ float sb[4];
    int bc = blockIdx.x;
    const float* p = x + (size_t)bc * NPIX;
    float s = 0.f;
    for (int i = threadIdx.x; i < NPIX; i += 256) s += p[i];
#pragma unroll
    for (int off = 32; off > 0; off >>= 1) s += __shfl_down(s, off, 64);
    if ((threadIdx.x & 63) == 0) sb[threadIdx.x >> 6] = s;
    __syncthreads();
    if (threadIdx.x == 0) mean[bc] = (sb[0] + sb[1] + sb[2] + sb[3]) * (1.f / (float)NPIX);
}

// ---------------- ECA gate ----------------
__global__ void eca_gate_kernel(const float* __restrict__ mean, const float* __restrict__ w5,
                                float* __restrict__ gate) {
    int b = blockIdx.x, c = threadIdx.x;
    float s = 0.f;
#pragma unroll
    for (int k = 0; k < 5; ++k) {
        int cc = c + k - 2;
        if (cc >= 0 && cc < CDIM) s += w5[k] * mean[b * CDIM + cc];
    }
    gate[b * CDIM + c] = sigmoidf_(s);
}

// ---------------- ESA + ECA combine ----------------
__global__ __launch_bounds__(256) void esa_kernel(const float* __restrict__ x,
                                                  const float* __restrict__ mean,
                                                  const float* __restrict__ gate,
                                                  const float* __restrict__ alpha_p,
                                                  float* __restrict__ out) {
    int b = blockIdx.y;
    int p = blockIdx.x * 256 + threadIdx.x;
    const float* xb = x + (size_t)b * CDIM * NPIX;
    const float* mb = mean + b * CDIM;
    float mx = -1e30f, mn = 1e30f;
    for (int c = 0; c < CDIM; ++c) {
        float v = xb[(size_t)c * NPIX + p] - mb[c];
        mx = fmaxf(mx, v);
        mn = fminf(mn, v);
    }
    float a = alpha_p[0];
    float s = sigmoidf_(mx) * a + sigmoidf_(mn) * (1.f - a);
    float* ob = out + (size_t)b * CDIM * NPIX;
    const float* gb = gate + b * CDIM;
    for (int c = 0; c < CDIM; ++c) {
        size_t i = (size_t)c * NPIX + p;
        ob[i] = xb[i] * (gb[c] + s);
    }
}

// ---------------- depthwise 3x3 conv (NCHW f32) ----------------
// mode 0: out = conv ; mode 1: out = in + conv
__global__ __launch_bounds__(256) void dwconv3_kernel(const float* __restrict__ in,
                                                      const float* __restrict__ wc,
                                                      const float* __restrict__ bias,
                                                      float* __restrict__ out,
                                                      int mode, int relu) {
    int c = blockIdx.y, b = blockIdx.z;
    int tx = threadIdx.x;
    int wd = tx & 63;
    int h = blockIdx.x * 4 + (tx >> 6);
    const float* inp = in + ((size_t)b * CDIM + c) * NPIX;
    float wr[9];
#pragma unroll
    for (int k = 0; k < 9; ++k) wr[k] = wc[c * 9 + k];
    float acc = bias[c];
#pragma unroll
    for (int dy = -1; dy <= 1; ++dy) {
        int hh = h + dy;
        if (hh < 0 || hh >= 64) continue;
#pragma unroll
        for (int dx = -1; dx <= 1; ++dx) {
            int ww = wd + dx;
            if (ww < 0 || ww >= 64) continue;
            acc += wr[(dy + 1) * 3 + (dx + 1)] * inp[hh * 64 + ww];
        }
    }
    float v = acc;
    if (mode == 1) v += inp[h * 64 + wd];
    if (relu) v = fmaxf(v, 0.f);
    out[((size_t)b * CDIM + c) * NPIX + h * 64 + wd] = v;
}

// ---------------- GroupNorm(1 group) stats ----------------
__global__ __launch_bounds__(256) void gn_stats_kernel(const float* __restrict__ xx,
                                                       float* __restrict__ stats) {
    __shared__ float sb[8];
    int b = blockIdx.y;
    const float* p = xx + (size_t)b * (CDIM * NPIX) + (size_t)blockIdx.x * 16384;
    float s = 0.f, s2 = 0.f;
    for (int i = threadIdx.x; i < 16384; i += 256) {
        float v = p[i];
        s += v; s2 += v * v;
    }
#pragma unroll
    for (int off = 32; off > 0; off >>= 1) {
        s += __shfl_down(s, off, 64);
        s2 += __shfl_down(s2, off, 64);
    }
    int wv = threadIdx.x >> 6;
    if ((threadIdx.x & 63) == 0) { sb[wv] = s; sb[4 + wv] = s2; }
    __syncthreads();
    if (threadIdx.x == 0) {
        atomicAdd(&stats[b * 2], sb[0] + sb[1] + sb[2] + sb[3]);
        atomicAdd(&stats[b * 2 + 1], sb[4] + sb[5] + sb[6] + sb[7]);
    }
}

// ---------------- NCHW f32 -> NHWC bf16 (mode 0: plain, mode 2: fused groupnorm) ----------------
__global__ __launch_bounds__(256) void to_nhwc_kernel(const float* __restrict__ src,
                                                      const float* __restrict__ stats,
                                                      const float* __restrict__ g,
                                                      const float* __restrict__ bta,
                                                      unsigned short* __restrict__ dst,
                                                      int mode) {
    __shared__ unsigned short tile[64][130];
    int b = blockIdx.y, p0 = blockIdx.x * 64;
    int tx = threadIdx.x, pl = tx & 63, cg = tx >> 6;
    float mu = 0.f, r = 1.f;
    if (mode == 2) {
        const float n = 1.f / (float)(CDIM * NPIX);
        mu = stats[b * 2] * n;
        float var = stats[b * 2 + 1] * n - mu * mu;
        r = rsqrtf(var + EPSN);
    }
    const float* sb = src + (size_t)b * CDIM * NPIX;
    for (int c = cg; c < CDIM; c += 4) {
        float v = sb[(size_t)c * NPIX + p0 + pl];
        if (mode == 2) v = (v - mu) * r * g[c] + bta[c];
        tile[pl][c] = f2b(v);
    }
    __syncthreads();
    int c2 = tx & 127, pr = tx >> 7;
    unsigned short* db = dst + ((size_t)b * NPIX + p0) * CDIM;
    for (int p = pr; p < 64; p += 2)
        db[(size_t)p * CDIM + c2] = tile[p][c2];
}

// ---------------- conv1x1 via bf16 MFMA ----------------
__global__ __launch_bounds__(256) void conv_mfma_kernel(const unsigned short* __restrict__ in_t,
                                                        const unsigned short* __restrict__ w,
                                                        const float* __restrict__ bias,
                                                        const float* __restrict__ res,
                                                        float* __restrict__ out,
                                                        unsigned short* __restrict__ out_t,
                                                        int Cin, int Cout, int relu) {
    __shared__ __align__(16) unsigned short A_s[128][136];
    __shared__ __align__(16) unsigned short B_s[128][136];
    int b = blockIdx.z, p0 = blockIdx.x * 128, o0 = blockIdx.y * 128;
    int tx = threadIdx.x;
    int wave = tx >> 6, lane = tx & 63;
    int wm = wave & 1, wn = wave >> 1;
    int quad = lane >> 4, l16 = lane & 15;

    f32x4 acc[4][4];
#pragma unroll
    for (int mt = 0; mt < 4; ++mt) {
#pragma unroll
        for (int r = 0; r < 4; ++r) {
            float bv = bias[o0 + wm * 64 + mt * 16 + quad * 4 + r];
#pragma unroll
            for (int nt = 0; nt < 4; ++nt) acc[mt][nt][r] = bv;
        }
    }

    for (int k0 = 0; k0 < Cin; k0 += 128) {
#pragma unroll
        for (int j = 0; j < 8; ++j) {
            int idx = tx + 256 * j;
            int row = idx >> 4, c16 = idx & 15;
            *(uint4*)&A_s[row][c16 * 8] =
                *(const uint4*)&w[(size_t)(o0 + row) * Cin + k0 + c16 * 8];
            *(uint4*)&B_s[row][c16 * 8] =
                *(const uint4*)&in_t[((size_t)b * NPIX + p0 + row) * Cin + k0 + c16 * 8];
        }
        __syncthreads();
#pragma unroll
        for (int ks = 0; ks < 128; ks += 32) {
            short8 af[4], bf[4];
#pragma unroll
            for (int mt = 0; mt < 4; ++mt)
                af[mt] = *(const short8*)&A_s[wm * 64 + mt * 16 + l16][ks + quad * 8];
#pragma unroll
            for (int nt = 0; nt < 4; ++nt)
                bf[nt] = *(const short8*)&B_s[wn * 64 + nt * 16 + l16][ks + quad * 8];
#pragma unroll
            for (int mt = 0; mt < 4; ++mt)
#pragma unroll
                for (int nt = 0; nt < 4; ++nt)
                    acc[mt][nt] = __builtin_amdgcn_mfma_f32_16x16x32_bf16(
                        af[mt], bf[nt], acc[mt][nt], 0, 0, 0);
        }
        __syncthreads();
    }

    if (out_t) {
#pragma unroll
        for (int mt = 0; mt < 4; ++mt) {
#pragma unroll
            for (int nt = 0; nt < 4; ++nt) {
                int p = p0 + wn * 64 + nt * 16 + l16;
                int ob = o0 + wm * 64 + mt * 16 + quad * 4;
                ushort4 u;
                float v0 = acc[mt][nt][0], v1 = acc[mt][nt][1];
                float v2 = acc[mt][nt][2], v3 = acc[mt][nt][3];
                if (relu) { v0 = fmaxf(v0, 0.f); v1 = fmaxf(v1, 0.f);
                            v2 = fmaxf(v2, 0.f); v3 = fmaxf(v3, 0.f); }
                u.x = f2b(v0); u.y = f2b(v1); u.z = f2b(v2); u.w = f2b(v3);
                *(ushort4*)&out_t[((size_t)b * NPIX + p) * Cout + ob] = u;
            }
        }
    } else {
        const float* resb = res ? res + (size_t)b * Cout * NPIX : nullptr;
        float* outb = out + (size_t)b * Cout * NPIX;
#pragma unroll
        for (int mt = 0; mt < 4; ++mt) {
#pragma unroll
            for (int nt = 0; nt < 4; ++nt) {
                int p = p0 + wn * 64 + nt * 16 + l16;
#pragma unroll
                for (int r = 0; r < 4; ++r) {
                    int o = o0 + wm * 64 + mt * 16 + quad * 4 + r;
                    float v = acc[mt][nt][r];
                    if (relu) v = fmaxf(v, 0.f);
                    if (resb) v += resb[(size_t)o * NPIX + p];
                    outb[(size_t)o * NPIX + p] = v;
                }
            }
        }
    }
}

// ---------------- MFMA window attention, register-resident P ----------------
// t_t: bf16 NHWC 640ch grouped [q0|k0|v0|q1|k1]; block 256 = 4 waves per (window, head).
// Computes S^T strips via mfma(A=K_strip, B=Q_frag); P stays in registers; PV via
// mfma(A=V^T chunk, B=P^T) with an in-register half-wave swap. a_out: f32 NHWC.
__global__ __launch_bounds__(256) void attn_mfma_kernel(const unsigned short* __restrict__ t_t,
                                                        float* __restrict__ a_out,
                                                        int qoff, int koff, int mode,
                                                        int accumulate) {
    __shared__ __align__(16) unsigned short Vt[16][264];
    int wi = blockIdx.x, head = blockIdx.y, b = blockIdx.z;
    int tx = threadIdx.x;
    int wave = tx >> 6, l = tx & 63;
    int l32 = l & 31, half = l >> 5;
    const size_t base = (size_t)b * NPIX;
    const int hc = head * 16;

    // stage V transposed (16 d x 256 tokens); thread tx handles token tx
    {
        int p = tok2pix(mode, wi, tx);
        const unsigned short* vp = &t_t[(base + p) * 640 + 256 + hc];
        unsigned short tmp[16];
        *(uint4*)&tmp[0] = *(const uint4*)vp;
        *(uint4*)&tmp[8] = *(const uint4*)(vp + 8);
#pragma unroll
        for (int d = 0; d < 16; ++d) Vt[d][tx] = tmp[d];
    }
    // K fragments: strip nt token = nt*32 + l32, d = half*8 + j
    short8 kf[8];
#pragma unroll
    for (int nt = 0; nt < 8; ++nt) {
        int p = tok2pix(mode, wi, nt * 32 + l32);
        kf[nt] = *(const short8*)&t_t[(base + p) * 640 + koff + hc + half * 8];
    }
    __syncthreads();

    for (int qi = 0; qi < 2; ++qi) {
        int qs = qi * 4 + wave;  // query strip 0..7
        int qp = tok2pix(mode, wi, qs * 32 + l32);
        short8 qf = *(const short8*)&t_t[(base + qp) * 640 + qoff + hc + half * 8];
        f32x16 o_acc;
#pragma unroll
        for (int r = 0; r < 16; ++r) o_acc[r] = 0.f;
        float rs = 0.f;
#pragma unroll
        for (int nt = 0; nt < 8; ++nt) {
            f32x16 z;
#pragma unroll
            for (int r = 0; r < 16; ++r) z[r] = 0.f;
            // S^T strip: D[t][m], lane col m=l32, rows t=(r&3)+8*(r>>2)+4*half
            f32x16 s = __builtin_amdgcn_mfma_f32_32x32x16_bf16(kf[nt], qf, z, 0, 0, 0);
            unsigned int pk[8];
#pragma unroll
            for (int i = 0; i < 8; ++i) {
                float e0 = __expf(s[2 * i]);
                float e1 = __expf(s[2 * i + 1]);
                rs += e0 + e1;
                // pack (bf16(e0), bf16(e1)) by truncation: 1 v_perm
                pk[i] = __builtin_amdgcn_perm(__float_as_uint(e1), __float_as_uint(e0),
                                              0x07060302u);
            }
            unsigned int xpk[8];
#pragma unroll
            for (int i = 0; i < 8; ++i)
                xpk[i] = (unsigned int)__shfl_xor((int)pk[i], 32, 64);
            // assemble P^T B-fragments (k = t-local, n = query col)
            unsigned int u0[4], u1[4];
            if (half == 0) {
                u0[0] = pk[0]; u0[1] = pk[1]; u0[2] = xpk[0]; u0[3] = xpk[1];
                u1[0] = pk[4]; u1[1] = pk[5]; u1[2] = xpk[4]; u1[3] = xpk[5];
            } else {
                u0[0] = xpk[2]; u0[1] = xpk[3]; u0[2] = pk[2]; u0[3] = pk[3];
                u1[0] = xpk[6]; u1[1] = xpk[7]; u1[2] = pk[6]; u1[3] = pk[7];
            }
            short8 vf0, vf1;
#pragma unroll
            for (int r = 0; r < 8; ++r) { vf0[r] = 0; vf1[r] = 0; }
            if (l32 < 16) {
                vf0 = *(const short8*)&Vt[l32][nt * 32 + half * 8];
                vf1 = *(const short8*)&Vt[l32][nt * 32 + 16 + half * 8];
            }
            o_acc = __builtin_amdgcn_mfma_f32_32x32x16_bf16(vf0, *(short8*)u0, o_acc, 0, 0, 0);
            o_acc = __builtin_amdgcn_mfma_f32_32x32x16_bf16(vf1, *(short8*)u1, o_acc, 0, 0, 0);
        }
        rs += __shfl_xor(rs, 32, 64);
        float rinv = 1.f / rs;
        // O^T: lane col m=l32 (pixel qp), rows d=(r&3)+8*(r>>2)+4*half (r<8 valid)
        float* dst = a_out + (base + qp) * 128 + hc;
#pragma unroll
        for (int r = 0; r < 8; ++r) {
            int d = (r & 3) + 8 * (r >> 2) + 4 * half;
            float v = o_acc[r] * rinv;
            if (accumulate) dst[d] += v;
            else dst[d] = v;
        }
    }
}

// ---------------- combined cpe dwconv (NHWC bf16 in, f32 NHWC accumulate) ----------------
__global__ __launch_bounds__(256) void cpe_nhwc_kernel(const unsigned short* __restrict__ t_t,
                                                       const float* __restrict__ wT,
                                                       const float* __restrict__ bsum,
                                                       float* __restrict__ a_out) {
    int b = blockIdx.y;
    int tx = threadIdx.x;
    int cg = tx & 15, pp = tx >> 4;
    int p = blockIdx.x * 16 + pp;
    int xx = p & 63, yy = p >> 6;
    int c0 = cg * 8;
    float acc[8];
#pragma unroll
    for (int j = 0; j < 8; ++j) acc[j] = bsum[c0 + j];
#pragma unroll
    for (int dy = -1; dy <= 1; ++dy) {
        int y2 = yy + dy;
        if (y2 < 0 || y2 >= 64) continue;
#pragma unroll
        for (int dx = -1; dx <= 1; ++dx) {
            int x2 = xx + dx;
            if (x2 < 0 || x2 >= 64) continue;
            int pn = y2 * 64 + x2;
            unsigned short v[8];
            *(uint4*)v = *(const uint4*)&t_t[((size_t)b * NPIX + pn) * 640 + 256 + c0];
            const float* wr = wT + ((dy + 1) * 3 + dx + 1) * 128 + c0;
#pragma unroll
            for (int j = 0; j < 8; ++j) acc[j] += b2f(v[j]) * wr[j];
        }
    }
    float* dst = a_out + ((size_t)b * NPIX + p) * 128 + c0;
#pragma unroll
    for (int j = 0; j < 8; ++j) dst[j] += acc[j];
}

// ---------------- m_t = bf16(a * act_res)  (both NHWC) ----------------
__global__ __launch_bounds__(256) void mul_to_bf16_kernel(const float* __restrict__ a,
                                                          const unsigned short* __restrict__ act,
                                                          unsigned short* __restrict__ dst) {
    size_t i = ((size_t)blockIdx.x * 256 + threadIdx.x) * 8;
    float4 a0 = *(const float4*)&a[i];
    float4 a1 = *(const float4*)&a[i + 4];
    unsigned short t[8];
    *(uint4*)t = *(const uint4*)&act[i];
    unsigned short r[8];
    r[0] = f2b(a0.x * b2f(t[0])); r[1] = f2b(a0.y * b2f(t[1]));
    r[2] = f2b(a0.z * b2f(t[2])); r[3] = f2b(a0.w * b2f(t[3]));
    r[4] = f2b(a1.x * b2f(t[4])); r[5] = f2b(a1.y * b2f(t[5]));
    r[6] = f2b(a1.z * b2f(t[6])); r[7] = f2b(a1.w * b2f(t[7]));
    *(uint4*)&dst[i] = *(uint4*)r;
}

extern "C" void kernel_launch(void* const* d_in, const int* in_sizes, int n_in,
                              void* d_out, int out_size, void* d_ws, size_t ws_size,
                              hipStream_t stream) {
    const float* x       = (const float*)d_in[0];
    const float* eca_w   = (const float*)d_in[1];
    const float* esa_al  = (const float*)d_in[2];
    const float* cpe1_w  = (const float*)d_in[3];  const float* cpe1_b = (const float*)d_in[4];
    const float* g1      = (const float*)d_in[5];  const float* b1     = (const float*)d_in[6];
    const float* actp_w  = (const float*)d_in[7];  const float* actp_b = (const float*)d_in[8];
    const float* inp_w   = (const float*)d_in[9];  const float* inp_b  = (const float*)d_in[10];
    const float* dwc_w   = (const float*)d_in[11]; const float* dwc_b  = (const float*)d_in[12];
    const float* qkv_w   = (const float*)d_in[13]; const float* qkv_b  = (const float*)d_in[14];
    const float* eaax_w  = (const float*)d_in[15]; const float* eaax_b = (const float*)d_in[16];
    const float* eaay_w  = (const float*)d_in[17]; const float* eaay_b = (const float*)d_in[18];
    const float* outp_w  = (const float*)d_in[19]; const float* outp_b = (const float*)d_in[20];
    const float* cpe2_w  = (const float*)d_in[21]; const float* cpe2_b = (const float*)d_in[22];
    const float* g2      = (const float*)d_in[23]; const float* b2     = (const float*)d_in[24];
    const float* mlp1_w  = (const float*)d_in[25]; const float* mlp1_b = (const float*)d_in[26];
    const float* mlp2_w  = (const float*)d_in[27]; const float* mlp2_b = (const float*)d_in[28];

    float* ws = (float*)d_ws;
    const size_t E = (size_t)BATCH * CDIM * NPIX;  // 4,194,304
    float* buf0 = ws;            // esa out (NCHW) / xt overlay
    float* buf1 = ws + E;        // shortcut (NCHW)
    float* buf3 = ws + 3 * E;    // inp-out / a_f32 (NHWC) / outp-out
    float* buf4 = ws + 4 * E;    // dwc-out / out2
    unsigned short* xt    = (unsigned short*)buf0;            // xn_t, later t_t input
    unsigned short* act_t = (unsigned short*)(ws + 2 * E);    // [2E, 2.5E)
    unsigned short* m_t   = (unsigned short*)(ws + 2 * E + E / 2);  // [2.5E, 3E)
    unsigned short* t_t   = (unsigned short*)(ws + 5 * E);    // [5E, 7.5E) qkv NHWC bf16
    unsigned short* hid_t = (unsigned short*)(ws + 5 * E);    // reuse after t_t dead
    unsigned short* g2_t  = (unsigned short*)(ws + 8 * E);    // [8E, 8.5E)
    unsigned short* wpool = (unsigned short*)(ws + 10 * E);   // 262144 bf16
    unsigned short* wq  = wpool;
    unsigned short* wm1 = wpool + 81920;
    unsigned short* wm2 = wpool + 147456;
    unsigned short* wa  = wpool + 212992;
    unsigned short* wi_ = wpool + 229376;
    unsigned short* wo  = wpool + 245760;
    float* meanb  = ws + 10 * E + 131072;
    float* gateb  = meanb + 1024;
    float* gstats = gateb + 1024;   // 32
    float* qb_r   = gstats + 32;    // 640
    float* wsT    = qb_r + 640;     // 1152
    float* bsum   = wsT + 1152;     // 128

    hipMemsetAsync(gstats, 0, 32 * sizeof(float), stream);
    convert_w_kernel<<<1032, 256, 0, stream>>>(qkv_w, mlp1_w, mlp2_w, actp_w, inp_w, outp_w,
                                               qkv_b, eaax_w, eaax_b, eaay_w, eaay_b,
                                               wpool, qb_r, wsT, bsum);

    // 1) ECA + ESA
    mean_bc_kernel<<<BATCH * CDIM, 256, 0, stream>>>(x, meanb);
    eca_gate_kernel<<<BATCH, CDIM, 0, stream>>>(meanb, eca_w, gateb);
    esa_kernel<<<dim3(16, BATCH), 256, 0, stream>>>(x, meanb, gateb, esa_al, buf0);
    // 2) shortcut = x + cpe1
    dwconv3_kernel<<<dim3(16, CDIM, BATCH), 256, 0, stream>>>(buf0, cpe1_w, cpe1_b, buf1, 1, 0);
    // 3) GroupNorm1 -> xt (bf16 NHWC)
    gn_stats_kernel<<<dim3(32, BATCH), 256, 0, stream>>>(buf1, gstats);
    to_nhwc_kernel<<<dim3(64, BATCH), 256, 0, stream>>>(buf1, gstats, g1, b1, xt, 2);
    // 4) act_res = relu(actp(xn)) -> act_t (bf16 NHWC)
    conv_mfma_kernel<<<dim3(32, 1, BATCH), 256, 0, stream>>>(xt, wa, actp_b, nullptr, nullptr,
                                                             act_t, 128, 128, 1);
    // 5) t = relu(dwc(inp(xn)))
    conv_mfma_kernel<<<dim3(32, 1, BATCH), 256, 0, stream>>>(xt, wi_, inp_b, nullptr, buf3,
                                                             nullptr, 128, 128, 0);
    dwconv3_kernel<<<dim3(16, CDIM, BATCH), 256, 0, stream>>>(buf3, dwc_w, dwc_b, buf4, 0, 1);
    to_nhwc_kernel<<<dim3(64, BATCH), 256, 0, stream>>>(buf4, nullptr, nullptr, nullptr, xt, 0);
    // 6) qkv (reordered channels) -> t_t (bf16 NHWC, 640)
    conv_mfma_kernel<<<dim3(32, 5, BATCH), 256, 0, stream>>>(xt, wq, qb_r, nullptr, nullptr,
                                                             t_t, 128, 640, 0);
    // 7) a = attn0 + attn1 + combined cpe(v0)  -> buf3 (f32 NHWC)
    attn_mfma_kernel<<<dim3(16, 8, BATCH), 256, 0, stream>>>(t_t, buf3, 0, 128, 0, 0);
    attn_mfma_kernel<<<dim3(16, 8, BATCH), 256, 0, stream>>>(t_t, buf3, 384, 512, 1, 1);
    cpe_nhwc_kernel<<<dim3(256, BATCH), 256, 0, stream>>>(t_t, wsT, bsum, buf3);
    // 8) m_t = bf16(a * act_res); out = outp(m) + shortcut -> buf3 (NCHW f32)
    mul_to_bf16_kernel<<<2048, 256, 0, stream>>>(buf3, act_t, m_t);
    conv_mfma_kernel<<<dim3(32, 1, BATCH), 256, 0, stream>>>(m_t, wo, outp_b, buf1, buf3,
                                                             nullptr, 128, 128, 0);
    // 9) out2 = out + cpe2 -> buf4
    dwconv3_kernel<<<dim3(16, CDIM, BATCH), 256, 0, stream>>>(buf3, cpe2_w, cpe2_b, buf4, 1, 0);
    // 10) GroupNorm2 -> g2_t
    gn_stats_kernel<<<dim3(32, BATCH), 256, 0, stream>>>(buf4, gstats + 16);
    to_nhwc_kernel<<<dim3(64, BATCH), 256, 0, stream>>>(buf4, gstats + 16, g2, b2, g2_t, 2);
    // 11) mlp
    conv_mfma_kernel<<<dim3(32, 4, BATCH), 256, 0, stream>>>(g2_t, wm1, mlp1_b, nullptr, nullptr,
                                                             hid_t, 128, 512, 1);
    conv_mfma_kernel<<<dim3(32, 1, BATCH), 256, 0, stream>>>(hid_t, wm2, mlp2_b, buf4,
                                                             (float*)d_out, nullptr, 512, 128, 0);
}

// Round 7
// 421.541 us; speedup vs baseline: 3.0742x; 1.1496x over previous
//
#include <hip/hip_runtime.h>

#define NPIX 4096
#define CDIM 128
#define BATCH 8
#define EPSN 1e-5f

typedef __attribute__((ext_vector_type(8))) short short8;
typedef __attribute__((ext_vector_type(4))) float f32x4;
typedef __attribute__((ext_vector_type(16))) float f32x16;

__device__ __forceinline__ float sigmoidf_(float x) { return 1.f / (1.f + __expf(-x)); }

__device__ __forceinline__ unsigned short f2b(float f) {
    unsigned int u = __float_as_uint(f);
    unsigned int r = (u + 0x7FFF + ((u >> 16) & 1)) >> 16;  // RNE
    return (unsigned short)r;
}
__device__ __forceinline__ float b2f(unsigned short u) {
    return __uint_as_float((unsigned int)u << 16);
}

// window token -> pixel index
__device__ __forceinline__ int tok2pix(int mode, int wi, int l) {
    return (mode == 0) ? ((l >> 2) * 64 + wi * 4 + (l & 3))
                       : ((wi * 4 + (l >> 6)) * 64 + (l & 63));
}

// ---------------- weight conversion / reorder / transposes ----------------
__global__ __launch_bounds__(256) void convert_w_kernel(const float* __restrict__ qkv_w,
                                                        const float* __restrict__ mlp1_w,
                                                        const float* __restrict__ mlp2_w,
                                                        const float* __restrict__ actp_w,
                                                        const float* __restrict__ inp_w,
                                                        const float* __restrict__ outp_w,
                                                        const float* __restrict__ qkv_b,
                                                        const float* __restrict__ eaax_w,
                                                        const float* __restrict__ eaax_b,
                                                        const float* __restrict__ eaay_w,
                                                        const float* __restrict__ eaay_b,
                                                        const float* __restrict__ cpe1_w,
                                                        const float* __restrict__ dwc_w,
                                                        const float* __restrict__ cpe2_w,
                                                        unsigned short* __restrict__ dst,
                                                        float* __restrict__ qb_r,
                                                        float* __restrict__ wsT,
                                                        float* __restrict__ bsum,
                                                        float* __restrict__ cpe1T,
                                                        float* __restrict__ dwcT,
                                                        float* __restrict__ cpe2T) {
    int i = blockIdx.x * 256 + threadIdx.x;
    if (i >= 267520) return;
    if (i < 262144) {
        float v;
        if (i < 81920) {
            int o = i >> 7, c = i & 127;              // reordered: o_new = g*128+cc
            v = qkv_w[(size_t)(5 * (o & 127) + (o >> 7)) * 128 + c];
        } else if (i < 147456) v = mlp1_w[i - 81920];
        else if (i < 212992)   v = mlp2_w[i - 147456];
        else if (i < 229376)   v = actp_w[i - 212992];
        else if (i < 245760)   v = inp_w[i - 229376];
        else                   v = outp_w[i - 245760];
        dst[i] = f2b(v);
    } else {
        int j = i - 262144;
        if (j < 640) qb_r[j] = qkv_b[5 * (j & 127) + (j >> 7)];
        else if (j < 1792) {
            int idx = j - 640; int k = idx >> 7, c = idx & 127;
            wsT[idx] = eaax_w[c * 9 + k] + eaay_w[c * 9 + k];
        } else if (j < 1920) bsum[j - 1792] = eaax_b[j - 1792] + eaay_b[j - 1792];
        else if (j < 3072) {
            int idx = j - 1920; int k = idx >> 7, c = idx & 127;
            cpe1T[idx] = cpe1_w[c * 9 + k];
        } else if (j < 4224) {
            int idx = j - 3072; int k = idx >> 7, c = idx & 127;
            dwcT[idx] = dwc_w[c * 9 + k];
        } else {
            int idx = j - 4224; int k = idx >> 7, c = idx & 127;
            cpe2T[idx] = cpe2_w[c * 9 + k];
        }
    }
}

// ---------------- per-(b,c) mean over HW (x is NCHW input) ----------------
__global__ __launch_bounds__(256) void mean_bc_kernel(const float* __restrict__ x,
                                                      float* __restrict__ mean) {
    __shared__ float sb[4];
    int bc = blockIdx.x;
    const float* p = x + (size_t)bc * NPIX;
    float s = 0.f;
    for (int i = threadIdx.x; i < NPIX; i += 256) s += p[i];
#pragma unroll
    for (int off = 32; off > 0; off >>= 1) s += __shfl_down(s, off, 64);
    if ((threadIdx.x & 63) == 0) sb[threadIdx.x >> 6] = s;
    __syncthreads();
    if (threadIdx.x == 0) mean[bc] = (sb[0] + sb[1] + sb[2] + sb[3]) * (1.f / (float)NPIX);
}

// ---------------- ECA gate ----------------
__global__ void eca_gate_kernel(const float* __restrict__ mean, const float* __restrict__ w5,
                                float* __restrict__ gate) {
    int b = blockIdx.x, c = threadIdx.x;
    float s = 0.f;
#pragma unroll
    for (int k = 0; k < 5; ++k) {
        int cc = c + k - 2;
        if (cc >= 0 && cc < CDIM) s += w5[k] * mean[b * CDIM + cc];
    }
    gate[b * CDIM + c] = sigmoidf_(s);
}

// ---------------- ESA+ECA fused with NCHW->NHWC transpose: y = x*(gate+s) ----------------
__global__ __launch_bounds__(256) void esa_tr_kernel(const float* __restrict__ x,
                                                     const float* __restrict__ mean,
                                                     const float* __restrict__ gate,
                                                     const float* __restrict__ alpha_p,
                                                     float* __restrict__ y) {
    __shared__ float tile[128][65];
    __shared__ float smx[4][64], smn[4][64], ssc[64];
    int b = blockIdx.y, p0 = blockIdx.x * 64;
    int tx = threadIdx.x, pl = tx & 63, part = tx >> 6;
    const float* xb = x + (size_t)b * CDIM * NPIX;
    const float* mb = mean + b * CDIM;
    for (int c = part; c < CDIM; c += 4)
        tile[c][pl] = xb[(size_t)c * NPIX + p0 + pl];
    __syncthreads();
    float mx = -1e30f, mn = 1e30f;
#pragma unroll
    for (int cc = 0; cc < 32; ++cc) {
        int c = part * 32 + cc;
        float v = tile[c][pl] - mb[c];
        mx = fmaxf(mx, v); mn = fminf(mn, v);
    }
    smx[part][pl] = mx; smn[part][pl] = mn;
    __syncthreads();
    if (part == 0) {
        float m1 = fmaxf(fmaxf(smx[0][pl], smx[1][pl]), fmaxf(smx[2][pl], smx[3][pl]));
        float m2 = fminf(fminf(smn[0][pl], smn[1][pl]), fminf(smn[2][pl], smn[3][pl]));
        float a = alpha_p[0];
        ssc[pl] = sigmoidf_(m1) * a + sigmoidf_(m2) * (1.f - a);
    }
    __syncthreads();
    const float* gb = gate + b * CDIM;
    int c2 = tx & 127, pr = tx >> 7;
    float* yb = y + ((size_t)b * NPIX + p0) * CDIM;
    float gv = gb[c2];
    for (int p = pr; p < 64; p += 2)
        yb[(size_t)p * CDIM + c2] = tile[c2][p] * (gv + ssc[p]);
}

// ---------------- NHWC f32 dwconv3 + residual + fused PER-BATCH GN stats ----------------
// out = in + conv(in); stats[b*2] += sum, stats[b*2+1] += sumsq   (b = blockIdx.y)
__global__ __launch_bounds__(256) void cpe_f32_kernel(const float* __restrict__ in,
                                                      const float* __restrict__ wT,
                                                      const float* __restrict__ bias,
                                                      float* __restrict__ out,
                                                      float* __restrict__ stats) {
    __shared__ float sb[8];
    int b = blockIdx.y, tx = threadIdx.x;
    int cg = tx & 15, pp = tx >> 4;
    int p = blockIdx.x * 16 + pp;
    int xx = p & 63, yy = p >> 6;
    int c0 = cg * 8;
    float acc[8], ctr[8];
#pragma unroll
    for (int j = 0; j < 8; ++j) acc[j] = bias[c0 + j];
#pragma unroll
    for (int dy = -1; dy <= 1; ++dy) {
        int y2 = yy + dy;
        if (y2 < 0 || y2 >= 64) continue;
#pragma unroll
        for (int dx = -1; dx <= 1; ++dx) {
            int x2 = xx + dx;
            if (x2 < 0 || x2 >= 64) continue;
            const float* ip = &in[((size_t)b * NPIX + y2 * 64 + x2) * 128 + c0];
            float4 v0 = *(const float4*)ip;
            float4 v1 = *(const float4*)(ip + 4);
            const float* wr = wT + ((dy + 1) * 3 + dx + 1) * 128 + c0;
            acc[0] += v0.x * wr[0]; acc[1] += v0.y * wr[1];
            acc[2] += v0.z * wr[2]; acc[3] += v0.w * wr[3];
            acc[4] += v1.x * wr[4]; acc[5] += v1.y * wr[5];
            acc[6] += v1.z * wr[6]; acc[7] += v1.w * wr[7];
            if (dy == 0 && dx == 0) {
                ctr[0] = v0.x; ctr[1] = v0.y; ctr[2] = v0.z; ctr[3] = v0.w;
                ctr[4] = v1.x; ctr[5] = v1.y; ctr[6] = v1.z; ctr[7] = v1.w;
            }
        }
    }
    float s = 0.f, s2 = 0.f;
    float r[8];
#pragma unroll
    for (int j = 0; j < 8; ++j) {
        r[j] = ctr[j] + acc[j];
        s += r[j]; s2 += r[j] * r[j];
    }
    float* op = &out[((size_t)b * NPIX + p) * 128 + c0];
    *(float4*)op = make_float4(r[0], r[1], r[2], r[3]);
    *(float4*)(op + 4) = make_float4(r[4], r[5], r[6], r[7]);
#pragma unroll
    for (int off = 32; off > 0; off >>= 1) {
        s += __shfl_down(s, off, 64);
        s2 += __shfl_down(s2, off, 64);
    }
    int wv = tx >> 6;
    if ((tx & 63) == 0) { sb[wv] = s; sb[4 + wv] = s2; }
    __syncthreads();
    if (tx == 0) {
        atomicAdd(&stats[b * 2], sb[0] + sb[1] + sb[2] + sb[3]);
        atomicAdd(&stats[b * 2 + 1], sb[4] + sb[5] + sb[6] + sb[7]);
    }
}

// ---------------- GN apply (elementwise, NHWC f32 -> NHWC bf16), PER-BATCH stats ----------------
__global__ __launch_bounds__(256) void gn_apply_kernel(const float* __restrict__ in,
                                                       const float* __restrict__ stats,
                                                       const float* __restrict__ g,
                                                       const float* __restrict__ bta,
                                                       unsigned short* __restrict__ dst) {
    int b = blockIdx.y;
    int i = blockIdx.x * 256 + threadIdx.x;   // 0..65535
    const float n = 1.f / (float)(CDIM * NPIX);
    float mu = stats[b * 2] * n;
    float var = stats[b * 2 + 1] * n - mu * mu;
    float rr = rsqrtf(var + EPSN);
    int c0 = (i & 15) * 8;
    size_t idx = (size_t)b * (NPIX * 128) + (size_t)i * 8;
    float4 v0 = *(const float4*)&in[idx];
    float4 v1 = *(const float4*)&in[idx + 4];
    unsigned short o[8];
    o[0] = f2b((v0.x - mu) * rr * g[c0 + 0] + bta[c0 + 0]);
    o[1] = f2b((v0.y - mu) * rr * g[c0 + 1] + bta[c0 + 1]);
    o[2] = f2b((v0.z - mu) * rr * g[c0 + 2] + bta[c0 + 2]);
    o[3] = f2b((v0.w - mu) * rr * g[c0 + 3] + bta[c0 + 3]);
    o[4] = f2b((v1.x - mu) * rr * g[c0 + 4] + bta[c0 + 4]);
    o[5] = f2b((v1.y - mu) * rr * g[c0 + 5] + bta[c0 + 5]);
    o[6] = f2b((v1.z - mu) * rr * g[c0 + 6] + bta[c0 + 6]);
    o[7] = f2b((v1.w - mu) * rr * g[c0 + 7] + bta[c0 + 7]);
    *(uint4*)&dst[idx] = *(uint4*)o;
}

// ---------------- NHWC bf16 dwconv3 + bias + relu -> bf16 ----------------
__global__ __launch_bounds__(256) void dwc_bf16_kernel(const unsigned short* __restrict__ in,
                                                       const float* __restrict__ wT,
                                                       const float* __restrict__ bias,
                                                       unsigned short* __restrict__ out) {
    int b = blockIdx.y, tx = threadIdx.x;
    int cg = tx & 15, pp = tx >> 4;
    int p = blockIdx.x * 16 + pp;
    int xx = p & 63, yy = p >> 6;
    int c0 = cg * 8;
    float acc[8];
#pragma unroll
    for (int j = 0; j < 8; ++j) acc[j] = bias[c0 + j];
#pragma unroll
    for (int dy = -1; dy <= 1; ++dy) {
        int y2 = yy + dy;
        if (y2 < 0 || y2 >= 64) continue;
#pragma unroll
        for (int dx = -1; dx <= 1; ++dx) {
            int x2 = xx + dx;
            if (x2 < 0 || x2 >= 64) continue;
            unsigned short v[8];
            *(uint4*)v = *(const uint4*)&in[((size_t)b * NPIX + y2 * 64 + x2) * 128 + c0];
            const float* wr = wT + ((dy + 1) * 3 + dx + 1) * 128 + c0;
#pragma unroll
            for (int j = 0; j < 8; ++j) acc[j] += b2f(v[j]) * wr[j];
        }
    }
    unsigned short o[8];
#pragma unroll
    for (int j = 0; j < 8; ++j) o[j] = f2b(fmaxf(acc[j], 0.f));
    *(uint4*)&out[((size_t)b * NPIX + p) * 128 + c0] = *(uint4*)o;
}

// ---------------- conv1x1 via bf16 MFMA ----------------
// epilogues: out_t (bf16 NHWC) | out+nchw=0 (f32 NHWC, res f32 NHWC) | out+nchw=1 (f32 NCHW, res f32 NHWC)
__global__ __launch_bounds__(256) void conv_mfma_kernel(const unsigned short* __restrict__ in_t,
                                                        const unsigned short* __restrict__ w,
                                                        const float* __restrict__ bias,
                                                        const float* __restrict__ res,
                                                        float* __restrict__ out,
                                                        unsigned short* __restrict__ out_t,
                                                        int Cin, int Cout, int relu, int nchw) {
    __shared__ __align__(16) unsigned short A_s[128][136];
    __shared__ __align__(16) unsigned short B_s[128][136];
    int b = blockIdx.z, p0 = blockIdx.x * 128, o0 = blockIdx.y * 128;
    int tx = threadIdx.x;
    int wave = tx >> 6, lane = tx & 63;
    int wm = wave & 1, wn = wave >> 1;
    int quad = lane >> 4, l16 = lane & 15;

    f32x4 acc[4][4];
#pragma unroll
    for (int mt = 0; mt < 4; ++mt) {
#pragma unroll
        for (int r = 0; r < 4; ++r) {
            float bv = bias[o0 + wm * 64 + mt * 16 + quad * 4 + r];
#pragma unroll
            for (int nt = 0; nt < 4; ++nt) acc[mt][nt][r] = bv;
        }
    }

    for (int k0 = 0; k0 < Cin; k0 += 128) {
#pragma unroll
        for (int j = 0; j < 8; ++j) {
            int idx = tx + 256 * j;
            int row = idx >> 4, c16 = idx & 15;
            *(uint4*)&A_s[row][c16 * 8] =
                *(const uint4*)&w[(size_t)(o0 + row) * Cin + k0 + c16 * 8];
            *(uint4*)&B_s[row][c16 * 8] =
                *(const uint4*)&in_t[((size_t)b * NPIX + p0 + row) * Cin + k0 + c16 * 8];
        }
        __syncthreads();
#pragma unroll
        for (int ks = 0; ks < 128; ks += 32) {
            short8 af[4], bf[4];
#pragma unroll
            for (int mt = 0; mt < 4; ++mt)
                af[mt] = *(const short8*)&A_s[wm * 64 + mt * 16 + l16][ks + quad * 8];
#pragma unroll
            for (int nt = 0; nt < 4; ++nt)
                bf[nt] = *(const short8*)&B_s[wn * 64 + nt * 16 + l16][ks + quad * 8];
#pragma unroll
            for (int mt = 0; mt < 4; ++mt)
#pragma unroll
                for (int nt = 0; nt < 4; ++nt)
                    acc[mt][nt] = __builtin_amdgcn_mfma_f32_16x16x32_bf16(
                        af[mt], bf[nt], acc[mt][nt], 0, 0, 0);
        }
        __syncthreads();
    }

    if (out_t) {
#pragma unroll
        for (int mt = 0; mt < 4; ++mt) {
#pragma unroll
            for (int nt = 0; nt < 4; ++nt) {
                int p = p0 + wn * 64 + nt * 16 + l16;
                int ob = o0 + wm * 64 + mt * 16 + quad * 4;
                ushort4 u;
                float v0 = acc[mt][nt][0], v1 = acc[mt][nt][1];
                float v2 = acc[mt][nt][2], v3 = acc[mt][nt][3];
                if (relu) { v0 = fmaxf(v0, 0.f); v1 = fmaxf(v1, 0.f);
                            v2 = fmaxf(v2, 0.f); v3 = fmaxf(v3, 0.f); }
                u.x = f2b(v0); u.y = f2b(v1); u.z = f2b(v2); u.w = f2b(v3);
                *(ushort4*)&out_t[((size_t)b * NPIX + p) * Cout + ob] = u;
            }
        }
    } else if (!nchw) {
#pragma unroll
        for (int mt = 0; mt < 4; ++mt) {
#pragma unroll
            for (int nt = 0; nt < 4; ++nt) {
                int p = p0 + wn * 64 + nt * 16 + l16;
                int ob = o0 + wm * 64 + mt * 16 + quad * 4;
                size_t ix = ((size_t)b * NPIX + p) * Cout + ob;
                float4 v = make_float4(acc[mt][nt][0], acc[mt][nt][1],
                                       acc[mt][nt][2], acc[mt][nt][3]);
                if (relu) { v.x = fmaxf(v.x, 0.f); v.y = fmaxf(v.y, 0.f);
                            v.z = fmaxf(v.z, 0.f); v.w = fmaxf(v.w, 0.f); }
                if (res) {
                    float4 rv = *(const float4*)&res[ix];
                    v.x += rv.x; v.y += rv.y; v.z += rv.z; v.w += rv.w;
                }
                *(float4*)&out[ix] = v;
            }
        }
    } else {
        float* outb = out + (size_t)b * Cout * NPIX;
#pragma unroll
        for (int mt = 0; mt < 4; ++mt) {
#pragma unroll
            for (int nt = 0; nt < 4; ++nt) {
                int p = p0 + wn * 64 + nt * 16 + l16;
                int ob = o0 + wm * 64 + mt * 16 + quad * 4;
                float4 rv = make_float4(0.f, 0.f, 0.f, 0.f);
                if (res) rv = *(const float4*)&res[((size_t)b * NPIX + p) * 128 + ob];
#pragma unroll
                for (int r = 0; r < 4; ++r) {
                    float v = acc[mt][nt][r];
                    if (relu) v = fmaxf(v, 0.f);
                    v += (r == 0 ? rv.x : r == 1 ? rv.y : r == 2 ? rv.z : rv.w);
                    outb[(size_t)(ob + r) * NPIX + p] = v;
                }
            }
        }
    }
}

// ---------------- MFMA window attention, both orientations in one launch ----------------
// t_t: bf16 NHWC 640ch grouped [q0|k0|v0|q1|k1]; blockIdx.z = b*2+which.
__global__ __launch_bounds__(256) void attn_dual_kernel(const unsigned short* __restrict__ t_t,
                                                        float* __restrict__ a0,
                                                        float* __restrict__ a1) {
    __shared__ __align__(16) unsigned short Vt[16][264];
    int wi = blockIdx.x, head = blockIdx.y;
    int z = blockIdx.z;
    int b = z >> 1, which = z & 1;
    int qoff = which ? 384 : 0;
    int koff = which ? 512 : 128;
    int mode = which;
    float* a_out = which ? a1 : a0;
    int tx = threadIdx.x;
    int wave = tx >> 6, l = tx & 63;
    int l32 = l & 31, half = l >> 5;
    const size_t base = (size_t)b * NPIX;
    const int hc = head * 16;

    // stage V transposed (16 d x 256 tokens); thread tx handles token tx
    {
        int p = tok2pix(mode, wi, tx);
        const unsigned short* vp = &t_t[(base + p) * 640 + 256 + hc];
        unsigned short tmp[16];
        *(uint4*)&tmp[0] = *(const uint4*)vp;
        *(uint4*)&tmp[8] = *(const uint4*)(vp + 8);
#pragma unroll
        for (int d = 0; d < 16; ++d) Vt[d][tx] = tmp[d];
    }
    __syncthreads();

    for (int qi = 0; qi < 2; ++qi) {
        int qs = qi * 4 + wave;  // query strip 0..7
        int qp = tok2pix(mode, wi, qs * 32 + l32);
        short8 qf = *(const short8*)&t_t[(base + qp) * 640 + qoff + hc + half * 8];
        f32x16 o_acc;
#pragma unroll
        for (int r = 0; r < 16; ++r) o_acc[r] = 0.f;
        float rs = 0.f;
#pragma unroll
        for (int nt = 0; nt < 8; ++nt) {
            int kp = tok2pix(mode, wi, nt * 32 + l32);
            short8 kf = *(const short8*)&t_t[(base + kp) * 640 + koff + hc + half * 8];
            f32x16 zz;
#pragma unroll
            for (int r = 0; r < 16; ++r) zz[r] = 0.f;
            // S^T strip: D[t][m], lane col m=l32, rows t=(r&3)+8*(r>>2)+4*half
            f32x16 s = __builtin_amdgcn_mfma_f32_32x32x16_bf16(kf, qf, zz, 0, 0, 0);
            unsigned int pk[8];
#pragma unroll
            for (int i = 0; i < 8; ++i) {
                float e0 = __expf(s[2 * i]);
                float e1 = __expf(s[2 * i + 1]);
                rs += e0 + e1;
                pk[i] = __builtin_amdgcn_perm(__float_as_uint(e1), __float_as_uint(e0),
                                              0x07060302u);
            }
            unsigned int xpk[8];
#pragma unroll
            for (int i = 0; i < 8; ++i)
                xpk[i] = (unsigned int)__shfl_xor((int)pk[i], 32, 64);
            unsigned int u0[4], u1[4];
            if (half == 0) {
                u0[0] = pk[0]; u0[1] = pk[1]; u0[2] = xpk[0]; u0[3] = xpk[1];
                u1[0] = pk[4]; u1[1] = pk[5]; u1[2] = xpk[4]; u1[3] = xpk[5];
            } else {
                u0[0] = xpk[2]; u0[1] = xpk[3]; u0[2] = pk[2]; u0[3] = pk[3];
                u1[0] = xpk[6]; u1[1] = xpk[7]; u1[2] = pk[6]; u1[3] = pk[7];
            }
            short8 vf0, vf1;
#pragma unroll
            for (int r = 0; r < 8; ++r) { vf0[r] = 0; vf1[r] = 0; }
            if (l32 < 16) {
                vf0 = *(const short8*)&Vt[l32][nt * 32 + half * 8];
                vf1 = *(const short8*)&Vt[l32][nt * 32 + 16 + half * 8];
            }
            o_acc = __builtin_amdgcn_mfma_f32_32x32x16_bf16(vf0, *(short8*)u0, o_acc, 0, 0, 0);
            o_acc = __builtin_amdgcn_mfma_f32_32x32x16_bf16(vf1, *(short8*)u1, o_acc, 0, 0, 0);
        }
        rs += __shfl_xor(rs, 32, 64);
        float rinv = 1.f / rs;
        float* dst = a_out + (base + qp) * 128 + hc;
#pragma unroll
        for (int r = 0; r < 8; ++r) {
            int d = (r & 3) + 8 * (r >> 2) + 4 * half;
            dst[d] = o_acc[r] * rinv;
        }
    }
}

// ---------------- combined cpe dwconv on v0 (stride-640 bf16 in, accumulate f32 NHWC) ----------------
__global__ __launch_bounds__(256) void cpe_nhwc_kernel(const unsigned short* __restrict__ t_t,
                                                       const float* __restrict__ wT,
                                                       const float* __restrict__ bsum,
                                                       float* __restrict__ a_out) {
    int b = blockIdx.y;
    int tx = threadIdx.x;
    int cg = tx & 15, pp = tx >> 4;
    int p = blockIdx.x * 16 + pp;
    int xx = p & 63, yy = p >> 6;
    int c0 = cg * 8;
    float acc[8];
#pragma unroll
    for (int j = 0; j < 8; ++j) acc[j] = bsum[c0 + j];
#pragma unroll
    for (int dy = -1; dy <= 1; ++dy) {
        int y2 = yy + dy;
        if (y2 < 0 || y2 >= 64) continue;
#pragma unroll
        for (int dx = -1; dx <= 1; ++dx) {
            int x2 = xx + dx;
            if (x2 < 0 || x2 >= 64) continue;
            int pn = y2 * 64 + x2;
            unsigned short v[8];
            *(uint4*)v = *(const uint4*)&t_t[((size_t)b * NPIX + pn) * 640 + 256 + c0];
            const float* wr = wT + ((dy + 1) * 3 + dx + 1) * 128 + c0;
#pragma unroll
            for (int j = 0; j < 8; ++j) acc[j] += b2f(v[j]) * wr[j];
        }
    }
    float* dst = a_out + ((size_t)b * NPIX + p) * 128 + c0;
#pragma unroll
    for (int j = 0; j < 8; ++j) dst[j] += acc[j];
}

// ---------------- m_t = bf16((a0+a1) * act_res)  (all NHWC) ----------------
__global__ __launch_bounds__(256) void mul3_kernel(const float* __restrict__ a0,
                                                   const float* __restrict__ a1,
                                                   const unsigned short* __restrict__ act,
                                                   unsigned short* __restrict__ dst) {
    size_t i = ((size_t)blockIdx.x * 256 + threadIdx.x) * 8;
    float4 x0 = *(const float4*)&a0[i];
    float4 x1 = *(const float4*)&a0[i + 4];
    float4 y0 = *(const float4*)&a1[i];
    float4 y1 = *(const float4*)&a1[i + 4];
    unsigned short t[8];
    *(uint4*)t = *(const uint4*)&act[i];
    unsigned short r[8];
    r[0] = f2b((x0.x + y0.x) * b2f(t[0])); r[1] = f2b((x0.y + y0.y) * b2f(t[1]));
    r[2] = f2b((x0.z + y0.z) * b2f(t[2])); r[3] = f2b((x0.w + y0.w) * b2f(t[3]));
    r[4] = f2b((x1.x + y1.x) * b2f(t[4])); r[5] = f2b((x1.y + y1.y) * b2f(t[5]));
    r[6] = f2b((x1.z + y1.z) * b2f(t[6])); r[7] = f2b((x1.w + y1.w) * b2f(t[7]));
    *(uint4*)&dst[i] = *(uint4*)r;
}

extern "C" void kernel_launch(void* const* d_in, const int* in_sizes, int n_in,
                              void* d_out, int out_size, void* d_ws, size_t ws_size,
                              hipStream_t stream) {
    const float* x       = (const float*)d_in[0];
    const float* eca_w   = (const float*)d_in[1];
    const float* esa_al  = (const float*)d_in[2];
    const float* cpe1_w  = (const float*)d_in[3];  const float* cpe1_b = (const float*)d_in[4];
    const float* g1      = (const float*)d_in[5];  const float* b1     = (const float*)d_in[6];
    const float* actp_w  = (const float*)d_in[7];  const float* actp_b = (const float*)d_in[8];
    const float* inp_w   = (const float*)d_in[9];  const float* inp_b  = (const float*)d_in[10];
    const float* dwc_w   = (const float*)d_in[11]; const float* dwc_b  = (const float*)d_in[12];
    const float* qkv_w   = (const float*)d_in[13]; const float* qkv_b  = (const float*)d_in[14];
    const float* eaax_w  = (const float*)d_in[15]; const float* eaax_b = (const float*)d_in[16];
    const float* eaay_w  = (const float*)d_in[17]; const float* eaay_b = (const float*)d_in[18];
    const float* outp_w  = (const float*)d_in[19]; const float* outp_b = (const float*)d_in[20];
    const float* cpe2_w  = (const float*)d_in[21]; const float* cpe2_b = (const float*)d_in[22];
    const float* g2      = (const float*)d_in[23]; const float* b2     = (const float*)d_in[24];
    const float* mlp1_w  = (const float*)d_in[25]; const float* mlp1_b = (const float*)d_in[26];
    const float* mlp2_w  = (const float*)d_in[27]; const float* mlp2_b = (const float*)d_in[28];

    float* ws = (float*)d_ws;
    unsigned short* U = (unsigned short*)d_ws;
    const size_t E = (size_t)BATCH * CDIM * NPIX;  // 4,194,304

    float* y_nhwc  = ws;               // [0,E)  esa out; later a0
    float* a0      = ws;               // reuse after y dead
    float* sc_nhwc = ws + E;           // [E,2E) shortcut (live to outp)
    unsigned short* xn_t  = U + 4 * E; // [2E,2.5E) f32-equiv
    unsigned short* act_t = U + 5 * E; // [2.5E,3E)
    unsigned short* it_t  = U + 6 * E; // [3E,3.5E)
    unsigned short* tin_t = U + 7 * E; // [3.5E,4E)
    float* a1      = ws + 4 * E;       // [4E,5E)
    unsigned short* t_t   = U + 10 * E; // [5E,7.5E)
    unsigned short* m_t   = U + 15 * E; // [7.5E,8E)
    float* out_nhwc = ws + 8 * E;      // [8E,9E)
    float* out2    = ws + 2 * E;       // [2E,3E)  (xn_t/act_t dead by then)
    unsigned short* g2_t  = U + 6 * E; // [3E,3.5E) (it_t dead)
    unsigned short* hid_t = U + 10 * E; // [5E,7E) (t_t dead)
    unsigned short* wpool = U + 20 * E; // 262144 bf16
    unsigned short* wq  = wpool;
    unsigned short* wm1 = wpool + 81920;
    unsigned short* wm2 = wpool + 147456;
    unsigned short* wa  = wpool + 212992;
    unsigned short* wi_ = wpool + 229376;
    unsigned short* wo  = wpool + 245760;
    float* fb     = ws + 10 * E + 131072;
    float* meanb  = fb;            // 1024
    float* gateb  = fb + 1024;     // 1024
    float* gstats = fb + 2048;     // 32 (gn1: [0,16), gn2: [16,32))
    float* qb_r   = fb + 2080;     // 640
    float* wsT    = fb + 2720;     // 1152
    float* bsum   = fb + 3872;     // 128
    float* cpe1T  = fb + 4000;     // 1152
    float* dwcT   = fb + 5152;     // 1152
    float* cpe2T  = fb + 6304;     // 1152

    hipMemsetAsync(gstats, 0, 32 * sizeof(float), stream);
    convert_w_kernel<<<1045, 256, 0, stream>>>(qkv_w, mlp1_w, mlp2_w, actp_w, inp_w, outp_w,
                                               qkv_b, eaax_w, eaax_b, eaay_w, eaay_b,
                                               cpe1_w, dwc_w, cpe2_w,
                                               wpool, qb_r, wsT, bsum, cpe1T, dwcT, cpe2T);

    // 1) ECA + ESA fused with transpose -> y (f32 NHWC)
    mean_bc_kernel<<<BATCH * CDIM, 256, 0, stream>>>(x, meanb);
    eca_gate_kernel<<<BATCH, CDIM, 0, stream>>>(meanb, eca_w, gateb);
    esa_tr_kernel<<<dim3(64, BATCH), 256, 0, stream>>>(x, meanb, gateb, esa_al, y_nhwc);
    // 2) shortcut = y + cpe1(y), fused per-batch GN1 stats
    cpe_f32_kernel<<<dim3(256, BATCH), 256, 0, stream>>>(y_nhwc, cpe1T, cpe1_b, sc_nhwc, gstats);
    // 3) GN1 apply -> xn_t (bf16 NHWC)
    gn_apply_kernel<<<dim3(256, BATCH), 256, 0, stream>>>(sc_nhwc, gstats, g1, b1, xn_t);
    // 4) act_res = relu(actp(xn)) -> act_t
    conv_mfma_kernel<<<dim3(32, 1, BATCH), 256, 0, stream>>>(xn_t, wa, actp_b, nullptr, nullptr,
                                                             act_t, 128, 128, 1, 0);
    // 5) t = relu(dwc(inp(xn)))  xn_t -> it_t -> tin_t  (all bf16 NHWC)
    conv_mfma_kernel<<<dim3(32, 1, BATCH), 256, 0, stream>>>(xn_t, wi_, inp_b, nullptr, nullptr,
                                                             it_t, 128, 128, 0, 0);
    dwc_bf16_kernel<<<dim3(256, BATCH), 256, 0, stream>>>(it_t, dwcT, dwc_b, tin_t);
    // 6) qkv -> t_t (bf16 NHWC, 640 grouped)
    conv_mfma_kernel<<<dim3(32, 5, BATCH), 256, 0, stream>>>(tin_t, wq, qb_r, nullptr, nullptr,
                                                             t_t, 128, 640, 0, 0);
    // 7) both attentions in one launch -> a0, a1 ; cpe(v0) accumulates into a1
    attn_dual_kernel<<<dim3(16, 8, 2 * BATCH), 256, 0, stream>>>(t_t, a0, a1);
    cpe_nhwc_kernel<<<dim3(256, BATCH), 256, 0, stream>>>(t_t, wsT, bsum, a1);
    // 8) m_t = bf16((a0+a1)*act_res) ; out = outp(m) + shortcut -> out_nhwc (f32 NHWC)
    mul3_kernel<<<2048, 256, 0, stream>>>(a0, a1, act_t, m_t);
    conv_mfma_kernel<<<dim3(32, 1, BATCH), 256, 0, stream>>>(m_t, wo, outp_b, sc_nhwc, out_nhwc,
                                                             nullptr, 128, 128, 0, 0);
    // 9) out2 = out + cpe2(out), fused per-batch GN2 stats
    cpe_f32_kernel<<<dim3(256, BATCH), 256, 0, stream>>>(out_nhwc, cpe2T, cpe2_b, out2,
                                                         gstats + 16);
    // 10) GN2 apply -> g2_t
    gn_apply_kernel<<<dim3(256, BATCH), 256, 0, stream>>>(out2, gstats + 16, g2, b2, g2_t);
    // 11) mlp
    conv_mfma_kernel<<<dim3(32, 4, BATCH), 256, 0, stream>>>(g2_t, wm1, mlp1_b, nullptr, nullptr,
                                                             hid_t, 128, 512, 1, 0);
    conv_mfma_kernel<<<dim3(32, 1, BATCH), 256, 0, stream>>>(hid_t, wm2, mlp2_b, out2,
                                                             (float*)d_out, nullptr, 512, 128, 0, 1);
}

// Round 8
// 329.442 us; speedup vs baseline: 3.9337x; 1.2796x over previous
//
#include <hip/hip_runtime.h>

#define NPIX 4096
#define CDIM 128
#define BATCH 8
#define EPSN 1e-5f

typedef __attribute__((ext_vector_type(8))) short short8;
typedef __attribute__((ext_vector_type(4))) float f32x4;
typedef __attribute__((ext_vector_type(16))) float f32x16;

__device__ __forceinline__ float sigmoidf_(float x) { return 1.f / (1.f + __expf(-x)); }

__device__ __forceinline__ unsigned short f2b(float f) {
    unsigned int u = __float_as_uint(f);
    unsigned int r = (u + 0x7FFF + ((u >> 16) & 1)) >> 16;  // RNE
    return (unsigned short)r;
}
__device__ __forceinline__ float b2f(unsigned short u) {
    return __uint_as_float((unsigned int)u << 16);
}

// window token -> pixel index
__device__ __forceinline__ int tok2pix(int mode, int wi, int l) {
    return (mode == 0) ? ((l >> 2) * 64 + wi * 4 + (l & 3))
                       : ((wi * 4 + (l >> 6)) * 64 + (l & 63));
}

// ---------------- weight conversion / reorder / transposes ----------------
__global__ __launch_bounds__(256) void convert_w_kernel(const float* __restrict__ qkv_w,
                                                        const float* __restrict__ mlp1_w,
                                                        const float* __restrict__ mlp2_w,
                                                        const float* __restrict__ actp_w,
                                                        const float* __restrict__ inp_w,
                                                        const float* __restrict__ outp_w,
                                                        const float* __restrict__ qkv_b,
                                                        const float* __restrict__ eaax_w,
                                                        const float* __restrict__ eaax_b,
                                                        const float* __restrict__ eaay_w,
                                                        const float* __restrict__ eaay_b,
                                                        const float* __restrict__ cpe1_w,
                                                        const float* __restrict__ dwc_w,
                                                        const float* __restrict__ cpe2_w,
                                                        unsigned short* __restrict__ dst,
                                                        float* __restrict__ qb_r,
                                                        float* __restrict__ wsT,
                                                        float* __restrict__ bsum,
                                                        float* __restrict__ cpe1T,
                                                        float* __restrict__ dwcT,
                                                        float* __restrict__ cpe2T) {
    int i = blockIdx.x * 256 + threadIdx.x;
    if (i >= 267520) return;
    if (i < 262144) {
        float v;
        if (i < 81920) {
            int o = i >> 7, c = i & 127;              // reordered: o_new = g*128+cc
            v = qkv_w[(size_t)(5 * (o & 127) + (o >> 7)) * 128 + c];
        } else if (i < 147456) v = mlp1_w[i - 81920];
        else if (i < 212992)   v = mlp2_w[i - 147456];
        else if (i < 229376)   v = actp_w[i - 212992];
        else if (i < 245760)   v = inp_w[i - 229376];
        else                   v = outp_w[i - 245760];
        dst[i] = f2b(v);
    } else {
        int j = i - 262144;
        if (j < 640) qb_r[j] = qkv_b[5 * (j & 127) + (j >> 7)];
        else if (j < 1792) {
            int idx = j - 640; int k = idx >> 7, c = idx & 127;
            wsT[idx] = eaax_w[c * 9 + k] + eaay_w[c * 9 + k];
        } else if (j < 1920) bsum[j - 1792] = eaax_b[j - 1792] + eaay_b[j - 1792];
        else if (j < 3072) {
            int idx = j - 1920; int k = idx >> 7, c = idx & 127;
            cpe1T[idx] = cpe1_w[c * 9 + k];
        } else if (j < 4224) {
            int idx = j - 3072; int k = idx >> 7, c = idx & 127;
            dwcT[idx] = dwc_w[c * 9 + k];
        } else {
            int idx = j - 4224; int k = idx >> 7, c = idx & 127;
            cpe2T[idx] = cpe2_w[c * 9 + k];
        }
    }
}

// ---------------- per-(b,c) mean over HW (x is NCHW input) ----------------
__global__ __launch_bounds__(256) void mean_bc_kernel(const float* __restrict__ x,
                                                      float* __restrict__ mean) {
    __shared__ float sb[4];
    int bc = blockIdx.x;
    const float* p = x + (size_t)bc * NPIX;
    float s = 0.f;
    for (int i = threadIdx.x; i < NPIX; i += 256) s += p[i];
#pragma unroll
    for (int off = 32; off > 0; off >>= 1) s += __shfl_down(s, off, 64);
    if ((threadIdx.x & 63) == 0) sb[threadIdx.x >> 6] = s;
    __syncthreads();
    if (threadIdx.x == 0) mean[bc] = (sb[0] + sb[1] + sb[2] + sb[3]) * (1.f / (float)NPIX);
}

// ---------------- ECA gate ----------------
__global__ void eca_gate_kernel(const float* __restrict__ mean, const float* __restrict__ w5,
                                float* __restrict__ gate) {
    int b = blockIdx.x, c = threadIdx.x;
    float s = 0.f;
#pragma unroll
    for (int k = 0; k < 5; ++k) {
        int cc = c + k - 2;
        if (cc >= 0 && cc < CDIM) s += w5[k] * mean[b * CDIM + cc];
    }
    gate[b * CDIM + c] = sigmoidf_(s);
}

// ---------------- ESA+ECA fused with NCHW->NHWC transpose: y = x*(gate+s) ----------------
__global__ __launch_bounds__(256) void esa_tr_kernel(const float* __restrict__ x,
                                                     const float* __restrict__ mean,
                                                     const float* __restrict__ gate,
                                                     const float* __restrict__ alpha_p,
                                                     float* __restrict__ y) {
    __shared__ float tile[128][65];
    __shared__ float smx[4][64], smn[4][64], ssc[64];
    int b = blockIdx.y, p0 = blockIdx.x * 64;
    int tx = threadIdx.x, pl = tx & 63, part = tx >> 6;
    const float* xb = x + (size_t)b * CDIM * NPIX;
    const float* mb = mean + b * CDIM;
    for (int c = part; c < CDIM; c += 4)
        tile[c][pl] = xb[(size_t)c * NPIX + p0 + pl];
    __syncthreads();
    float mx = -1e30f, mn = 1e30f;
#pragma unroll
    for (int cc = 0; cc < 32; ++cc) {
        int c = part * 32 + cc;
        float v = tile[c][pl] - mb[c];
        mx = fmaxf(mx, v); mn = fminf(mn, v);
    }
    smx[part][pl] = mx; smn[part][pl] = mn;
    __syncthreads();
    if (part == 0) {
        float m1 = fmaxf(fmaxf(smx[0][pl], smx[1][pl]), fmaxf(smx[2][pl], smx[3][pl]));
        float m2 = fminf(fminf(smn[0][pl], smn[1][pl]), fminf(smn[2][pl], smn[3][pl]));
        float a = alpha_p[0];
        ssc[pl] = sigmoidf_(m1) * a + sigmoidf_(m2) * (1.f - a);
    }
    __syncthreads();
    const float* gb = gate + b * CDIM;
    int c2 = tx & 127, pr = tx >> 7;
    float* yb = y + ((size_t)b * NPIX + p0) * CDIM;
    float gv = gb[c2];
    for (int p = pr; p < 64; p += 2)
        yb[(size_t)p * CDIM + c2] = tile[c2][p] * (gv + ssc[p]);
}

// ---------------- NHWC f32 dwconv3 + residual + fused PER-BATCH GN stats ----------------
// out = in + conv(in); stats slot layout: [b][slot][16] floats, slot = blockIdx.x & 7
// (each slot on its own 64B cache line -> low atomic contention)
__global__ __launch_bounds__(256) void cpe_f32_kernel(const float* __restrict__ in,
                                                      const float* __restrict__ wT,
                                                      const float* __restrict__ bias,
                                                      float* __restrict__ out,
                                                      float* __restrict__ stats) {
    __shared__ float sb[8];
    int b = blockIdx.y, tx = threadIdx.x;
    int cg = tx & 15, pp = tx >> 4;
    int p = blockIdx.x * 16 + pp;
    int xx = p & 63, yy = p >> 6;
    int c0 = cg * 8;
    float acc[8], ctr[8];
#pragma unroll
    for (int j = 0; j < 8; ++j) acc[j] = bias[c0 + j];
#pragma unroll
    for (int dy = -1; dy <= 1; ++dy) {
        int y2 = yy + dy;
        if (y2 < 0 || y2 >= 64) continue;
#pragma unroll
        for (int dx = -1; dx <= 1; ++dx) {
            int x2 = xx + dx;
            if (x2 < 0 || x2 >= 64) continue;
            const float* ip = &in[((size_t)b * NPIX + y2 * 64 + x2) * 128 + c0];
            float4 v0 = *(const float4*)ip;
            float4 v1 = *(const float4*)(ip + 4);
            const float* wr = wT + ((dy + 1) * 3 + dx + 1) * 128 + c0;
            acc[0] += v0.x * wr[0]; acc[1] += v0.y * wr[1];
            acc[2] += v0.z * wr[2]; acc[3] += v0.w * wr[3];
            acc[4] += v1.x * wr[4]; acc[5] += v1.y * wr[5];
            acc[6] += v1.z * wr[6]; acc[7] += v1.w * wr[7];
            if (dy == 0 && dx == 0) {
                ctr[0] = v0.x; ctr[1] = v0.y; ctr[2] = v0.z; ctr[3] = v0.w;
                ctr[4] = v1.x; ctr[5] = v1.y; ctr[6] = v1.z; ctr[7] = v1.w;
            }
        }
    }
    float s = 0.f, s2 = 0.f;
    float r[8];
#pragma unroll
    for (int j = 0; j < 8; ++j) {
        r[j] = ctr[j] + acc[j];
        s += r[j]; s2 += r[j] * r[j];
    }
    float* op = &out[((size_t)b * NPIX + p) * 128 + c0];
    *(float4*)op = make_float4(r[0], r[1], r[2], r[3]);
    *(float4*)(op + 4) = make_float4(r[4], r[5], r[6], r[7]);
#pragma unroll
    for (int off = 32; off > 0; off >>= 1) {
        s += __shfl_down(s, off, 64);
        s2 += __shfl_down(s2, off, 64);
    }
    int wv = tx >> 6;
    if ((tx & 63) == 0) { sb[wv] = s; sb[4 + wv] = s2; }
    __syncthreads();
    if (tx == 0) {
        int slot = (b * 8 + (blockIdx.x & 7)) * 16;
        atomicAdd(&stats[slot], sb[0] + sb[1] + sb[2] + sb[3]);
        atomicAdd(&stats[slot + 1], sb[4] + sb[5] + sb[6] + sb[7]);
    }
}

// ---------------- GN apply (elementwise, NHWC f32 -> NHWC bf16), 8-slot PER-BATCH stats ----------------
__global__ __launch_bounds__(256) void gn_apply_kernel(const float* __restrict__ in,
                                                       const float* __restrict__ stats,
                                                       const float* __restrict__ g,
                                                       const float* __restrict__ bta,
                                                       unsigned short* __restrict__ dst) {
    int b = blockIdx.y;
    int i = blockIdx.x * 256 + threadIdx.x;   // 0..65535
    float su = 0.f, sq = 0.f;
#pragma unroll
    for (int sl = 0; sl < 8; ++sl) {
        su += stats[(b * 8 + sl) * 16];
        sq += stats[(b * 8 + sl) * 16 + 1];
    }
    const float n = 1.f / (float)(CDIM * NPIX);
    float mu = su * n;
    float var = sq * n - mu * mu;
    float rr = rsqrtf(var + EPSN);
    int c0 = (i & 15) * 8;
    size_t idx = (size_t)b * (NPIX * 128) + (size_t)i * 8;
    float4 v0 = *(const float4*)&in[idx];
    float4 v1 = *(const float4*)&in[idx + 4];
    unsigned short o[8];
    o[0] = f2b((v0.x - mu) * rr * g[c0 + 0] + bta[c0 + 0]);
    o[1] = f2b((v0.y - mu) * rr * g[c0 + 1] + bta[c0 + 1]);
    o[2] = f2b((v0.z - mu) * rr * g[c0 + 2] + bta[c0 + 2]);
    o[3] = f2b((v0.w - mu) * rr * g[c0 + 3] + bta[c0 + 3]);
    o[4] = f2b((v1.x - mu) * rr * g[c0 + 4] + bta[c0 + 4]);
    o[5] = f2b((v1.y - mu) * rr * g[c0 + 5] + bta[c0 + 5]);
    o[6] = f2b((v1.z - mu) * rr * g[c0 + 6] + bta[c0 + 6]);
    o[7] = f2b((v1.w - mu) * rr * g[c0 + 7] + bta[c0 + 7]);
    *(uint4*)&dst[idx] = *(uint4*)o;
}

// ---------------- NHWC bf16 dwconv3 + bias + relu -> bf16 ----------------
__global__ __launch_bounds__(256) void dwc_bf16_kernel(const unsigned short* __restrict__ in,
                                                       const float* __restrict__ wT,
                                                       const float* __restrict__ bias,
                                                       unsigned short* __restrict__ out) {
    int b = blockIdx.y, tx = threadIdx.x;
    int cg = tx & 15, pp = tx >> 4;
    int p = blockIdx.x * 16 + pp;
    int xx = p & 63, yy = p >> 6;
    int c0 = cg * 8;
    float acc[8];
#pragma unroll
    for (int j = 0; j < 8; ++j) acc[j] = bias[c0 + j];
#pragma unroll
    for (int dy = -1; dy <= 1; ++dy) {
        int y2 = yy + dy;
        if (y2 < 0 || y2 >= 64) continue;
#pragma unroll
        for (int dx = -1; dx <= 1; ++dx) {
            int x2 = xx + dx;
            if (x2 < 0 || x2 >= 64) continue;
            unsigned short v[8];
            *(uint4*)v = *(const uint4*)&in[((size_t)b * NPIX + y2 * 64 + x2) * 128 + c0];
            const float* wr = wT + ((dy + 1) * 3 + dx + 1) * 128 + c0;
#pragma unroll
            for (int j = 0; j < 8; ++j) acc[j] += b2f(v[j]) * wr[j];
        }
    }
    unsigned short o[8];
#pragma unroll
    for (int j = 0; j < 8; ++j) o[j] = f2b(fmaxf(acc[j], 0.f));
    *(uint4*)&out[((size_t)b * NPIX + p) * 128 + c0] = *(uint4*)o;
}

// ---------------- conv1x1 via bf16 MFMA ----------------
// epilogues: out_t (bf16 NHWC) | out+nchw=0 (f32 NHWC, res f32 NHWC) | out+nchw=1 (f32 NCHW, res f32 NHWC)
__global__ __launch_bounds__(256) void conv_mfma_kernel(const unsigned short* __restrict__ in_t,
                                                        const unsigned short* __restrict__ w,
                                                        const float* __restrict__ bias,
                                                        const float* __restrict__ res,
                                                        float* __restrict__ out,
                                                        unsigned short* __restrict__ out_t,
                                                        int Cin, int Cout, int relu, int nchw) {
    __shared__ __align__(16) unsigned short A_s[128][136];
    __shared__ __align__(16) unsigned short B_s[128][136];
    int b = blockIdx.z, p0 = blockIdx.x * 128, o0 = blockIdx.y * 128;
    int tx = threadIdx.x;
    int wave = tx >> 6, lane = tx & 63;
    int wm = wave & 1, wn = wave >> 1;
    int quad = lane >> 4, l16 = lane & 15;

    f32x4 acc[4][4];
#pragma unroll
    for (int mt = 0; mt < 4; ++mt) {
#pragma unroll
        for (int r = 0; r < 4; ++r) {
            float bv = bias[o0 + wm * 64 + mt * 16 + quad * 4 + r];
#pragma unroll
            for (int nt = 0; nt < 4; ++nt) acc[mt][nt][r] = bv;
        }
    }

    for (int k0 = 0; k0 < Cin; k0 += 128) {
#pragma unroll
        for (int j = 0; j < 8; ++j) {
            int idx = tx + 256 * j;
            int row = idx >> 4, c16 = idx & 15;
            *(uint4*)&A_s[row][c16 * 8] =
                *(const uint4*)&w[(size_t)(o0 + row) * Cin + k0 + c16 * 8];
            *(uint4*)&B_s[row][c16 * 8] =
                *(const uint4*)&in_t[((size_t)b * NPIX + p0 + row) * Cin + k0 + c16 * 8];
        }
        __syncthreads();
#pragma unroll
        for (int ks = 0; ks < 128; ks += 32) {
            short8 af[4], bf[4];
#pragma unroll
            for (int mt = 0; mt < 4; ++mt)
                af[mt] = *(const short8*)&A_s[wm * 64 + mt * 16 + l16][ks + quad * 8];
#pragma unroll
            for (int nt = 0; nt < 4; ++nt)
                bf[nt] = *(const short8*)&B_s[wn * 64 + nt * 16 + l16][ks + quad * 8];
#pragma unroll
            for (int mt = 0; mt < 4; ++mt)
#pragma unroll
                for (int nt = 0; nt < 4; ++nt)
                    acc[mt][nt] = __builtin_amdgcn_mfma_f32_16x16x32_bf16(
                        af[mt], bf[nt], acc[mt][nt], 0, 0, 0);
        }
        __syncthreads();
    }

    if (out_t) {
#pragma unroll
        for (int mt = 0; mt < 4; ++mt) {
#pragma unroll
            for (int nt = 0; nt < 4; ++nt) {
                int p = p0 + wn * 64 + nt * 16 + l16;
                int ob = o0 + wm * 64 + mt * 16 + quad * 4;
                ushort4 u;
                float v0 = acc[mt][nt][0], v1 = acc[mt][nt][1];
                float v2 = acc[mt][nt][2], v3 = acc[mt][nt][3];
                if (relu) { v0 = fmaxf(v0, 0.f); v1 = fmaxf(v1, 0.f);
                            v2 = fmaxf(v2, 0.f); v3 = fmaxf(v3, 0.f); }
                u.x = f2b(v0); u.y = f2b(v1); u.z = f2b(v2); u.w = f2b(v3);
                *(ushort4*)&out_t[((size_t)b * NPIX + p) * Cout + ob] = u;
            }
        }
    } else if (!nchw) {
#pragma unroll
        for (int mt = 0; mt < 4; ++mt) {
#pragma unroll
            for (int nt = 0; nt < 4; ++nt) {
                int p = p0 + wn * 64 + nt * 16 + l16;
                int ob = o0 + wm * 64 + mt * 16 + quad * 4;
                size_t ix = ((size_t)b * NPIX + p) * Cout + ob;
                float4 v = make_float4(acc[mt][nt][0], acc[mt][nt][1],
                                       acc[mt][nt][2], acc[mt][nt][3]);
                if (relu) { v.x = fmaxf(v.x, 0.f); v.y = fmaxf(v.y, 0.f);
                            v.z = fmaxf(v.z, 0.f); v.w = fmaxf(v.w, 0.f); }
                if (res) {
                    float4 rv = *(const float4*)&res[ix];
                    v.x += rv.x; v.y += rv.y; v.z += rv.z; v.w += rv.w;
                }
                *(float4*)&out[ix] = v;
            }
        }
    } else {
        float* outb = out + (size_t)b * Cout * NPIX;
#pragma unroll
        for (int mt = 0; mt < 4; ++mt) {
#pragma unroll
            for (int nt = 0; nt < 4; ++nt) {
                int p = p0 + wn * 64 + nt * 16 + l16;
                int ob = o0 + wm * 64 + mt * 16 + quad * 4;
                float4 rv = make_float4(0.f, 0.f, 0.f, 0.f);
                if (res) rv = *(const float4*)&res[((size_t)b * NPIX + p) * 128 + ob];
#pragma unroll
                for (int r = 0; r < 4; ++r) {
                    float v = acc[mt][nt][r];
                    if (relu) v = fmaxf(v, 0.f);
                    v += (r == 0 ? rv.x : r == 1 ? rv.y : r == 2 ? rv.z : rv.w);
                    outb[(size_t)(ob + r) * NPIX + p] = v;
                }
            }
        }
    }
}

// ---------------- MFMA window attention, both orientations in one launch ----------------
// t_t: bf16 NHWC 640ch grouped [q0|k0|v0|q1|k1]; blockIdx.z = b*2+which.
__global__ __launch_bounds__(256) void attn_dual_kernel(const unsigned short* __restrict__ t_t,
                                                        float* __restrict__ a0,
                                                        float* __restrict__ a1) {
    __shared__ __align__(16) unsigned short Vt[16][264];
    int wi = blockIdx.x, head = blockIdx.y;
    int z = blockIdx.z;
    int b = z >> 1, which = z & 1;
    int qoff = which ? 384 : 0;
    int koff = which ? 512 : 128;
    int mode = which;
    float* a_out = which ? a1 : a0;
    int tx = threadIdx.x;
    int wave = tx >> 6, l = tx & 63;
    int l32 = l & 31, half = l >> 5;
    const size_t base = (size_t)b * NPIX;
    const int hc = head * 16;

    // stage V transposed (16 d x 256 tokens); thread tx handles token tx
    {
        int p = tok2pix(mode, wi, tx);
        const unsigned short* vp = &t_t[(base + p) * 640 + 256 + hc];
        unsigned short tmp[16];
        *(uint4*)&tmp[0] = *(const uint4*)vp;
        *(uint4*)&tmp[8] = *(const uint4*)(vp + 8);
#pragma unroll
        for (int d = 0; d < 16; ++d) Vt[d][tx] = tmp[d];
    }
    __syncthreads();

    for (int qi = 0; qi < 2; ++qi) {
        int qs = qi * 4 + wave;  // query strip 0..7
        int qp = tok2pix(mode, wi, qs * 32 + l32);
        short8 qf = *(const short8*)&t_t[(base + qp) * 640 + qoff + hc + half * 8];
        f32x16 o_acc;
#pragma unroll
        for (int r = 0; r < 16; ++r) o_acc[r] = 0.f;
        float rs = 0.f;
#pragma unroll
        for (int nt = 0; nt < 8; ++nt) {
            int kp = tok2pix(mode, wi, nt * 32 + l32);
            short8 kf = *(const short8*)&t_t[(base + kp) * 640 + koff + hc + half * 8];
            f32x16 zz;
#pragma unroll
            for (int r = 0; r < 16; ++r) zz[r] = 0.f;
            // S^T strip: D[t][m], lane col m=l32, rows t=(r&3)+8*(r>>2)+4*half
            f32x16 s = __builtin_amdgcn_mfma_f32_32x32x16_bf16(kf, qf, zz, 0, 0, 0);
            unsigned int pk[8];
#pragma unroll
            for (int i = 0; i < 8; ++i) {
                float e0 = __expf(s[2 * i]);
                float e1 = __expf(s[2 * i + 1]);
                rs += e0 + e1;
                pk[i] = __builtin_amdgcn_perm(__float_as_uint(e1), __float_as_uint(e0),
                                              0x07060302u);
            }
            unsigned int xpk[8];
#pragma unroll
            for (int i = 0; i < 8; ++i)
                xpk[i] = (unsigned int)__shfl_xor((int)pk[i], 32, 64);
            unsigned int u0[4], u1[4];
            if (half == 0) {
                u0[0] = pk[0]; u0[1] = pk[1]; u0[2] = xpk[0]; u0[3] = xpk[1];
                u1[0] = pk[4]; u1[1] = pk[5]; u1[2] = xpk[4]; u1[3] = xpk[5];
            } else {
                u0[0] = xpk[2]; u0[1] = xpk[3]; u0[2] = pk[2]; u0[3] = pk[3];
                u1[0] = xpk[6]; u1[1] = xpk[7]; u1[2] = pk[6]; u1[3] = pk[7];
            }
            short8 vf0, vf1;
#pragma unroll
            for (int r = 0; r < 8; ++r) { vf0[r] = 0; vf1[r] = 0; }
            if (l32 < 16) {
                vf0 = *(const short8*)&Vt[l32][nt * 32 + half * 8];
                vf1 = *(const short8*)&Vt[l32][nt * 32 + 16 + half * 8];
            }
            o_acc = __builtin_amdgcn_mfma_f32_32x32x16_bf16(vf0, *(short8*)u0, o_acc, 0, 0, 0);
            o_acc = __builtin_amdgcn_mfma_f32_32x32x16_bf16(vf1, *(short8*)u1, o_acc, 0, 0, 0);
        }
        rs += __shfl_xor(rs, 32, 64);
        float rinv = 1.f / rs;
        float* dst = a_out + (base + qp) * 128 + hc;
#pragma unroll
        for (int r = 0; r < 8; ++r) {
            int d = (r & 3) + 8 * (r >> 2) + 4 * half;
            dst[d] = o_acc[r] * rinv;
        }
    }
}

// ---------------- combined cpe dwconv on v0 (stride-640 bf16 in, accumulate f32 NHWC) ----------------
__global__ __launch_bounds__(256) void cpe_nhwc_kernel(const unsigned short* __restrict__ t_t,
                                                       const float* __restrict__ wT,
                                                       const float* __restrict__ bsum,
                                                       float* __restrict__ a_out) {
    int b = blockIdx.y;
    int tx = threadIdx.x;
    int cg = tx & 15, pp = tx >> 4;
    int p = blockIdx.x * 16 + pp;
    int xx = p & 63, yy = p >> 6;
    int c0 = cg * 8;
    float acc[8];
#pragma unroll
    for (int j = 0; j < 8; ++j) acc[j] = bsum[c0 + j];
#pragma unroll
    for (int dy = -1; dy <= 1; ++dy) {
        int y2 = yy + dy;
        if (y2 < 0 || y2 >= 64) continue;
#pragma unroll
        for (int dx = -1; dx <= 1; ++dx) {
            int x2 = xx + dx;
            if (x2 < 0 || x2 >= 64) continue;
            int pn = y2 * 64 + x2;
            unsigned short v[8];
            *(uint4*)v = *(const uint4*)&t_t[((size_t)b * NPIX + pn) * 640 + 256 + c0];
            const float* wr = wT + ((dy + 1) * 3 + dx + 1) * 128 + c0;
#pragma unroll
            for (int j = 0; j < 8; ++j) acc[j] += b2f(v[j]) * wr[j];
        }
    }
    float* dst = a_out + ((size_t)b * NPIX + p) * 128 + c0;
#pragma unroll
    for (int j = 0; j < 8; ++j) dst[j] += acc[j];
}

// ---------------- m_t = bf16((a0+a1) * act_res)  (all NHWC) ----------------
__global__ __launch_bounds__(256) void mul3_kernel(const float* __restrict__ a0,
                                                   const float* __restrict__ a1,
                                                   const unsigned short* __restrict__ act,
                                                   unsigned short* __restrict__ dst) {
    size_t i = ((size_t)blockIdx.x * 256 + threadIdx.x) * 8;
    float4 x0 = *(const float4*)&a0[i];
    float4 x1 = *(const float4*)&a0[i + 4];
    float4 y0 = *(const float4*)&a1[i];
    float4 y1 = *(const float4*)&a1[i + 4];
    unsigned short t[8];
    *(uint4*)t = *(const uint4*)&act[i];
    unsigned short r[8];
    r[0] = f2b((x0.x + y0.x) * b2f(t[0])); r[1] = f2b((x0.y + y0.y) * b2f(t[1]));
    r[2] = f2b((x0.z + y0.z) * b2f(t[2])); r[3] = f2b((x0.w + y0.w) * b2f(t[3]));
    r[4] = f2b((x1.x + y1.x) * b2f(t[4])); r[5] = f2b((x1.y + y1.y) * b2f(t[5]));
    r[6] = f2b((x1.z + y1.z) * b2f(t[6])); r[7] = f2b((x1.w + y1.w) * b2f(t[7]));
    *(uint4*)&dst[i] = *(uint4*)r;
}

extern "C" void kernel_launch(void* const* d_in, const int* in_sizes, int n_in,
                              void* d_out, int out_size, void* d_ws, size_t ws_size,
                              hipStream_t stream) {
    const float* x       = (const float*)d_in[0];
    const float* eca_w   = (const float*)d_in[1];
    const float* esa_al  = (const float*)d_in[2];
    const float* cpe1_w  = (const float*)d_in[3];  const float* cpe1_b = (const float*)d_in[4];
    const float* g1      = (const float*)d_in[5];  const float* b1     = (const float*)d_in[6];
    const float* actp_w  = (const float*)d_in[7];  const float* actp_b = (const float*)d_in[8];
    const float* inp_w   = (const float*)d_in[9];  const float* inp_b  = (const float*)d_in[10];
    const float* dwc_w   = (const float*)d_in[11]; const float* dwc_b  = (const float*)d_in[12];
    const float* qkv_w   = (const float*)d_in[13]; const float* qkv_b  = (const float*)d_in[14];
    const float* eaax_w  = (const float*)d_in[15]; const float* eaax_b = (const float*)d_in[16];
    const float* eaay_w  = (const float*)d_in[17]; const float* eaay_b = (const float*)d_in[18];
    const float* outp_w  = (const float*)d_in[19]; const float* outp_b = (const float*)d_in[20];
    const float* cpe2_w  = (const float*)d_in[21]; const float* cpe2_b = (const float*)d_in[22];
    const float* g2      = (const float*)d_in[23]; const float* b2     = (const float*)d_in[24];
    const float* mlp1_w  = (const float*)d_in[25]; const float* mlp1_b = (const float*)d_in[26];
    const float* mlp2_w  = (const float*)d_in[27]; const float* mlp2_b = (const float*)d_in[28];

    float* ws = (float*)d_ws;
    unsigned short* U = (unsigned short*)d_ws;
    const size_t E = (size_t)BATCH * CDIM * NPIX;  // 4,194,304

    float* y_nhwc  = ws;               // [0,E)  esa out; later a0
    float* a0      = ws;               // reuse after y dead
    float* sc_nhwc = ws + E;           // [E,2E) shortcut (live to outp)
    unsigned short* xn_t  = U + 4 * E; // [2E,2.5E) f32-equiv
    unsigned short* act_t = U + 5 * E; // [2.5E,3E)
    unsigned short* it_t  = U + 6 * E; // [3E,3.5E)
    unsigned short* tin_t = U + 7 * E; // [3.5E,4E)
    float* a1      = ws + 4 * E;       // [4E,5E)
    unsigned short* t_t   = U + 10 * E; // [5E,7.5E)
    unsigned short* m_t   = U + 15 * E; // [7.5E,8E)
    float* out_nhwc = ws + 8 * E;      // [8E,9E)
    float* out2    = ws + 2 * E;       // [2E,3E)  (xn_t/act_t dead by then)
    unsigned short* g2_t  = U + 6 * E; // [3E,3.5E) (it_t dead)
    unsigned short* hid_t = U + 10 * E; // [5E,7E) (t_t dead)
    unsigned short* wpool = U + 20 * E; // 262144 bf16
    unsigned short* wq  = wpool;
    unsigned short* wm1 = wpool + 81920;
    unsigned short* wm2 = wpool + 147456;
    unsigned short* wa  = wpool + 212992;
    unsigned short* wi_ = wpool + 229376;
    unsigned short* wo  = wpool + 245760;
    float* fb     = ws + 10 * E + 131072;
    float* meanb  = fb;            // 1024
    float* gateb  = fb + 1024;     // 1024
    float* gstats = fb + 2048;     // 2048: gn1 [0,1024), gn2 [1024,2048) — 8 slots x 16 floats x 8 b
    float* qb_r   = fb + 4096;     // 640
    float* wsT    = fb + 4736;     // 1152
    float* bsum   = fb + 5888;     // 128
    float* cpe1T  = fb + 6016;     // 1152
    float* dwcT   = fb + 7168;     // 1152
    float* cpe2T  = fb + 8320;     // 1152

    hipMemsetAsync(gstats, 0, 2048 * sizeof(float), stream);
    convert_w_kernel<<<1045, 256, 0, stream>>>(qkv_w, mlp1_w, mlp2_w, actp_w, inp_w, outp_w,
                                               qkv_b, eaax_w, eaax_b, eaay_w, eaay_b,
                                               cpe1_w, dwc_w, cpe2_w,
                                               wpool, qb_r, wsT, bsum, cpe1T, dwcT, cpe2T);

    // 1) ECA + ESA fused with transpose -> y (f32 NHWC)
    mean_bc_kernel<<<BATCH * CDIM, 256, 0, stream>>>(x, meanb);
    eca_gate_kernel<<<BATCH, CDIM, 0, stream>>>(meanb, eca_w, gateb);
    esa_tr_kernel<<<dim3(64, BATCH), 256, 0, stream>>>(x, meanb, gateb, esa_al, y_nhwc);
    // 2) shortcut = y + cpe1(y), fused per-batch GN1 stats (8 spread slots)
    cpe_f32_kernel<<<dim3(256, BATCH), 256, 0, stream>>>(y_nhwc, cpe1T, cpe1_b, sc_nhwc, gstats);
    // 3) GN1 apply -> xn_t (bf16 NHWC)
    gn_apply_kernel<<<dim3(256, BATCH), 256, 0, stream>>>(sc_nhwc, gstats, g1, b1, xn_t);
    // 4) act_res = relu(actp(xn)) -> act_t
    conv_mfma_kernel<<<dim3(32, 1, BATCH), 256, 0, stream>>>(xn_t, wa, actp_b, nullptr, nullptr,
                                                             act_t, 128, 128, 1, 0);
    // 5) t = relu(dwc(inp(xn)))  xn_t -> it_t -> tin_t  (all bf16 NHWC)
    conv_mfma_kernel<<<dim3(32, 1, BATCH), 256, 0, stream>>>(xn_t, wi_, inp_b, nullptr, nullptr,
                                                             it_t, 128, 128, 0, 0);
    dwc_bf16_kernel<<<dim3(256, BATCH), 256, 0, stream>>>(it_t, dwcT, dwc_b, tin_t);
    // 6) qkv -> t_t (bf16 NHWC, 640 grouped)
    conv_mfma_kernel<<<dim3(32, 5, BATCH), 256, 0, stream>>>(tin_t, wq, qb_r, nullptr, nullptr,
                                                             t_t, 128, 640, 0, 0);
    // 7) both attentions in one launch -> a0, a1 ; cpe(v0) accumulates into a1
    attn_dual_kernel<<<dim3(16, 8, 2 * BATCH), 256, 0, stream>>>(t_t, a0, a1);
    cpe_nhwc_kernel<<<dim3(256, BATCH), 256, 0, stream>>>(t_t, wsT, bsum, a1);
    // 8) m_t = bf16((a0+a1)*act_res) ; out = outp(m) + shortcut -> out_nhwc (f32 NHWC)
    mul3_kernel<<<2048, 256, 0, stream>>>(a0, a1, act_t, m_t);
    conv_mfma_kernel<<<dim3(32, 1, BATCH), 256, 0, stream>>>(m_t, wo, outp_b, sc_nhwc, out_nhwc,
                                                             nullptr, 128, 128, 0, 0);
    // 9) out2 = out + cpe2(out), fused per-batch GN2 stats
    cpe_f32_kernel<<<dim3(256, BATCH), 256, 0, stream>>>(out_nhwc, cpe2T, cpe2_b, out2,
                                                         gstats + 1024);
    // 10) GN2 apply -> g2_t
    gn_apply_kernel<<<dim3(256, BATCH), 256, 0, stream>>>(out2, gstats + 1024, g2, b2, g2_t);
    // 11) mlp
    conv_mfma_kernel<<<dim3(32, 4, BATCH), 256, 0, stream>>>(g2_t, wm1, mlp1_b, nullptr, nullptr,
                                                             hid_t, 128, 512, 1, 0);
    conv_mfma_kernel<<<dim3(32, 1, BATCH), 256, 0, stream>>>(hid_t, wm2, mlp2_b, out2,
                                                             (float*)d_out, nullptr, 512, 128, 0, 1);
}

// Round 9
// 314.018 us; speedup vs baseline: 4.1269x; 1.0491x over previous
//
#include <hip/hip_runtime.h>

#define NPIX 4096
#define CDIM 128
#define BATCH 8
#define EPSN 1e-5f

typedef __attribute__((ext_vector_type(8))) short short8;
typedef __attribute__((ext_vector_type(4))) float f32x4;
typedef __attribute__((ext_vector_type(16))) float f32x16;

__device__ __forceinline__ float sigmoidf_(float x) { return 1.f / (1.f + __expf(-x)); }

__device__ __forceinline__ unsigned short f2b(float f) {
    unsigned int u = __float_as_uint(f);
    unsigned int r = (u + 0x7FFF + ((u >> 16) & 1)) >> 16;  // RNE
    return (unsigned short)r;
}
__device__ __forceinline__ float b2f(unsigned short u) {
    return __uint_as_float((unsigned int)u << 16);
}

// window token -> pixel index
__device__ __forceinline__ int tok2pix(int mode, int wi, int l) {
    return (mode == 0) ? ((l >> 2) * 64 + wi * 4 + (l & 3))
                       : ((wi * 4 + (l >> 6)) * 64 + (l & 63));
}

// ---------------- weight conversion / reorder / transposes ----------------
__global__ __launch_bounds__(256) void convert_w_kernel(const float* __restrict__ qkv_w,
                                                        const float* __restrict__ mlp1_w,
                                                        const float* __restrict__ mlp2_w,
                                                        const float* __restrict__ actp_w,
                                                        const float* __restrict__ inp_w,
                                                        const float* __restrict__ outp_w,
                                                        const float* __restrict__ qkv_b,
                                                        const float* __restrict__ eaax_w,
                                                        const float* __restrict__ eaax_b,
                                                        const float* __restrict__ eaay_w,
                                                        const float* __restrict__ eaay_b,
                                                        const float* __restrict__ cpe1_w,
                                                        const float* __restrict__ dwc_w,
                                                        const float* __restrict__ cpe2_w,
                                                        const float* __restrict__ actp_b,
                                                        const float* __restrict__ inp_b,
                                                        unsigned short* __restrict__ dst,
                                                        float* __restrict__ qb_r,
                                                        float* __restrict__ wsT,
                                                        float* __restrict__ bsum,
                                                        float* __restrict__ cpe1T,
                                                        float* __restrict__ dwcT,
                                                        float* __restrict__ cpe2T,
                                                        float* __restrict__ abi) {
    int i = blockIdx.x * 256 + threadIdx.x;
    if (i >= 267776) return;
    if (i < 262144) {
        float v;
        if (i < 81920) {
            int o = i >> 7, c = i & 127;              // reordered: o_new = g*128+cc
            v = qkv_w[(size_t)(5 * (o & 127) + (o >> 7)) * 128 + c];
        } else if (i < 147456) v = mlp1_w[i - 81920];
        else if (i < 212992)   v = mlp2_w[i - 147456];
        else if (i < 229376)   v = actp_w[i - 212992];
        else if (i < 245760)   v = inp_w[i - 229376];
        else                   v = outp_w[i - 245760];
        dst[i] = f2b(v);
    } else {
        int j = i - 262144;
        if (j < 640) qb_r[j] = qkv_b[5 * (j & 127) + (j >> 7)];
        else if (j < 1792) {
            int idx = j - 640; int k = idx >> 7, c = idx & 127;
            wsT[idx] = eaax_w[c * 9 + k] + eaay_w[c * 9 + k];
        } else if (j < 1920) bsum[j - 1792] = eaax_b[j - 1792] + eaay_b[j - 1792];
        else if (j < 3072) {
            int idx = j - 1920; int k = idx >> 7, c = idx & 127;
            cpe1T[idx] = cpe1_w[c * 9 + k];
        } else if (j < 4224) {
            int idx = j - 3072; int k = idx >> 7, c = idx & 127;
            dwcT[idx] = dwc_w[c * 9 + k];
        } else if (j < 5376) {
            int idx = j - 4224; int k = idx >> 7, c = idx & 127;
            cpe2T[idx] = cpe2_w[c * 9 + k];
        } else {
            int idx = j - 5376;
            abi[idx] = (idx < 128) ? actp_b[idx] : inp_b[idx - 128];
        }
    }
}

// ---------------- per-(b,c) mean over HW (x is NCHW input) ----------------
__global__ __launch_bounds__(256) void mean_bc_kernel(const float* __restrict__ x,
                                                      float* __restrict__ mean) {
    __shared__ float sb[4];
    int bc = blockIdx.x;
    const float* p = x + (size_t)bc * NPIX;
    float s = 0.f;
    for (int i = threadIdx.x; i < NPIX; i += 256) s += p[i];
#pragma unroll
    for (int off = 32; off > 0; off >>= 1) s += __shfl_down(s, off, 64);
    if ((threadIdx.x & 63) == 0) sb[threadIdx.x >> 6] = s;
    __syncthreads();
    if (threadIdx.x == 0) mean[bc] = (sb[0] + sb[1] + sb[2] + sb[3]) * (1.f / (float)NPIX);
}

// ---------------- ESA+ECA fused (gate computed inline) with NCHW->NHWC transpose ----------------
__global__ __launch_bounds__(256) void esa_tr_kernel(const float* __restrict__ x,
                                                     const float* __restrict__ mean,
                                                     const float* __restrict__ w5,
                                                     const float* __restrict__ alpha_p,
                                                     float* __restrict__ y) {
    __shared__ float tile[128][65];
    __shared__ float smx[4][64], smn[4][64], ssc[64], gat[128];
    int b = blockIdx.y, p0 = blockIdx.x * 64;
    int tx = threadIdx.x, pl = tx & 63, part = tx >> 6;
    const float* xb = x + (size_t)b * CDIM * NPIX;
    const float* mb = mean + b * CDIM;
    for (int c = part; c < CDIM; c += 4)
        tile[c][pl] = xb[(size_t)c * NPIX + p0 + pl];
    __syncthreads();
    float mx = -1e30f, mn = 1e30f;
#pragma unroll
    for (int cc = 0; cc < 32; ++cc) {
        int c = part * 32 + cc;
        float v = tile[c][pl] - mb[c];
        mx = fmaxf(mx, v); mn = fminf(mn, v);
    }
    smx[part][pl] = mx; smn[part][pl] = mn;
    __syncthreads();
    if (tx < 128) {
        float s = 0.f;
#pragma unroll
        for (int k = 0; k < 5; ++k) {
            int cc = tx + k - 2;
            if (cc >= 0 && cc < CDIM) s += w5[k] * mb[cc];
        }
        gat[tx] = sigmoidf_(s);
    }
    if (part == 0) {
        float m1 = fmaxf(fmaxf(smx[0][pl], smx[1][pl]), fmaxf(smx[2][pl], smx[3][pl]));
        float m2 = fminf(fminf(smn[0][pl], smn[1][pl]), fminf(smn[2][pl], smn[3][pl]));
        float a = alpha_p[0];
        ssc[pl] = sigmoidf_(m1) * a + sigmoidf_(m2) * (1.f - a);
    }
    __syncthreads();
    int c2 = tx & 127, pr = tx >> 7;
    float* yb = y + ((size_t)b * NPIX + p0) * CDIM;
    float gv = gat[c2];
    for (int p = pr; p < 64; p += 2)
        yb[(size_t)p * CDIM + c2] = tile[c2][p] * (gv + ssc[p]);
}

// ---------------- NHWC f32 dwconv3 + residual + fused PER-BATCH GN stats (8 spread slots) ----------------
__global__ __launch_bounds__(256) void cpe_f32_kernel(const float* __restrict__ in,
                                                      const float* __restrict__ wT,
                                                      const float* __restrict__ bias,
                                                      float* __restrict__ out,
                                                      float* __restrict__ stats) {
    __shared__ float sb[8];
    int b = blockIdx.y, tx = threadIdx.x;
    int cg = tx & 15, pp = tx >> 4;
    int p = blockIdx.x * 16 + pp;
    int xx = p & 63, yy = p >> 6;
    int c0 = cg * 8;
    float acc[8], ctr[8];
#pragma unroll
    for (int j = 0; j < 8; ++j) acc[j] = bias[c0 + j];
#pragma unroll
    for (int dy = -1; dy <= 1; ++dy) {
        int y2 = yy + dy;
        if (y2 < 0 || y2 >= 64) continue;
#pragma unroll
        for (int dx = -1; dx <= 1; ++dx) {
            int x2 = xx + dx;
            if (x2 < 0 || x2 >= 64) continue;
            const float* ip = &in[((size_t)b * NPIX + y2 * 64 + x2) * 128 + c0];
            float4 v0 = *(const float4*)ip;
            float4 v1 = *(const float4*)(ip + 4);
            const float* wr = wT + ((dy + 1) * 3 + dx + 1) * 128 + c0;
            acc[0] += v0.x * wr[0]; acc[1] += v0.y * wr[1];
            acc[2] += v0.z * wr[2]; acc[3] += v0.w * wr[3];
            acc[4] += v1.x * wr[4]; acc[5] += v1.y * wr[5];
            acc[6] += v1.z * wr[6]; acc[7] += v1.w * wr[7];
            if (dy == 0 && dx == 0) {
                ctr[0] = v0.x; ctr[1] = v0.y; ctr[2] = v0.z; ctr[3] = v0.w;
                ctr[4] = v1.x; ctr[5] = v1.y; ctr[6] = v1.z; ctr[7] = v1.w;
            }
        }
    }
    float s = 0.f, s2 = 0.f;
    float r[8];
#pragma unroll
    for (int j = 0; j < 8; ++j) {
        r[j] = ctr[j] + acc[j];
        s += r[j]; s2 += r[j] * r[j];
    }
    float* op = &out[((size_t)b * NPIX + p) * 128 + c0];
    *(float4*)op = make_float4(r[0], r[1], r[2], r[3]);
    *(float4*)(op + 4) = make_float4(r[4], r[5], r[6], r[7]);
#pragma unroll
    for (int off = 32; off > 0; off >>= 1) {
        s += __shfl_down(s, off, 64);
        s2 += __shfl_down(s2, off, 64);
    }
    int wv = tx >> 6;
    if ((tx & 63) == 0) { sb[wv] = s; sb[4 + wv] = s2; }
    __syncthreads();
    if (tx == 0) {
        int slot = (b * 8 + (blockIdx.x & 7)) * 16;
        atomicAdd(&stats[slot], sb[0] + sb[1] + sb[2] + sb[3]);
        atomicAdd(&stats[slot + 1], sb[4] + sb[5] + sb[6] + sb[7]);
    }
}

// ---------------- NHWC bf16 dwconv3 + bias + relu -> bf16 ----------------
__global__ __launch_bounds__(256) void dwc_bf16_kernel(const unsigned short* __restrict__ in,
                                                       const float* __restrict__ wT,
                                                       const float* __restrict__ bias,
                                                       unsigned short* __restrict__ out) {
    int b = blockIdx.y, tx = threadIdx.x;
    int cg = tx & 15, pp = tx >> 4;
    int p = blockIdx.x * 16 + pp;
    int xx = p & 63, yy = p >> 6;
    int c0 = cg * 8;
    float acc[8];
#pragma unroll
    for (int j = 0; j < 8; ++j) acc[j] = bias[c0 + j];
#pragma unroll
    for (int dy = -1; dy <= 1; ++dy) {
        int y2 = yy + dy;
        if (y2 < 0 || y2 >= 64) continue;
#pragma unroll
        for (int dx = -1; dx <= 1; ++dx) {
            int x2 = xx + dx;
            if (x2 < 0 || x2 >= 64) continue;
            unsigned short v[8];
            *(uint4*)v = *(const uint4*)&in[((size_t)b * NPIX + y2 * 64 + x2) * 128 + c0];
            const float* wr = wT + ((dy + 1) * 3 + dx + 1) * 128 + c0;
#pragma unroll
            for (int j = 0; j < 8; ++j) acc[j] += b2f(v[j]) * wr[j];
        }
    }
    unsigned short o[8];
#pragma unroll
    for (int j = 0; j < 8; ++j) o[j] = f2b(fmaxf(acc[j], 0.f));
    *(uint4*)&out[((size_t)b * NPIX + p) * 128 + c0] = *(uint4*)o;
}

// ---------------- conv1x1 via bf16 MFMA, 128out x 64px tile ----------------
// input: in_t (bf16 NHWC) OR in_f32 (f32 NHWC + fused GN: gst 8-slot stats, gg, gbta; Cin must be 128)
// epilogues: out_t [+out_t2 dual split at o0>=128] (bf16) | out f32 NHWC (+res) | nchw=1: out f32 NCHW (+res NHWC)
// relu: 0 none, 1 all, 2 only blockIdx.y==0
__global__ __launch_bounds__(256) void conv_mfma_kernel(const unsigned short* __restrict__ in_t,
                                                        const float* __restrict__ in_f32,
                                                        const float* __restrict__ gst,
                                                        const float* __restrict__ gg,
                                                        const float* __restrict__ gbta,
                                                        const unsigned short* __restrict__ w,
                                                        const float* __restrict__ bias,
                                                        const float* __restrict__ res,
                                                        float* __restrict__ out,
                                                        unsigned short* __restrict__ out_t,
                                                        unsigned short* __restrict__ out_t2,
                                                        int Cin, int Cout, int relu, int nchw) {
    __shared__ __align__(16) unsigned short A_s[128][136];
    __shared__ __align__(16) unsigned short B_s[64][136];
    int b = blockIdx.z, p0 = blockIdx.x * 64, o0 = blockIdx.y * 128;
    int tx = threadIdx.x;
    int wave = tx >> 6, lane = tx & 63;
    int wm = wave & 1, wn = wave >> 1;
    int quad = lane >> 4, l16 = lane & 15;

    float mu = 0.f, rr = 1.f;
    if (in_f32) {
        float su = 0.f, sq = 0.f;
#pragma unroll
        for (int sl = 0; sl < 8; ++sl) {
            su += gst[(b * 8 + sl) * 16];
            sq += gst[(b * 8 + sl) * 16 + 1];
        }
        const float n = 1.f / (float)(CDIM * NPIX);
        mu = su * n;
        float var = sq * n - mu * mu;
        rr = rsqrtf(var + EPSN);
    }

    f32x4 acc[4][2];
#pragma unroll
    for (int mt = 0; mt < 4; ++mt) {
#pragma unroll
        for (int r = 0; r < 4; ++r) {
            float bv = bias[o0 + wm * 64 + mt * 16 + quad * 4 + r];
#pragma unroll
            for (int nt = 0; nt < 2; ++nt) acc[mt][nt][r] = bv;
        }
    }

    for (int k0 = 0; k0 < Cin; k0 += 128) {
#pragma unroll
        for (int j = 0; j < 8; ++j) {
            int idx = tx + 256 * j;
            int row = idx >> 4, c16 = idx & 15;
            *(uint4*)&A_s[row][c16 * 8] =
                *(const uint4*)&w[(size_t)(o0 + row) * Cin + k0 + c16 * 8];
        }
        if (in_f32) {
#pragma unroll
            for (int j = 0; j < 4; ++j) {
                int idx = tx + 256 * j;
                int row = idx >> 4, c16 = idx & 15;
                int ch = c16 * 8;  // Cin==128
                const float* ip = &in_f32[((size_t)b * NPIX + p0 + row) * 128 + ch];
                float4 v0 = *(const float4*)ip;
                float4 v1 = *(const float4*)(ip + 4);
                unsigned short o[8];
                o[0] = f2b((v0.x - mu) * rr * gg[ch + 0] + gbta[ch + 0]);
                o[1] = f2b((v0.y - mu) * rr * gg[ch + 1] + gbta[ch + 1]);
                o[2] = f2b((v0.z - mu) * rr * gg[ch + 2] + gbta[ch + 2]);
                o[3] = f2b((v0.w - mu) * rr * gg[ch + 3] + gbta[ch + 3]);
                o[4] = f2b((v1.x - mu) * rr * gg[ch + 4] + gbta[ch + 4]);
                o[5] = f2b((v1.y - mu) * rr * gg[ch + 5] + gbta[ch + 5]);
                o[6] = f2b((v1.z - mu) * rr * gg[ch + 6] + gbta[ch + 6]);
                o[7] = f2b((v1.w - mu) * rr * gg[ch + 7] + gbta[ch + 7]);
                *(uint4*)&B_s[row][c16 * 8] = *(uint4*)o;
            }
        } else {
#pragma unroll
            for (int j = 0; j < 4; ++j) {
                int idx = tx + 256 * j;
                int row = idx >> 4, c16 = idx & 15;
                *(uint4*)&B_s[row][c16 * 8] =
                    *(const uint4*)&in_t[((size_t)b * NPIX + p0 + row) * Cin + k0 + c16 * 8];
            }
        }
        __syncthreads();
#pragma unroll
        for (int ks = 0; ks < 128; ks += 32) {
            short8 af[4], bf[2];
#pragma unroll
            for (int mt = 0; mt < 4; ++mt)
                af[mt] = *(const short8*)&A_s[wm * 64 + mt * 16 + l16][ks + quad * 8];
#pragma unroll
            for (int nt = 0; nt < 2; ++nt)
                bf[nt] = *(const short8*)&B_s[wn * 32 + nt * 16 + l16][ks + quad * 8];
#pragma unroll
            for (int mt = 0; mt < 4; ++mt)
#pragma unroll
                for (int nt = 0; nt < 2; ++nt)
                    acc[mt][nt] = __builtin_amdgcn_mfma_f32_16x16x32_bf16(
                        af[mt], bf[nt], acc[mt][nt], 0, 0, 0);
        }
        __syncthreads();
    }

    int dorelu = (relu == 1) || (relu == 2 && blockIdx.y == 0);
    if (out_t) {
#pragma unroll
        for (int mt = 0; mt < 4; ++mt) {
#pragma unroll
            for (int nt = 0; nt < 2; ++nt) {
                int p = p0 + wn * 32 + nt * 16 + l16;
                int ob = o0 + wm * 64 + mt * 16 + quad * 4;
                unsigned short* dbuf = out_t;
                int oc = ob;
                if (out_t2 && o0 >= 128) { dbuf = out_t2; oc = ob - 128; }
                ushort4 u;
                float v0 = acc[mt][nt][0], v1 = acc[mt][nt][1];
                float v2 = acc[mt][nt][2], v3 = acc[mt][nt][3];
                if (dorelu) { v0 = fmaxf(v0, 0.f); v1 = fmaxf(v1, 0.f);
                              v2 = fmaxf(v2, 0.f); v3 = fmaxf(v3, 0.f); }
                u.x = f2b(v0); u.y = f2b(v1); u.z = f2b(v2); u.w = f2b(v3);
                *(ushort4*)&dbuf[((size_t)b * NPIX + p) * Cout + oc] = u;
            }
        }
    } else if (!nchw) {
#pragma unroll
        for (int mt = 0; mt < 4; ++mt) {
#pragma unroll
            for (int nt = 0; nt < 2; ++nt) {
                int p = p0 + wn * 32 + nt * 16 + l16;
                int ob = o0 + wm * 64 + mt * 16 + quad * 4;
                size_t ix = ((size_t)b * NPIX + p) * Cout + ob;
                float4 v = make_float4(acc[mt][nt][0], acc[mt][nt][1],
                                       acc[mt][nt][2], acc[mt][nt][3]);
                if (dorelu) { v.x = fmaxf(v.x, 0.f); v.y = fmaxf(v.y, 0.f);
                              v.z = fmaxf(v.z, 0.f); v.w = fmaxf(v.w, 0.f); }
                if (res) {
                    float4 rv = *(const float4*)&res[ix];
                    v.x += rv.x; v.y += rv.y; v.z += rv.z; v.w += rv.w;
                }
                *(float4*)&out[ix] = v;
            }
        }
    } else {
        float* outb = out + (size_t)b * Cout * NPIX;
#pragma unroll
        for (int mt = 0; mt < 4; ++mt) {
#pragma unroll
            for (int nt = 0; nt < 2; ++nt) {
                int p = p0 + wn * 32 + nt * 16 + l16;
                int ob = o0 + wm * 64 + mt * 16 + quad * 4;
                float4 rv = make_float4(0.f, 0.f, 0.f, 0.f);
                if (res) rv = *(const float4*)&res[((size_t)b * NPIX + p) * 128 + ob];
#pragma unroll
                for (int r = 0; r < 4; ++r) {
                    float v = acc[mt][nt][r];
                    if (dorelu) v = fmaxf(v, 0.f);
                    v += (r == 0 ? rv.x : r == 1 ? rv.y : r == 2 ? rv.z : rv.w);
                    outb[(size_t)(ob + r) * NPIX + p] = v;
                }
            }
        }
    }
}

// ---------------- MFMA window attention, both orientations in one launch ----------------
__global__ __launch_bounds__(256) void attn_dual_kernel(const unsigned short* __restrict__ t_t,
                                                        float* __restrict__ a0,
                                                        float* __restrict__ a1) {
    __shared__ __align__(16) unsigned short Vt[16][264];
    int wi = blockIdx.x, head = blockIdx.y;
    int z = blockIdx.z;
    int b = z >> 1, which = z & 1;
    int qoff = which ? 384 : 0;
    int koff = which ? 512 : 128;
    int mode = which;
    float* a_out = which ? a1 : a0;
    int tx = threadIdx.x;
    int wave = tx >> 6, l = tx & 63;
    int l32 = l & 31, half = l >> 5;
    const size_t base = (size_t)b * NPIX;
    const int hc = head * 16;

    {
        int p = tok2pix(mode, wi, tx);
        const unsigned short* vp = &t_t[(base + p) * 640 + 256 + hc];
        unsigned short tmp[16];
        *(uint4*)&tmp[0] = *(const uint4*)vp;
        *(uint4*)&tmp[8] = *(const uint4*)(vp + 8);
#pragma unroll
        for (int d = 0; d < 16; ++d) Vt[d][tx] = tmp[d];
    }
    __syncthreads();

    for (int qi = 0; qi < 2; ++qi) {
        int qs = qi * 4 + wave;
        int qp = tok2pix(mode, wi, qs * 32 + l32);
        short8 qf = *(const short8*)&t_t[(base + qp) * 640 + qoff + hc + half * 8];
        f32x16 o_acc;
#pragma unroll
        for (int r = 0; r < 16; ++r) o_acc[r] = 0.f;
        float rs = 0.f;
#pragma unroll
        for (int nt = 0; nt < 8; ++nt) {
            int kp = tok2pix(mode, wi, nt * 32 + l32);
            short8 kf = *(const short8*)&t_t[(base + kp) * 640 + koff + hc + half * 8];
            f32x16 zz;
#pragma unroll
            for (int r = 0; r < 16; ++r) zz[r] = 0.f;
            f32x16 s = __builtin_amdgcn_mfma_f32_32x32x16_bf16(kf, qf, zz, 0, 0, 0);
            unsigned int pk[8];
#pragma unroll
            for (int i = 0; i < 8; ++i) {
                float e0 = __expf(s[2 * i]);
                float e1 = __expf(s[2 * i + 1]);
                rs += e0 + e1;
                pk[i] = __builtin_amdgcn_perm(__float_as_uint(e1), __float_as_uint(e0),
                                              0x07060302u);
            }
            unsigned int xpk[8];
#pragma unroll
            for (int i = 0; i < 8; ++i)
                xpk[i] = (unsigned int)__shfl_xor((int)pk[i], 32, 64);
            unsigned int u0[4], u1[4];
            if (half == 0) {
                u0[0] = pk[0]; u0[1] = pk[1]; u0[2] = xpk[0]; u0[3] = xpk[1];
                u1[0] = pk[4]; u1[1] = pk[5]; u1[2] = xpk[4]; u1[3] = xpk[5];
            } else {
                u0[0] = xpk[2]; u0[1] = xpk[3]; u0[2] = pk[2]; u0[3] = pk[3];
                u1[0] = xpk[6]; u1[1] = xpk[7]; u1[2] = pk[6]; u1[3] = pk[7];
            }
            short8 vf0, vf1;
#pragma unroll
            for (int r = 0; r < 8; ++r) { vf0[r] = 0; vf1[r] = 0; }
            if (l32 < 16) {
                vf0 = *(const short8*)&Vt[l32][nt * 32 + half * 8];
                vf1 = *(const short8*)&Vt[l32][nt * 32 + 16 + half * 8];
            }
            o_acc = __builtin_amdgcn_mfma_f32_32x32x16_bf16(vf0, *(short8*)u0, o_acc, 0, 0, 0);
            o_acc = __builtin_amdgcn_mfma_f32_32x32x16_bf16(vf1, *(short8*)u1, o_acc, 0, 0, 0);
        }
        rs += __shfl_xor(rs, 32, 64);
        float rinv = 1.f / rs;
        float* dst = a_out + (base + qp) * 128 + hc;
#pragma unroll
        for (int r = 0; r < 8; ++r) {
            int d = (r & 3) + 8 * (r >> 2) + 4 * half;
            dst[d] = o_acc[r] * rinv;
        }
    }
}

// ---------------- m_t = bf16((a0 + a1 + cpe(v0)) * act_res)  (all NHWC) ----------------
__global__ __launch_bounds__(256) void mul3_cpe_kernel(const float* __restrict__ a0,
                                                       const float* __restrict__ a1,
                                                       const unsigned short* __restrict__ act,
                                                       const unsigned short* __restrict__ t_t,
                                                       const float* __restrict__ wT,
                                                       const float* __restrict__ bsum,
                                                       unsigned short* __restrict__ dst) {
    int b = blockIdx.y;
    int tx = threadIdx.x;
    int cg = tx & 15, pp = tx >> 4;
    int p = blockIdx.x * 16 + pp;
    int xx = p & 63, yy = p >> 6;
    int c0 = cg * 8;
    float acc[8];
#pragma unroll
    for (int j = 0; j < 8; ++j) acc[j] = bsum[c0 + j];
#pragma unroll
    for (int dy = -1; dy <= 1; ++dy) {
        int y2 = yy + dy;
        if (y2 < 0 || y2 >= 64) continue;
#pragma unroll
        for (int dx = -1; dx <= 1; ++dx) {
            int x2 = xx + dx;
            if (x2 < 0 || x2 >= 64) continue;
            int pn = y2 * 64 + x2;
            unsigned short v[8];
            *(uint4*)v = *(const uint4*)&t_t[((size_t)b * NPIX + pn) * 640 + 256 + c0];
            const float* wr = wT + ((dy + 1) * 3 + dx + 1) * 128 + c0;
#pragma unroll
            for (int j = 0; j < 8; ++j) acc[j] += b2f(v[j]) * wr[j];
        }
    }
    size_t base = ((size_t)b * NPIX + p) * 128 + c0;
    float4 x0 = *(const float4*)&a0[base];
    float4 x1 = *(const float4*)&a0[base + 4];
    float4 y0 = *(const float4*)&a1[base];
    float4 y1 = *(const float4*)&a1[base + 4];
    unsigned short t[8];
    *(uint4*)t = *(const uint4*)&act[base];
    unsigned short r[8];
    r[0] = f2b((x0.x + y0.x + acc[0]) * b2f(t[0]));
    r[1] = f2b((x0.y + y0.y + acc[1]) * b2f(t[1]));
    r[2] = f2b((x0.z + y0.z + acc[2]) * b2f(t[2]));
    r[3] = f2b((x0.w + y0.w + acc[3]) * b2f(t[3]));
    r[4] = f2b((x1.x + y1.x + acc[4]) * b2f(t[4]));
    r[5] = f2b((x1.y + y1.y + acc[5]) * b2f(t[5]));
    r[6] = f2b((x1.z + y1.z + acc[6]) * b2f(t[6]));
    r[7] = f2b((x1.w + y1.w + acc[7]) * b2f(t[7]));
    *(uint4*)&dst[base] = *(uint4*)r;
}

extern "C" void kernel_launch(void* const* d_in, const int* in_sizes, int n_in,
                              void* d_out, int out_size, void* d_ws, size_t ws_size,
                              hipStream_t stream) {
    const float* x       = (const float*)d_in[0];
    const float* eca_w   = (const float*)d_in[1];
    const float* esa_al  = (const float*)d_in[2];
    const float* cpe1_w  = (const float*)d_in[3];  const float* cpe1_b = (const float*)d_in[4];
    const float* g1      = (const float*)d_in[5];  const float* b1     = (const float*)d_in[6];
    const float* actp_w  = (const float*)d_in[7];  const float* actp_b = (const float*)d_in[8];
    const float* inp_w   = (const float*)d_in[9];  const float* inp_b  = (const float*)d_in[10];
    const float* dwc_w   = (const float*)d_in[11]; const float* dwc_b  = (const float*)d_in[12];
    const float* qkv_w   = (const float*)d_in[13]; const float* qkv_b  = (const float*)d_in[14];
    const float* eaax_w  = (const float*)d_in[15]; const float* eaax_b = (const float*)d_in[16];
    const float* eaay_w  = (const float*)d_in[17]; const float* eaay_b = (const float*)d_in[18];
    const float* outp_w  = (const float*)d_in[19]; const float* outp_b = (const float*)d_in[20];
    const float* cpe2_w  = (const float*)d_in[21]; const float* cpe2_b = (const float*)d_in[22];
    const float* g2      = (const float*)d_in[23]; const float* b2     = (const float*)d_in[24];
    const float* mlp1_w  = (const float*)d_in[25]; const float* mlp1_b = (const float*)d_in[26];
    const float* mlp2_w  = (const float*)d_in[27]; const float* mlp2_b = (const float*)d_in[28];

    float* ws = (float*)d_ws;
    unsigned short* U = (unsigned short*)d_ws;
    const size_t E = (size_t)BATCH * CDIM * NPIX;  // 4,194,304

    float* y_nhwc  = ws;                // [0,E)  esa out; later a0
    float* a0      = ws;
    float* sc_nhwc = ws + E;            // [E,2E) shortcut (live to outp)
    unsigned short* act_t = U + 5 * E;  // [2.5E,3E)
    unsigned short* it_t  = U + 6 * E;  // [3E,3.5E)
    unsigned short* tin_t = U + 7 * E;  // [3.5E,4E)
    float* a1      = ws + 4 * E;        // [4E,5E)
    unsigned short* t_t   = U + 10 * E; // [5E,7.5E)
    unsigned short* m_t   = U + 15 * E; // [7.5E,8E)
    float* out_nhwc = ws + 8 * E;       // [8E,9E)
    float* out2    = ws + 2 * E;        // [2E,3E)  (act_t dead by then)
    unsigned short* hid_t = U + 10 * E; // [5E,7E)  (t_t dead after mul3_cpe)
    unsigned short* wpool = U + 20 * E; // 262144 bf16
    unsigned short* wq  = wpool;
    unsigned short* wm1 = wpool + 81920;
    unsigned short* wm2 = wpool + 147456;
    unsigned short* wai = wpool + 212992;   // actp rows 0-127, inp rows 128-255 (contiguous)
    unsigned short* wo  = wpool + 245760;
    float* fb     = ws + 10 * E + 131072;
    float* meanb  = fb;            // 1024
    float* gstats = fb + 2048;     // 2048: gn1 [0,1024), gn2 [1024,2048)
    float* qb_r   = fb + 4096;     // 640
    float* wsT    = fb + 4736;     // 1152
    float* bsum   = fb + 5888;     // 128
    float* cpe1T  = fb + 6016;     // 1152
    float* dwcT   = fb + 7168;     // 1152
    float* cpe2T  = fb + 8320;     // 1152
    float* abi    = fb + 9472;     // 256

    hipMemsetAsync(gstats, 0, 2048 * sizeof(float), stream);
    convert_w_kernel<<<1046, 256, 0, stream>>>(qkv_w, mlp1_w, mlp2_w, actp_w, inp_w, outp_w,
                                               qkv_b, eaax_w, eaax_b, eaay_w, eaay_b,
                                               cpe1_w, dwc_w, cpe2_w, actp_b, inp_b,
                                               wpool, qb_r, wsT, bsum, cpe1T, dwcT, cpe2T, abi);

    // 1) ECA + ESA (gate inline) with transpose -> y (f32 NHWC)
    mean_bc_kernel<<<BATCH * CDIM, 256, 0, stream>>>(x, meanb);
    esa_tr_kernel<<<dim3(64, BATCH), 256, 0, stream>>>(x, meanb, eca_w, esa_al, y_nhwc);
    // 2) shortcut = y + cpe1(y), fused GN1 stats
    cpe_f32_kernel<<<dim3(256, BATCH), 256, 0, stream>>>(y_nhwc, cpe1T, cpe1_b, sc_nhwc, gstats);
    // 3+4+5a) merged actp+inp conv with fused GN1 apply: sc_nhwc -> act_t (relu), it_t
    conv_mfma_kernel<<<dim3(64, 2, BATCH), 256, 0, stream>>>(nullptr, sc_nhwc, gstats, g1, b1,
                                                             wai, abi, nullptr, nullptr,
                                                             act_t, it_t, 128, 128, 2, 0);
    // 5b) tin = relu(dwc(it))
    dwc_bf16_kernel<<<dim3(256, BATCH), 256, 0, stream>>>(it_t, dwcT, dwc_b, tin_t);
    // 6) qkv -> t_t (bf16 NHWC, 640 grouped)
    conv_mfma_kernel<<<dim3(64, 5, BATCH), 256, 0, stream>>>(tin_t, nullptr, nullptr, nullptr,
                                                             nullptr, wq, qb_r, nullptr, nullptr,
                                                             t_t, nullptr, 128, 640, 0, 0);
    // 7) both attentions -> a0, a1
    attn_dual_kernel<<<dim3(16, 8, 2 * BATCH), 256, 0, stream>>>(t_t, a0, a1);
    // 8) m_t = bf16((a0+a1+cpe(v0))*act) ; out = outp(m) + shortcut -> out_nhwc
    mul3_cpe_kernel<<<dim3(256, BATCH), 256, 0, stream>>>(a0, a1, act_t, t_t, wsT, bsum, m_t);
    conv_mfma_kernel<<<dim3(64, 1, BATCH), 256, 0, stream>>>(m_t, nullptr, nullptr, nullptr,
                                                             nullptr, wo, outp_b, sc_nhwc,
                                                             out_nhwc, nullptr, nullptr,
                                                             128, 128, 0, 0);
    // 9) out2 = out + cpe2(out), fused GN2 stats
    cpe_f32_kernel<<<dim3(256, BATCH), 256, 0, stream>>>(out_nhwc, cpe2T, cpe2_b, out2,
                                                         gstats + 1024);
    // 10+11) mlp1 with fused GN2 apply -> hid_t ; mlp2 + out2 residual -> d_out (NCHW)
    conv_mfma_kernel<<<dim3(64, 4, BATCH), 256, 0, stream>>>(nullptr, out2, gstats + 1024, g2, b2,
                                                             wm1, mlp1_b, nullptr, nullptr,
                                                             hid_t, nullptr, 128, 512, 1, 0);
    conv_mfma_kernel<<<dim3(64, 1, BATCH), 256, 0, stream>>>(hid_t, nullptr, nullptr, nullptr,
                                                             nullptr, wm2, mlp2_b, out2,
                                                             (float*)d_out, nullptr, nullptr,
                                                             512, 128, 0, 1);
}

// Round 10
// 313.297 us; speedup vs baseline: 4.1364x; 1.0023x over previous
//
#include <hip/hip_runtime.h>

#define NPIX 4096
#define CDIM 128
#define BATCH 8
#define EPSN 1e-5f
#define LOG2E 1.44269504088896340736f

typedef __attribute__((ext_vector_type(8))) short short8;
typedef __attribute__((ext_vector_type(4))) float f32x4;
typedef __attribute__((ext_vector_type(16))) float f32x16;

__device__ __forceinline__ float sigmoidf_(float x) { return 1.f / (1.f + __expf(-x)); }

__device__ __forceinline__ unsigned short f2b(float f) {
    unsigned int u = __float_as_uint(f);
    unsigned int r = (u + 0x7FFF + ((u >> 16) & 1)) >> 16;  // RNE
    return (unsigned short)r;
}
__device__ __forceinline__ float b2f(unsigned short u) {
    return __uint_as_float((unsigned int)u << 16);
}

// window token -> pixel index
__device__ __forceinline__ int tok2pix(int mode, int wi, int l) {
    return (mode == 0) ? ((l >> 2) * 64 + wi * 4 + (l & 3))
                       : ((wi * 4 + (l >> 6)) * 64 + (l & 63));
}

// ---------------- weight conversion / reorder / transposes ----------------
// q0/q1 weight+bias groups pre-scaled by log2(e) so attention can use native exp2.
__global__ __launch_bounds__(256) void convert_w_kernel(const float* __restrict__ qkv_w,
                                                        const float* __restrict__ mlp1_w,
                                                        const float* __restrict__ mlp2_w,
                                                        const float* __restrict__ actp_w,
                                                        const float* __restrict__ inp_w,
                                                        const float* __restrict__ outp_w,
                                                        const float* __restrict__ qkv_b,
                                                        const float* __restrict__ eaax_w,
                                                        const float* __restrict__ eaax_b,
                                                        const float* __restrict__ eaay_w,
                                                        const float* __restrict__ eaay_b,
                                                        const float* __restrict__ cpe1_w,
                                                        const float* __restrict__ dwc_w,
                                                        const float* __restrict__ cpe2_w,
                                                        const float* __restrict__ actp_b,
                                                        const float* __restrict__ inp_b,
                                                        unsigned short* __restrict__ dst,
                                                        float* __restrict__ qb_r,
                                                        float* __restrict__ wsT,
                                                        float* __restrict__ bsum,
                                                        float* __restrict__ cpe1T,
                                                        float* __restrict__ dwcT,
                                                        float* __restrict__ cpe2T,
                                                        float* __restrict__ abi) {
    int i = blockIdx.x * 256 + threadIdx.x;
    if (i >= 267776) return;
    if (i < 262144) {
        float v;
        if (i < 81920) {
            int o = i >> 7, c = i & 127;              // reordered: o_new = g*128+cc
            int g = o >> 7;
            v = qkv_w[(size_t)(5 * (o & 127) + g) * 128 + c];
            if (g == 0 || g == 3) v *= LOG2E;         // q0/q1 pre-scale for exp2
        } else if (i < 147456) v = mlp1_w[i - 81920];
        else if (i < 212992)   v = mlp2_w[i - 147456];
        else if (i < 229376)   v = actp_w[i - 212992];
        else if (i < 245760)   v = inp_w[i - 229376];
        else                   v = outp_w[i - 245760];
        dst[i] = f2b(v);
    } else {
        int j = i - 262144;
        if (j < 640) {
            int g = j >> 7;
            float v = qkv_b[5 * (j & 127) + g];
            if (g == 0 || g == 3) v *= LOG2E;
            qb_r[j] = v;
        }
        else if (j < 1792) {
            int idx = j - 640; int k = idx >> 7, c = idx & 127;
            wsT[idx] = eaax_w[c * 9 + k] + eaay_w[c * 9 + k];
        } else if (j < 1920) bsum[j - 1792] = eaax_b[j - 1792] + eaay_b[j - 1792];
        else if (j < 3072) {
            int idx = j - 1920; int k = idx >> 7, c = idx & 127;
            cpe1T[idx] = cpe1_w[c * 9 + k];
        } else if (j < 4224) {
            int idx = j - 3072; int k = idx >> 7, c = idx & 127;
            dwcT[idx] = dwc_w[c * 9 + k];
        } else if (j < 5376) {
            int idx = j - 4224; int k = idx >> 7, c = idx & 127;
            cpe2T[idx] = cpe2_w[c * 9 + k];
        } else {
            int idx = j - 5376;
            abi[idx] = (idx < 128) ? actp_b[idx] : inp_b[idx - 128];
        }
    }
}

// ---------------- per-(b,c) mean over HW (x is NCHW input) ----------------
__global__ __launch_bounds__(256) void mean_bc_kernel(const float* __restrict__ x,
                                                      float* __restrict__ mean) {
    __shared__ float sb[4];
    int bc = blockIdx.x;
    const float* p = x + (size_t)bc * NPIX;
    float s = 0.f;
    for (int i = threadIdx.x; i < NPIX; i += 256) s += p[i];
#pragma unroll
    for (int off = 32; off > 0; off >>= 1) s += __shfl_down(s, off, 64);
    if ((threadIdx.x & 63) == 0) sb[threadIdx.x >> 6] = s;
    __syncthreads();
    if (threadIdx.x == 0) mean[bc] = (sb[0] + sb[1] + sb[2] + sb[3]) * (1.f / (float)NPIX);
}

// ---------------- ESA+ECA fused (gate computed inline) with NCHW->NHWC transpose ----------------
__global__ __launch_bounds__(256) void esa_tr_kernel(const float* __restrict__ x,
                                                     const float* __restrict__ mean,
                                                     const float* __restrict__ w5,
                                                     const float* __restrict__ alpha_p,
                                                     float* __restrict__ y) {
    __shared__ float tile[128][65];
    __shared__ float smx[4][64], smn[4][64], ssc[64], gat[128];
    int b = blockIdx.y, p0 = blockIdx.x * 64;
    int tx = threadIdx.x, pl = tx & 63, part = tx >> 6;
    const float* xb = x + (size_t)b * CDIM * NPIX;
    const float* mb = mean + b * CDIM;
    for (int c = part; c < CDIM; c += 4)
        tile[c][pl] = xb[(size_t)c * NPIX + p0 + pl];
    __syncthreads();
    float mx = -1e30f, mn = 1e30f;
#pragma unroll
    for (int cc = 0; cc < 32; ++cc) {
        int c = part * 32 + cc;
        float v = tile[c][pl] - mb[c];
        mx = fmaxf(mx, v); mn = fminf(mn, v);
    }
    smx[part][pl] = mx; smn[part][pl] = mn;
    __syncthreads();
    if (tx < 128) {
        float s = 0.f;
#pragma unroll
        for (int k = 0; k < 5; ++k) {
            int cc = tx + k - 2;
            if (cc >= 0 && cc < CDIM) s += w5[k] * mb[cc];
        }
        gat[tx] = sigmoidf_(s);
    }
    if (part == 0) {
        float m1 = fmaxf(fmaxf(smx[0][pl], smx[1][pl]), fmaxf(smx[2][pl], smx[3][pl]));
        float m2 = fminf(fminf(smn[0][pl], smn[1][pl]), fminf(smn[2][pl], smn[3][pl]));
        float a = alpha_p[0];
        ssc[pl] = sigmoidf_(m1) * a + sigmoidf_(m2) * (1.f - a);
    }
    __syncthreads();
    int c2 = tx & 127, pr = tx >> 7;
    float* yb = y + ((size_t)b * NPIX + p0) * CDIM;
    float gv = gat[c2];
    for (int p = pr; p < 64; p += 2)
        yb[(size_t)p * CDIM + c2] = tile[c2][p] * (gv + ssc[p]);
}

// ---------------- NHWC f32 dwconv3 + residual + fused PER-BATCH GN stats (8 spread slots) ----------------
__global__ __launch_bounds__(256) void cpe_f32_kernel(const float* __restrict__ in,
                                                      const float* __restrict__ wT,
                                                      const float* __restrict__ bias,
                                                      float* __restrict__ out,
                                                      float* __restrict__ stats) {
    __shared__ float sb[8];
    int b = blockIdx.y, tx = threadIdx.x;
    int cg = tx & 15, pp = tx >> 4;
    int p = blockIdx.x * 16 + pp;
    int xx = p & 63, yy = p >> 6;
    int c0 = cg * 8;
    float acc[8], ctr[8];
#pragma unroll
    for (int j = 0; j < 8; ++j) acc[j] = bias[c0 + j];
#pragma unroll
    for (int dy = -1; dy <= 1; ++dy) {
        int y2 = yy + dy;
        if (y2 < 0 || y2 >= 64) continue;
#pragma unroll
        for (int dx = -1; dx <= 1; ++dx) {
            int x2 = xx + dx;
            if (x2 < 0 || x2 >= 64) continue;
            const float* ip = &in[((size_t)b * NPIX + y2 * 64 + x2) * 128 + c0];
            float4 v0 = *(const float4*)ip;
            float4 v1 = *(const float4*)(ip + 4);
            const float* wr = wT + ((dy + 1) * 3 + dx + 1) * 128 + c0;
            acc[0] += v0.x * wr[0]; acc[1] += v0.y * wr[1];
            acc[2] += v0.z * wr[2]; acc[3] += v0.w * wr[3];
            acc[4] += v1.x * wr[4]; acc[5] += v1.y * wr[5];
            acc[6] += v1.z * wr[6]; acc[7] += v1.w * wr[7];
            if (dy == 0 && dx == 0) {
                ctr[0] = v0.x; ctr[1] = v0.y; ctr[2] = v0.z; ctr[3] = v0.w;
                ctr[4] = v1.x; ctr[5] = v1.y; ctr[6] = v1.z; ctr[7] = v1.w;
            }
        }
    }
    float s = 0.f, s2 = 0.f;
    float r[8];
#pragma unroll
    for (int j = 0; j < 8; ++j) {
        r[j] = ctr[j] + acc[j];
        s += r[j]; s2 += r[j] * r[j];
    }
    float* op = &out[((size_t)b * NPIX + p) * 128 + c0];
    *(float4*)op = make_float4(r[0], r[1], r[2], r[3]);
    *(float4*)(op + 4) = make_float4(r[4], r[5], r[6], r[7]);
#pragma unroll
    for (int off = 32; off > 0; off >>= 1) {
        s += __shfl_down(s, off, 64);
        s2 += __shfl_down(s2, off, 64);
    }
    int wv = tx >> 6;
    if ((tx & 63) == 0) { sb[wv] = s; sb[4 + wv] = s2; }
    __syncthreads();
    if (tx == 0) {
        int slot = (b * 8 + (blockIdx.x & 7)) * 16;
        atomicAdd(&stats[slot], sb[0] + sb[1] + sb[2] + sb[3]);
        atomicAdd(&stats[slot + 1], sb[4] + sb[5] + sb[6] + sb[7]);
    }
}

// ---------------- NHWC bf16 dwconv3 + bias + relu -> bf16 ----------------
__global__ __launch_bounds__(256) void dwc_bf16_kernel(const unsigned short* __restrict__ in,
                                                       const float* __restrict__ wT,
                                                       const float* __restrict__ bias,
                                                       unsigned short* __restrict__ out) {
    int b = blockIdx.y, tx = threadIdx.x;
    int cg = tx & 15, pp = tx >> 4;
    int p = blockIdx.x * 16 + pp;
    int xx = p & 63, yy = p >> 6;
    int c0 = cg * 8;
    float acc[8];
#pragma unroll
    for (int j = 0; j < 8; ++j) acc[j] = bias[c0 + j];
#pragma unroll
    for (int dy = -1; dy <= 1; ++dy) {
        int y2 = yy + dy;
        if (y2 < 0 || y2 >= 64) continue;
#pragma unroll
        for (int dx = -1; dx <= 1; ++dx) {
            int x2 = xx + dx;
            if (x2 < 0 || x2 >= 64) continue;
            unsigned short v[8];
            *(uint4*)v = *(const uint4*)&in[((size_t)b * NPIX + y2 * 64 + x2) * 128 + c0];
            const float* wr = wT + ((dy + 1) * 3 + dx + 1) * 128 + c0;
#pragma unroll
            for (int j = 0; j < 8; ++j) acc[j] += b2f(v[j]) * wr[j];
        }
    }
    unsigned short o[8];
#pragma unroll
    for (int j = 0; j < 8; ++j) o[j] = f2b(fmaxf(acc[j], 0.f));
    *(uint4*)&out[((size_t)b * NPIX + p) * 128 + c0] = *(uint4*)o;
}

// ---------------- conv1x1 via bf16 MFMA, 128out x 64px tile ----------------
__global__ __launch_bounds__(256) void conv_mfma_kernel(const unsigned short* __restrict__ in_t,
                                                        const float* __restrict__ in_f32,
                                                        const float* __restrict__ gst,
                                                        const float* __restrict__ gg,
                                                        const float* __restrict__ gbta,
                                                        const unsigned short* __restrict__ w,
                                                        const float* __restrict__ bias,
                                                        const float* __restrict__ res,
                                                        float* __restrict__ out,
                                                        unsigned short* __restrict__ out_t,
                                                        unsigned short* __restrict__ out_t2,
                                                        int Cin, int Cout, int relu, int nchw) {
    __shared__ __align__(16) unsigned short A_s[128][136];
    __shared__ __align__(16) unsigned short B_s[64][136];
    int b = blockIdx.z, p0 = blockIdx.x * 64, o0 = blockIdx.y * 128;
    int tx = threadIdx.x;
    int wave = tx >> 6, lane = tx & 63;
    int wm = wave & 1, wn = wave >> 1;
    int quad = lane >> 4, l16 = lane & 15;

    float mu = 0.f, rr = 1.f;
    if (in_f32) {
        float su = 0.f, sq = 0.f;
#pragma unroll
        for (int sl = 0; sl < 8; ++sl) {
            su += gst[(b * 8 + sl) * 16];
            sq += gst[(b * 8 + sl) * 16 + 1];
        }
        const float n = 1.f / (float)(CDIM * NPIX);
        mu = su * n;
        float var = sq * n - mu * mu;
        rr = rsqrtf(var + EPSN);
    }

    f32x4 acc[4][2];
#pragma unroll
    for (int mt = 0; mt < 4; ++mt) {
#pragma unroll
        for (int r = 0; r < 4; ++r) {
            float bv = bias[o0 + wm * 64 + mt * 16 + quad * 4 + r];
#pragma unroll
            for (int nt = 0; nt < 2; ++nt) acc[mt][nt][r] = bv;
        }
    }

    for (int k0 = 0; k0 < Cin; k0 += 128) {
#pragma unroll
        for (int j = 0; j < 8; ++j) {
            int idx = tx + 256 * j;
            int row = idx >> 4, c16 = idx & 15;
            *(uint4*)&A_s[row][c16 * 8] =
                *(const uint4*)&w[(size_t)(o0 + row) * Cin + k0 + c16 * 8];
        }
        if (in_f32) {
#pragma unroll
            for (int j = 0; j < 4; ++j) {
                int idx = tx + 256 * j;
                int row = idx >> 4, c16 = idx & 15;
                int ch = c16 * 8;  // Cin==128
                const float* ip = &in_f32[((size_t)b * NPIX + p0 + row) * 128 + ch];
                float4 v0 = *(const float4*)ip;
                float4 v1 = *(const float4*)(ip + 4);
                unsigned short o[8];
                o[0] = f2b((v0.x - mu) * rr * gg[ch + 0] + gbta[ch + 0]);
                o[1] = f2b((v0.y - mu) * rr * gg[ch + 1] + gbta[ch + 1]);
                o[2] = f2b((v0.z - mu) * rr * gg[ch + 2] + gbta[ch + 2]);
                o[3] = f2b((v0.w - mu) * rr * gg[ch + 3] + gbta[ch + 3]);
                o[4] = f2b((v1.x - mu) * rr * gg[ch + 4] + gbta[ch + 4]);
                o[5] = f2b((v1.y - mu) * rr * gg[ch + 5] + gbta[ch + 5]);
                o[6] = f2b((v1.z - mu) * rr * gg[ch + 6] + gbta[ch + 6]);
                o[7] = f2b((v1.w - mu) * rr * gg[ch + 7] + gbta[ch + 7]);
                *(uint4*)&B_s[row][c16 * 8] = *(uint4*)o;
            }
        } else {
#pragma unroll
            for (int j = 0; j < 4; ++j) {
                int idx = tx + 256 * j;
                int row = idx >> 4, c16 = idx & 15;
                *(uint4*)&B_s[row][c16 * 8] =
                    *(const uint4*)&in_t[((size_t)b * NPIX + p0 + row) * Cin + k0 + c16 * 8];
            }
        }
        __syncthreads();
#pragma unroll
        for (int ks = 0; ks < 128; ks += 32) {
            short8 af[4], bf[2];
#pragma unroll
            for (int mt = 0; mt < 4; ++mt)
                af[mt] = *(const short8*)&A_s[wm * 64 + mt * 16 + l16][ks + quad * 8];
#pragma unroll
            for (int nt = 0; nt < 2; ++nt)
                bf[nt] = *(const short8*)&B_s[wn * 32 + nt * 16 + l16][ks + quad * 8];
#pragma unroll
            for (int mt = 0; mt < 4; ++mt)
#pragma unroll
                for (int nt = 0; nt < 2; ++nt)
                    acc[mt][nt] = __builtin_amdgcn_mfma_f32_16x16x32_bf16(
                        af[mt], bf[nt], acc[mt][nt], 0, 0, 0);
        }
        __syncthreads();
    }

    int dorelu = (relu == 1) || (relu == 2 && blockIdx.y == 0);
    if (out_t) {
#pragma unroll
        for (int mt = 0; mt < 4; ++mt) {
#pragma unroll
            for (int nt = 0; nt < 2; ++nt) {
                int p = p0 + wn * 32 + nt * 16 + l16;
                int ob = o0 + wm * 64 + mt * 16 + quad * 4;
                unsigned short* dbuf = out_t;
                int oc = ob;
                if (out_t2 && o0 >= 128) { dbuf = out_t2; oc = ob - 128; }
                ushort4 u;
                float v0 = acc[mt][nt][0], v1 = acc[mt][nt][1];
                float v2 = acc[mt][nt][2], v3 = acc[mt][nt][3];
                if (dorelu) { v0 = fmaxf(v0, 0.f); v1 = fmaxf(v1, 0.f);
                              v2 = fmaxf(v2, 0.f); v3 = fmaxf(v3, 0.f); }
                u.x = f2b(v0); u.y = f2b(v1); u.z = f2b(v2); u.w = f2b(v3);
                *(ushort4*)&dbuf[((size_t)b * NPIX + p) * Cout + oc] = u;
            }
        }
    } else if (!nchw) {
#pragma unroll
        for (int mt = 0; mt < 4; ++mt) {
#pragma unroll
            for (int nt = 0; nt < 2; ++nt) {
                int p = p0 + wn * 32 + nt * 16 + l16;
                int ob = o0 + wm * 64 + mt * 16 + quad * 4;
                size_t ix = ((size_t)b * NPIX + p) * Cout + ob;
                float4 v = make_float4(acc[mt][nt][0], acc[mt][nt][1],
                                       acc[mt][nt][2], acc[mt][nt][3]);
                if (dorelu) { v.x = fmaxf(v.x, 0.f); v.y = fmaxf(v.y, 0.f);
                              v.z = fmaxf(v.z, 0.f); v.w = fmaxf(v.w, 0.f); }
                if (res) {
                    float4 rv = *(const float4*)&res[ix];
                    v.x += rv.x; v.y += rv.y; v.z += rv.z; v.w += rv.w;
                }
                *(float4*)&out[ix] = v;
            }
        }
    } else {
        float* outb = out + (size_t)b * Cout * NPIX;
#pragma unroll
        for (int mt = 0; mt < 4; ++mt) {
#pragma unroll
            for (int nt = 0; nt < 2; ++nt) {
                int p = p0 + wn * 32 + nt * 16 + l16;
                int ob = o0 + wm * 64 + mt * 16 + quad * 4;
                float4 rv = make_float4(0.f, 0.f, 0.f, 0.f);
                if (res) rv = *(const float4*)&res[((size_t)b * NPIX + p) * 128 + ob];
#pragma unroll
                for (int r = 0; r < 4; ++r) {
                    float v = acc[mt][nt][r];
                    if (dorelu) v = fmaxf(v, 0.f);
                    v += (r == 0 ? rv.x : r == 1 ? rv.y : r == 2 ? rv.z : rv.w);
                    outb[(size_t)(ob + r) * NPIX + p] = v;
                }
            }
        }
    }
}

// ---------------- MFMA window attention, both orientations in one launch ----------------
// q pre-scaled by log2(e) at weight-convert time -> native exp2; row-sum harvested from
// the PV MFMA via a ones-row at A row 16 (lands in o_acc[8] of half 0).
__global__ __launch_bounds__(256) void attn_dual_kernel(const unsigned short* __restrict__ t_t,
                                                        float* __restrict__ a0,
                                                        float* __restrict__ a1) {
    __shared__ __align__(16) unsigned short Vt[16][264];
    int wi = blockIdx.x, head = blockIdx.y;
    int z = blockIdx.z;
    int b = z >> 1, which = z & 1;
    int qoff = which ? 384 : 0;
    int koff = which ? 512 : 128;
    int mode = which;
    float* a_out = which ? a1 : a0;
    int tx = threadIdx.x;
    int wave = tx >> 6, l = tx & 63;
    int l32 = l & 31, half = l >> 5;
    const size_t base = (size_t)b * NPIX;
    const int hc = head * 16;

    {
        int p = tok2pix(mode, wi, tx);
        const unsigned short* vp = &t_t[(base + p) * 640 + 256 + hc];
        unsigned short tmp[16];
        *(uint4*)&tmp[0] = *(const uint4*)vp;
        *(uint4*)&tmp[8] = *(const uint4*)(vp + 8);
#pragma unroll
        for (int d = 0; d < 16; ++d) Vt[d][tx] = tmp[d];
    }
    __syncthreads();

    for (int qi = 0; qi < 2; ++qi) {
        int qs = qi * 4 + wave;
        int qp = tok2pix(mode, wi, qs * 32 + l32);
        short8 qf = *(const short8*)&t_t[(base + qp) * 640 + qoff + hc + half * 8];
        f32x16 o_acc;
#pragma unroll
        for (int r = 0; r < 16; ++r) o_acc[r] = 0.f;
#pragma unroll
        for (int nt = 0; nt < 8; ++nt) {
            int kp = tok2pix(mode, wi, nt * 32 + l32);
            short8 kf = *(const short8*)&t_t[(base + kp) * 640 + koff + hc + half * 8];
            f32x16 zz;
#pragma unroll
            for (int r = 0; r < 16; ++r) zz[r] = 0.f;
            f32x16 s = __builtin_amdgcn_mfma_f32_32x32x16_bf16(kf, qf, zz, 0, 0, 0);
            unsigned int pk[8];
#pragma unroll
            for (int i = 0; i < 8; ++i) {
                float e0 = exp2f(s[2 * i]);       // q pre-scaled by log2e
                float e1 = exp2f(s[2 * i + 1]);
                pk[i] = __builtin_amdgcn_perm(__float_as_uint(e1), __float_as_uint(e0),
                                              0x07060302u);
            }
            unsigned int xpk[8];
#pragma unroll
            for (int i = 0; i < 8; ++i)
                xpk[i] = (unsigned int)__shfl_xor((int)pk[i], 32, 64);
            unsigned int u0[4], u1[4];
            if (half == 0) {
                u0[0] = pk[0]; u0[1] = pk[1]; u0[2] = xpk[0]; u0[3] = xpk[1];
                u1[0] = pk[4]; u1[1] = pk[5]; u1[2] = xpk[4]; u1[3] = xpk[5];
            } else {
                u0[0] = xpk[2]; u0[1] = xpk[3]; u0[2] = pk[2]; u0[3] = pk[3];
                u1[0] = xpk[6]; u1[1] = xpk[7]; u1[2] = pk[6]; u1[3] = pk[7];
            }
            short8 vf0, vf1;
            if (l32 < 16) {
                vf0 = *(const short8*)&Vt[l32][nt * 32 + half * 8];
                vf1 = *(const short8*)&Vt[l32][nt * 32 + 16 + half * 8];
            } else if (l32 == 16) {
#pragma unroll
                for (int r = 0; r < 8; ++r) { vf0[r] = 0x3F80; vf1[r] = 0x3F80; }  // ones row
            } else {
#pragma unroll
                for (int r = 0; r < 8; ++r) { vf0[r] = 0; vf1[r] = 0; }
            }
            o_acc = __builtin_amdgcn_mfma_f32_32x32x16_bf16(vf0, *(short8*)u0, o_acc, 0, 0, 0);
            o_acc = __builtin_amdgcn_mfma_f32_32x32x16_bf16(vf1, *(short8*)u1, o_acc, 0, 0, 0);
        }
        // row 16 of PV output = sum_t P[t][col]  (only visible to half-0 lanes at r=8)
        float rs = o_acc[8];
        rs += __shfl_xor(rs, 32, 64);
        float rinv = 1.f / rs;
        float* dst = a_out + (base + qp) * 128 + hc;
#pragma unroll
        for (int r = 0; r < 8; ++r) {
            int d = (r & 3) + 8 * (r >> 2) + 4 * half;
            dst[d] = o_acc[r] * rinv;
        }
    }
}

// ---------------- m_t = bf16((a0 + a1 + cpe(v0)) * act_res)  (all NHWC) ----------------
__global__ __launch_bounds__(256) void mul3_cpe_kernel(const float* __restrict__ a0,
                                                       const float* __restrict__ a1,
                                                       const unsigned short* __restrict__ act,
                                                       const unsigned short* __restrict__ t_t,
                                                       const float* __restrict__ wT,
                                                       const float* __restrict__ bsum,
                                                       unsigned short* __restrict__ dst) {
    int b = blockIdx.y;
    int tx = threadIdx.x;
    int cg = tx & 15, pp = tx >> 4;
    int p = blockIdx.x * 16 + pp;
    int xx = p & 63, yy = p >> 6;
    int c0 = cg * 8;
    float acc[8];
#pragma unroll
    for (int j = 0; j < 8; ++j) acc[j] = bsum[c0 + j];
#pragma unroll
    for (int dy = -1; dy <= 1; ++dy) {
        int y2 = yy + dy;
        if (y2 < 0 || y2 >= 64) continue;
#pragma unroll
        for (int dx = -1; dx <= 1; ++dx) {
            int x2 = xx + dx;
            if (x2 < 0 || x2 >= 64) continue;
            int pn = y2 * 64 + x2;
            unsigned short v[8];
            *(uint4*)v = *(const uint4*)&t_t[((size_t)b * NPIX + pn) * 640 + 256 + c0];
            const float* wr = wT + ((dy + 1) * 3 + dx + 1) * 128 + c0;
#pragma unroll
            for (int j = 0; j < 8; ++j) acc[j] += b2f(v[j]) * wr[j];
        }
    }
    size_t base = ((size_t)b * NPIX + p) * 128 + c0;
    float4 x0 = *(const float4*)&a0[base];
    float4 x1 = *(const float4*)&a0[base + 4];
    float4 y0 = *(const float4*)&a1[base];
    float4 y1 = *(const float4*)&a1[base + 4];
    unsigned short t[8];
    *(uint4*)t = *(const uint4*)&act[base];
    unsigned short r[8];
    r[0] = f2b((x0.x + y0.x + acc[0]) * b2f(t[0]));
    r[1] = f2b((x0.y + y0.y + acc[1]) * b2f(t[1]));
    r[2] = f2b((x0.z + y0.z + acc[2]) * b2f(t[2]));
    r[3] = f2b((x0.w + y0.w + acc[3]) * b2f(t[3]));
    r[4] = f2b((x1.x + y1.x + acc[4]) * b2f(t[4]));
    r[5] = f2b((x1.y + y1.y + acc[5]) * b2f(t[5]));
    r[6] = f2b((x1.z + y1.z + acc[6]) * b2f(t[6]));
    r[7] = f2b((x1.w + y1.w + acc[7]) * b2f(t[7]));
    *(uint4*)&dst[base] = *(uint4*)r;
}

extern "C" void kernel_launch(void* const* d_in, const int* in_sizes, int n_in,
                              void* d_out, int out_size, void* d_ws, size_t ws_size,
                              hipStream_t stream) {
    const float* x       = (const float*)d_in[0];
    const float* eca_w   = (const float*)d_in[1];
    const float* esa_al  = (const float*)d_in[2];
    const float* cpe1_w  = (const float*)d_in[3];  const float* cpe1_b = (const float*)d_in[4];
    const float* g1      = (const float*)d_in[5];  const float* b1     = (const float*)d_in[6];
    const float* actp_w  = (const float*)d_in[7];  const float* actp_b = (const float*)d_in[8];
    const float* inp_w   = (const float*)d_in[9];  const float* inp_b  = (const float*)d_in[10];
    const float* dwc_w   = (const float*)d_in[11]; const float* dwc_b  = (const float*)d_in[12];
    const float* qkv_w   = (const float*)d_in[13]; const float* qkv_b  = (const float*)d_in[14];
    const float* eaax_w  = (const float*)d_in[15]; const float* eaax_b = (const float*)d_in[16];
    const float* eaay_w  = (const float*)d_in[17]; const float* eaay_b = (const float*)d_in[18];
    const float* outp_w  = (const float*)d_in[19]; const float* outp_b = (const float*)d_in[20];
    const float* cpe2_w  = (const float*)d_in[21]; const float* cpe2_b = (const float*)d_in[22];
    const float* g2      = (const float*)d_in[23]; const float* b2     = (const float*)d_in[24];
    const float* mlp1_w  = (const float*)d_in[25]; const float* mlp1_b = (const float*)d_in[26];
    const float* mlp2_w  = (const float*)d_in[27]; const float* mlp2_b = (const float*)d_in[28];

    float* ws = (float*)d_ws;
    unsigned short* U = (unsigned short*)d_ws;
    const size_t E = (size_t)BATCH * CDIM * NPIX;  // 4,194,304

    float* y_nhwc  = ws;                // [0,E)  esa out; later a0
    float* a0      = ws;
    float* sc_nhwc = ws + E;            // [E,2E) shortcut (live to outp)
    unsigned short* act_t = U + 5 * E;  // [2.5E,3E)
    unsigned short* it_t  = U + 6 * E;  // [3E,3.5E)
    unsigned short* tin_t = U + 7 * E;  // [3.5E,4E)
    float* a1      = ws + 4 * E;        // [4E,5E)
    unsigned short* t_t   = U + 10 * E; // [5E,7.5E)
    unsigned short* m_t   = U + 15 * E; // [7.5E,8E)
    float* out_nhwc = ws + 8 * E;       // [8E,9E)
    float* out2    = ws + 2 * E;        // [2E,3E)  (act_t dead by then)
    unsigned short* hid_t = U + 10 * E; // [5E,7E)  (t_t dead after mul3_cpe)
    unsigned short* wpool = U + 20 * E; // 262144 bf16
    unsigned short* wq  = wpool;
    unsigned short* wm1 = wpool + 81920;
    unsigned short* wm2 = wpool + 147456;
    unsigned short* wai = wpool + 212992;   // actp rows 0-127, inp rows 128-255 (contiguous)
    unsigned short* wo  = wpool + 245760;
    float* fb     = ws + 10 * E + 131072;
    float* meanb  = fb;            // 1024
    float* gstats = fb + 2048;     // 2048: gn1 [0,1024), gn2 [1024,2048)
    float* qb_r   = fb + 4096;     // 640
    float* wsT    = fb + 4736;     // 1152
    float* bsum   = fb + 5888;     // 128
    float* cpe1T  = fb + 6016;     // 1152
    float* dwcT   = fb + 7168;     // 1152
    float* cpe2T  = fb + 8320;     // 1152
    float* abi    = fb + 9472;     // 256

    hipMemsetAsync(gstats, 0, 2048 * sizeof(float), stream);
    convert_w_kernel<<<1046, 256, 0, stream>>>(qkv_w, mlp1_w, mlp2_w, actp_w, inp_w, outp_w,
                                               qkv_b, eaax_w, eaax_b, eaay_w, eaay_b,
                                               cpe1_w, dwc_w, cpe2_w, actp_b, inp_b,
                                               wpool, qb_r, wsT, bsum, cpe1T, dwcT, cpe2T, abi);

    // 1) ECA + ESA (gate inline) with transpose -> y (f32 NHWC)
    mean_bc_kernel<<<BATCH * CDIM, 256, 0, stream>>>(x, meanb);
    esa_tr_kernel<<<dim3(64, BATCH), 256, 0, stream>>>(x, meanb, eca_w, esa_al, y_nhwc);
    // 2) shortcut = y + cpe1(y), fused GN1 stats
    cpe_f32_kernel<<<dim3(256, BATCH), 256, 0, stream>>>(y_nhwc, cpe1T, cpe1_b, sc_nhwc, gstats);
    // 3+4+5a) merged actp+inp conv with fused GN1 apply: sc_nhwc -> act_t (relu), it_t
    conv_mfma_kernel<<<dim3(64, 2, BATCH), 256, 0, stream>>>(nullptr, sc_nhwc, gstats, g1, b1,
                                                             wai, abi, nullptr, nullptr,
                                                             act_t, it_t, 128, 128, 2, 0);
    // 5b) tin = relu(dwc(it))
    dwc_bf16_kernel<<<dim3(256, BATCH), 256, 0, stream>>>(it_t, dwcT, dwc_b, tin_t);
    // 6) qkv -> t_t (bf16 NHWC, 640 grouped; q groups pre-scaled by log2e)
    conv_mfma_kernel<<<dim3(64, 5, BATCH), 256, 0, stream>>>(tin_t, nullptr, nullptr, nullptr,
                                                             nullptr, wq, qb_r, nullptr, nullptr,
                                                             t_t, nullptr, 128, 640, 0, 0);
    // 7) both attentions -> a0, a1
    attn_dual_kernel<<<dim3(16, 8, 2 * BATCH), 256, 0, stream>>>(t_t, a0, a1);
    // 8) m_t = bf16((a0+a1+cpe(v0))*act) ; out = outp(m) + shortcut -> out_nhwc
    mul3_cpe_kernel<<<dim3(256, BATCH), 256, 0, stream>>>(a0, a1, act_t, t_t, wsT, bsum, m_t);
    conv_mfma_kernel<<<dim3(64, 1, BATCH), 256, 0, stream>>>(m_t, nullptr, nullptr, nullptr,
                                                             nullptr, wo, outp_b, sc_nhwc,
                                                             out_nhwc, nullptr, nullptr,
                                                             128, 128, 0, 0);
    // 9) out2 = out + cpe2(out), fused GN2 stats
    cpe_f32_kernel<<<dim3(256, BATCH), 256, 0, stream>>>(out_nhwc, cpe2T, cpe2_b, out2,
                                                         gstats + 1024);
    // 10+11) mlp1 with fused GN2 apply -> hid_t ; mlp2 + out2 residual -> d_out (NCHW)
    conv_mfma_kernel<<<dim3(64, 4, BATCH), 256, 0, stream>>>(nullptr, out2, gstats + 1024, g2, b2,
                                                             wm1, mlp1_b, nullptr, nullptr,
                                                             hid_t, nullptr, 128, 512, 1, 0);
    conv_mfma_kernel<<<dim3(64, 1, BATCH), 256, 0, stream>>>(hid_t, nullptr, nullptr, nullptr,
                                                             nullptr, wm2, mlp2_b, out2,
                                                             (float*)d_out, nullptr, nullptr,
                                                             512, 128, 0, 1);
}

// Round 11
// 311.513 us; speedup vs baseline: 4.1601x; 1.0057x over previous
//
#include <hip/hip_runtime.h>

#define NPIX 4096
#define CDIM 128
#define BATCH 8
#define EPSN 1e-5f
#define LOG2E 1.44269504088896340736f

typedef __attribute__((ext_vector_type(8))) short short8;
typedef __attribute__((ext_vector_type(4))) float f32x4;
typedef __attribute__((ext_vector_type(16))) float f32x16;

__device__ __forceinline__ float sigmoidf_(float x) { return 1.f / (1.f + __expf(-x)); }

__device__ __forceinline__ unsigned short f2b(float f) {
    unsigned int u = __float_as_uint(f);
    unsigned int r = (u + 0x7FFF + ((u >> 16) & 1)) >> 16;  // RNE
    return (unsigned short)r;
}
__device__ __forceinline__ float b2f(unsigned short u) {
    return __uint_as_float((unsigned int)u << 16);
}

// window token -> pixel index
__device__ __forceinline__ int tok2pix(int mode, int wi, int l) {
    return (mode == 0) ? ((l >> 2) * 64 + wi * 4 + (l & 3))
                       : ((wi * 4 + (l >> 6)) * 64 + (l & 63));
}

// ---------------- weight conversion / reorder / transposes / gstats zeroing ----------------
// q0/q1 weight+bias groups pre-scaled by log2(e) so attention can use native exp2.
__global__ __launch_bounds__(256) void convert_w_kernel(const float* __restrict__ qkv_w,
                                                        const float* __restrict__ mlp1_w,
                                                        const float* __restrict__ mlp2_w,
                                                        const float* __restrict__ actp_w,
                                                        const float* __restrict__ inp_w,
                                                        const float* __restrict__ outp_w,
                                                        const float* __restrict__ qkv_b,
                                                        const float* __restrict__ eaax_w,
                                                        const float* __restrict__ eaax_b,
                                                        const float* __restrict__ eaay_w,
                                                        const float* __restrict__ eaay_b,
                                                        const float* __restrict__ cpe1_w,
                                                        const float* __restrict__ dwc_w,
                                                        const float* __restrict__ cpe2_w,
                                                        const float* __restrict__ actp_b,
                                                        const float* __restrict__ inp_b,
                                                        unsigned short* __restrict__ dst,
                                                        float* __restrict__ qb_r,
                                                        float* __restrict__ wsT,
                                                        float* __restrict__ bsum,
                                                        float* __restrict__ cpe1T,
                                                        float* __restrict__ dwcT,
                                                        float* __restrict__ cpe2T,
                                                        float* __restrict__ abi,
                                                        float* __restrict__ gstats) {
    int i = blockIdx.x * 256 + threadIdx.x;
    if (i >= 267776) {
        if (i < 269824) gstats[i - 267776] = 0.f;
        return;
    }
    if (i < 262144) {
        float v;
        if (i < 81920) {
            int o = i >> 7, c = i & 127;              // reordered: o_new = g*128+cc
            int g = o >> 7;
            v = qkv_w[(size_t)(5 * (o & 127) + g) * 128 + c];
            if (g == 0 || g == 3) v *= LOG2E;         // q0/q1 pre-scale for exp2
        } else if (i < 147456) v = mlp1_w[i - 81920];
        else if (i < 212992)   v = mlp2_w[i - 147456];
        else if (i < 229376)   v = actp_w[i - 212992];
        else if (i < 245760)   v = inp_w[i - 229376];
        else                   v = outp_w[i - 245760];
        dst[i] = f2b(v);
    } else {
        int j = i - 262144;
        if (j < 640) {
            int g = j >> 7;
            float v = qkv_b[5 * (j & 127) + g];
            if (g == 0 || g == 3) v *= LOG2E;
            qb_r[j] = v;
        }
        else if (j < 1792) {
            int idx = j - 640; int k = idx >> 7, c = idx & 127;
            wsT[idx] = eaax_w[c * 9 + k] + eaay_w[c * 9 + k];
        } else if (j < 1920) bsum[j - 1792] = eaax_b[j - 1792] + eaay_b[j - 1792];
        else if (j < 3072) {
            int idx = j - 1920; int k = idx >> 7, c = idx & 127;
            cpe1T[idx] = cpe1_w[c * 9 + k];
        } else if (j < 4224) {
            int idx = j - 3072; int k = idx >> 7, c = idx & 127;
            dwcT[idx] = dwc_w[c * 9 + k];
        } else if (j < 5376) {
            int idx = j - 4224; int k = idx >> 7, c = idx & 127;
            cpe2T[idx] = cpe2_w[c * 9 + k];
        } else {
            int idx = j - 5376;
            abi[idx] = (idx < 128) ? actp_b[idx] : inp_b[idx - 128];
        }
    }
}

// ---------------- per-(b,c) mean over HW (x is NCHW input) ----------------
__global__ __launch_bounds__(256) void mean_bc_kernel(const float* __restrict__ x,
                                                      float* __restrict__ mean) {
    __shared__ float sb[4];
    int bc = blockIdx.x;
    const float* p = x + (size_t)bc * NPIX;
    float s = 0.f;
    for (int i = threadIdx.x; i < NPIX; i += 256) s += p[i];
#pragma unroll
    for (int off = 32; off > 0; off >>= 1) s += __shfl_down(s, off, 64);
    if ((threadIdx.x & 63) == 0) sb[threadIdx.x >> 6] = s;
    __syncthreads();
    if (threadIdx.x == 0) mean[bc] = (sb[0] + sb[1] + sb[2] + sb[3]) * (1.f / (float)NPIX);
}

// ---------------- ESA+ECA fused (gate computed inline) with NCHW->NHWC transpose ----------------
__global__ __launch_bounds__(256) void esa_tr_kernel(const float* __restrict__ x,
                                                     const float* __restrict__ mean,
                                                     const float* __restrict__ w5,
                                                     const float* __restrict__ alpha_p,
                                                     float* __restrict__ y) {
    __shared__ float tile[128][65];
    __shared__ float smx[4][64], smn[4][64], ssc[64], gat[128];
    int b = blockIdx.y, p0 = blockIdx.x * 64;
    int tx = threadIdx.x, pl = tx & 63, part = tx >> 6;
    const float* xb = x + (size_t)b * CDIM * NPIX;
    const float* mb = mean + b * CDIM;
    for (int c = part; c < CDIM; c += 4)
        tile[c][pl] = xb[(size_t)c * NPIX + p0 + pl];
    __syncthreads();
    float mx = -1e30f, mn = 1e30f;
#pragma unroll
    for (int cc = 0; cc < 32; ++cc) {
        int c = part * 32 + cc;
        float v = tile[c][pl] - mb[c];
        mx = fmaxf(mx, v); mn = fminf(mn, v);
    }
    smx[part][pl] = mx; smn[part][pl] = mn;
    __syncthreads();
    if (tx < 128) {
        float s = 0.f;
#pragma unroll
        for (int k = 0; k < 5; ++k) {
            int cc = tx + k - 2;
            if (cc >= 0 && cc < CDIM) s += w5[k] * mb[cc];
        }
        gat[tx] = sigmoidf_(s);
    }
    if (part == 0) {
        float m1 = fmaxf(fmaxf(smx[0][pl], smx[1][pl]), fmaxf(smx[2][pl], smx[3][pl]));
        float m2 = fminf(fminf(smn[0][pl], smn[1][pl]), fminf(smn[2][pl], smn[3][pl]));
        float a = alpha_p[0];
        ssc[pl] = sigmoidf_(m1) * a + sigmoidf_(m2) * (1.f - a);
    }
    __syncthreads();
    int c2 = tx & 127, pr = tx >> 7;
    float* yb = y + ((size_t)b * NPIX + p0) * CDIM;
    float gv = gat[c2];
    for (int p = pr; p < 64; p += 2)
        yb[(size_t)p * CDIM + c2] = tile[c2][p] * (gv + ssc[p]);
}

// ---------------- NHWC f32 dwconv3 + residual + fused PER-BATCH GN stats (8 spread slots) ----------------
__global__ __launch_bounds__(256) void cpe_f32_kernel(const float* __restrict__ in,
                                                      const float* __restrict__ wT,
                                                      const float* __restrict__ bias,
                                                      float* __restrict__ out,
                                                      float* __restrict__ stats) {
    __shared__ float sb[8];
    int b = blockIdx.y, tx = threadIdx.x;
    int cg = tx & 15, pp = tx >> 4;
    int p = blockIdx.x * 16 + pp;
    int xx = p & 63, yy = p >> 6;
    int c0 = cg * 8;
    float acc[8], ctr[8];
#pragma unroll
    for (int j = 0; j < 8; ++j) acc[j] = bias[c0 + j];
#pragma unroll
    for (int dy = -1; dy <= 1; ++dy) {
        int y2 = yy + dy;
        if (y2 < 0 || y2 >= 64) continue;
#pragma unroll
        for (int dx = -1; dx <= 1; ++dx) {
            int x2 = xx + dx;
            if (x2 < 0 || x2 >= 64) continue;
            const float* ip = &in[((size_t)b * NPIX + y2 * 64 + x2) * 128 + c0];
            float4 v0 = *(const float4*)ip;
            float4 v1 = *(const float4*)(ip + 4);
            const float* wr = wT + ((dy + 1) * 3 + dx + 1) * 128 + c0;
            acc[0] += v0.x * wr[0]; acc[1] += v0.y * wr[1];
            acc[2] += v0.z * wr[2]; acc[3] += v0.w * wr[3];
            acc[4] += v1.x * wr[4]; acc[5] += v1.y * wr[5];
            acc[6] += v1.z * wr[6]; acc[7] += v1.w * wr[7];
            if (dy == 0 && dx == 0) {
                ctr[0] = v0.x; ctr[1] = v0.y; ctr[2] = v0.z; ctr[3] = v0.w;
                ctr[4] = v1.x; ctr[5] = v1.y; ctr[6] = v1.z; ctr[7] = v1.w;
            }
        }
    }
    float s = 0.f, s2 = 0.f;
    float r[8];
#pragma unroll
    for (int j = 0; j < 8; ++j) {
        r[j] = ctr[j] + acc[j];
        s += r[j]; s2 += r[j] * r[j];
    }
    float* op = &out[((size_t)b * NPIX + p) * 128 + c0];
    *(float4*)op = make_float4(r[0], r[1], r[2], r[3]);
    *(float4*)(op + 4) = make_float4(r[4], r[5], r[6], r[7]);
#pragma unroll
    for (int off = 32; off > 0; off >>= 1) {
        s += __shfl_down(s, off, 64);
        s2 += __shfl_down(s2, off, 64);
    }
    int wv = tx >> 6;
    if ((tx & 63) == 0) { sb[wv] = s; sb[4 + wv] = s2; }
    __syncthreads();
    if (tx == 0) {
        int slot = (b * 8 + (blockIdx.x & 7)) * 16;
        atomicAdd(&stats[slot], sb[0] + sb[1] + sb[2] + sb[3]);
        atomicAdd(&stats[slot + 1], sb[4] + sb[5] + sb[6] + sb[7]);
    }
}

// ---------------- NHWC bf16 dwconv3 + bias + relu -> bf16 ----------------
__global__ __launch_bounds__(256) void dwc_bf16_kernel(const unsigned short* __restrict__ in,
                                                       const float* __restrict__ wT,
                                                       const float* __restrict__ bias,
                                                       unsigned short* __restrict__ out) {
    int b = blockIdx.y, tx = threadIdx.x;
    int cg = tx & 15, pp = tx >> 4;
    int p = blockIdx.x * 16 + pp;
    int xx = p & 63, yy = p >> 6;
    int c0 = cg * 8;
    float acc[8];
#pragma unroll
    for (int j = 0; j < 8; ++j) acc[j] = bias[c0 + j];
#pragma unroll
    for (int dy = -1; dy <= 1; ++dy) {
        int y2 = yy + dy;
        if (y2 < 0 || y2 >= 64) continue;
#pragma unroll
        for (int dx = -1; dx <= 1; ++dx) {
            int x2 = xx + dx;
            if (x2 < 0 || x2 >= 64) continue;
            unsigned short v[8];
            *(uint4*)v = *(const uint4*)&in[((size_t)b * NPIX + y2 * 64 + x2) * 128 + c0];
            const float* wr = wT + ((dy + 1) * 3 + dx + 1) * 128 + c0;
#pragma unroll
            for (int j = 0; j < 8; ++j) acc[j] += b2f(v[j]) * wr[j];
        }
    }
    unsigned short o[8];
#pragma unroll
    for (int j = 0; j < 8; ++j) o[j] = f2b(fmaxf(acc[j], 0.f));
    *(uint4*)&out[((size_t)b * NPIX + p) * 128 + c0] = *(uint4*)o;
}

// ---------------- conv1x1 via bf16 MFMA, 128out x 64px tile ----------------
__global__ __launch_bounds__(256) void conv_mfma_kernel(const unsigned short* __restrict__ in_t,
                                                        const float* __restrict__ in_f32,
                                                        const float* __restrict__ gst,
                                                        const float* __restrict__ gg,
                                                        const float* __restrict__ gbta,
                                                        const unsigned short* __restrict__ w,
                                                        const float* __restrict__ bias,
                                                        const float* __restrict__ res,
                                                        float* __restrict__ out,
                                                        unsigned short* __restrict__ out_t,
                                                        unsigned short* __restrict__ out_t2,
                                                        int Cin, int Cout, int relu, int nchw) {
    __shared__ __align__(16) unsigned short A_s[128][136];
    __shared__ __align__(16) unsigned short B_s[64][136];
    int b = blockIdx.z, p0 = blockIdx.x * 64, o0 = blockIdx.y * 128;
    int tx = threadIdx.x;
    int wave = tx >> 6, lane = tx & 63;
    int wm = wave & 1, wn = wave >> 1;
    int quad = lane >> 4, l16 = lane & 15;

    float mu = 0.f, rr = 1.f;
    if (in_f32) {
        float su = 0.f, sq = 0.f;
#pragma unroll
        for (int sl = 0; sl < 8; ++sl) {
            su += gst[(b * 8 + sl) * 16];
            sq += gst[(b * 8 + sl) * 16 + 1];
        }
        const float n = 1.f / (float)(CDIM * NPIX);
        mu = su * n;
        float var = sq * n - mu * mu;
        rr = rsqrtf(var + EPSN);
    }

    f32x4 acc[4][2];
#pragma unroll
    for (int mt = 0; mt < 4; ++mt) {
#pragma unroll
        for (int r = 0; r < 4; ++r) {
            float bv = bias[o0 + wm * 64 + mt * 16 + quad * 4 + r];
#pragma unroll
            for (int nt = 0; nt < 2; ++nt) acc[mt][nt][r] = bv;
        }
    }

    for (int k0 = 0; k0 < Cin; k0 += 128) {
#pragma unroll
        for (int j = 0; j < 8; ++j) {
            int idx = tx + 256 * j;
            int row = idx >> 4, c16 = idx & 15;
            *(uint4*)&A_s[row][c16 * 8] =
                *(const uint4*)&w[(size_t)(o0 + row) * Cin + k0 + c16 * 8];
        }
        if (in_f32) {
#pragma unroll
            for (int j = 0; j < 4; ++j) {
                int idx = tx + 256 * j;
                int row = idx >> 4, c16 = idx & 15;
                int ch = c16 * 8;  // Cin==128
                const float* ip = &in_f32[((size_t)b * NPIX + p0 + row) * 128 + ch];
                float4 v0 = *(const float4*)ip;
                float4 v1 = *(const float4*)(ip + 4);
                unsigned short o[8];
                o[0] = f2b((v0.x - mu) * rr * gg[ch + 0] + gbta[ch + 0]);
                o[1] = f2b((v0.y - mu) * rr * gg[ch + 1] + gbta[ch + 1]);
                o[2] = f2b((v0.z - mu) * rr * gg[ch + 2] + gbta[ch + 2]);
                o[3] = f2b((v0.w - mu) * rr * gg[ch + 3] + gbta[ch + 3]);
                o[4] = f2b((v1.x - mu) * rr * gg[ch + 4] + gbta[ch + 4]);
                o[5] = f2b((v1.y - mu) * rr * gg[ch + 5] + gbta[ch + 5]);
                o[6] = f2b((v1.z - mu) * rr * gg[ch + 6] + gbta[ch + 6]);
                o[7] = f2b((v1.w - mu) * rr * gg[ch + 7] + gbta[ch + 7]);
                *(uint4*)&B_s[row][c16 * 8] = *(uint4*)o;
            }
        } else {
#pragma unroll
            for (int j = 0; j < 4; ++j) {
                int idx = tx + 256 * j;
                int row = idx >> 4, c16 = idx & 15;
                *(uint4*)&B_s[row][c16 * 8] =
                    *(const uint4*)&in_t[((size_t)b * NPIX + p0 + row) * Cin + k0 + c16 * 8];
            }
        }
        __syncthreads();
#pragma unroll
        for (int ks = 0; ks < 128; ks += 32) {
            short8 af[4], bf[2];
#pragma unroll
            for (int mt = 0; mt < 4; ++mt)
                af[mt] = *(const short8*)&A_s[wm * 64 + mt * 16 + l16][ks + quad * 8];
#pragma unroll
            for (int nt = 0; nt < 2; ++nt)
                bf[nt] = *(const short8*)&B_s[wn * 32 + nt * 16 + l16][ks + quad * 8];
#pragma unroll
            for (int mt = 0; mt < 4; ++mt)
#pragma unroll
                for (int nt = 0; nt < 2; ++nt)
                    acc[mt][nt] = __builtin_amdgcn_mfma_f32_16x16x32_bf16(
                        af[mt], bf[nt], acc[mt][nt], 0, 0, 0);
        }
        __syncthreads();
    }

    int dorelu = (relu == 1) || (relu == 2 && blockIdx.y == 0);
    if (out_t) {
#pragma unroll
        for (int mt = 0; mt < 4; ++mt) {
#pragma unroll
            for (int nt = 0; nt < 2; ++nt) {
                int p = p0 + wn * 32 + nt * 16 + l16;
                int ob = o0 + wm * 64 + mt * 16 + quad * 4;
                unsigned short* dbuf = out_t;
                int oc = ob;
                if (out_t2 && o0 >= 128) { dbuf = out_t2; oc = ob - 128; }
                ushort4 u;
                float v0 = acc[mt][nt][0], v1 = acc[mt][nt][1];
                float v2 = acc[mt][nt][2], v3 = acc[mt][nt][3];
                if (dorelu) { v0 = fmaxf(v0, 0.f); v1 = fmaxf(v1, 0.f);
                              v2 = fmaxf(v2, 0.f); v3 = fmaxf(v3, 0.f); }
                u.x = f2b(v0); u.y = f2b(v1); u.z = f2b(v2); u.w = f2b(v3);
                *(ushort4*)&dbuf[((size_t)b * NPIX + p) * Cout + oc] = u;
            }
        }
    } else if (!nchw) {
#pragma unroll
        for (int mt = 0; mt < 4; ++mt) {
#pragma unroll
            for (int nt = 0; nt < 2; ++nt) {
                int p = p0 + wn * 32 + nt * 16 + l16;
                int ob = o0 + wm * 64 + mt * 16 + quad * 4;
                size_t ix = ((size_t)b * NPIX + p) * Cout + ob;
                float4 v = make_float4(acc[mt][nt][0], acc[mt][nt][1],
                                       acc[mt][nt][2], acc[mt][nt][3]);
                if (dorelu) { v.x = fmaxf(v.x, 0.f); v.y = fmaxf(v.y, 0.f);
                              v.z = fmaxf(v.z, 0.f); v.w = fmaxf(v.w, 0.f); }
                if (res) {
                    float4 rv = *(const float4*)&res[ix];
                    v.x += rv.x; v.y += rv.y; v.z += rv.z; v.w += rv.w;
                }
                *(float4*)&out[ix] = v;
            }
        }
    } else {
        float* outb = out + (size_t)b * Cout * NPIX;
#pragma unroll
        for (int mt = 0; mt < 4; ++mt) {
#pragma unroll
            for (int nt = 0; nt < 2; ++nt) {
                int p = p0 + wn * 32 + nt * 16 + l16;
                int ob = o0 + wm * 64 + mt * 16 + quad * 4;
                float4 rv = make_float4(0.f, 0.f, 0.f, 0.f);
                if (res) rv = *(const float4*)&res[((size_t)b * NPIX + p) * 128 + ob];
#pragma unroll
                for (int r = 0; r < 4; ++r) {
                    float v = acc[mt][nt][r];
                    if (dorelu) v = fmaxf(v, 0.f);
                    v += (r == 0 ? rv.x : r == 1 ? rv.y : r == 2 ? rv.z : rv.w);
                    outb[(size_t)(ob + r) * NPIX + p] = v;
                }
            }
        }
    }
}

// ---------------- MFMA window attention, both orientations in one launch ----------------
// q pre-scaled by log2(e) -> native exp2; row-sum via ones-row at PV A row 16 (o_acc[8]).
// k addressing strength-reduced: both window modes step a constant pixel stride per nt.
__global__ __launch_bounds__(256) void attn_dual_kernel(const unsigned short* __restrict__ t_t,
                                                        float* __restrict__ a0,
                                                        float* __restrict__ a1) {
    __shared__ __align__(16) unsigned short Vt[16][264];
    int wi = blockIdx.x, head = blockIdx.y;
    int z = blockIdx.z;
    int b = z >> 1, which = z & 1;
    int qoff = which ? 384 : 0;
    int koff = which ? 512 : 128;
    int mode = which;
    float* a_out = which ? a1 : a0;
    int tx = threadIdx.x;
    int wave = tx >> 6, l = tx & 63;
    int l32 = l & 31, half = l >> 5;
    const size_t base = (size_t)b * NPIX;
    const int hc = head * 16;

    {
        int p = tok2pix(mode, wi, tx);
        const unsigned short* vp = &t_t[(base + p) * 640 + 256 + hc];
        unsigned short tmp[16];
        *(uint4*)&tmp[0] = *(const uint4*)vp;
        *(uint4*)&tmp[8] = *(const uint4*)(vp + 8);
#pragma unroll
        for (int d = 0; d < 16; ++d) Vt[d][tx] = tmp[d];
    }
    __syncthreads();

    // constant-stride k pointer: token nt*32+l32 advances +512 px (mode 0) / +32 px (mode 1)
    int p0k = tok2pix(mode, wi, l32);
    const size_t kstep = (size_t)(mode ? 32 : 512) * 640;
    const unsigned short* kptr = &t_t[(base + p0k) * 640 + koff + hc + half * 8];

    f32x16 zzero;
#pragma unroll
    for (int r = 0; r < 16; ++r) zzero[r] = 0.f;
    short8 vones, vzero;
#pragma unroll
    for (int r = 0; r < 8; ++r) { vones[r] = (short)0x3F80; vzero[r] = 0; }

    for (int qi = 0; qi < 2; ++qi) {
        int qs = qi * 4 + wave;
        int qp = tok2pix(mode, wi, qs * 32 + l32);
        short8 qf = *(const short8*)&t_t[(base + qp) * 640 + qoff + hc + half * 8];
        f32x16 o_acc = zzero;
        const unsigned short* kp = kptr;
#pragma unroll
        for (int nt = 0; nt < 8; ++nt) {
            short8 kf = *(const short8*)kp;
            kp += kstep;
            f32x16 s = __builtin_amdgcn_mfma_f32_32x32x16_bf16(kf, qf, zzero, 0, 0, 0);
            unsigned int pk[8];
#pragma unroll
            for (int i = 0; i < 8; ++i) {
                float e0 = exp2f(s[2 * i]);
                float e1 = exp2f(s[2 * i + 1]);
                pk[i] = __builtin_amdgcn_perm(__float_as_uint(e1), __float_as_uint(e0),
                                              0x07060302u);
            }
            unsigned int xpk[8];
#pragma unroll
            for (int i = 0; i < 8; ++i)
                xpk[i] = (unsigned int)__shfl_xor((int)pk[i], 32, 64);
            unsigned int u0[4], u1[4];
            if (half == 0) {
                u0[0] = pk[0]; u0[1] = pk[1]; u0[2] = xpk[0]; u0[3] = xpk[1];
                u1[0] = pk[4]; u1[1] = pk[5]; u1[2] = xpk[4]; u1[3] = xpk[5];
            } else {
                u0[0] = xpk[2]; u0[1] = xpk[3]; u0[2] = pk[2]; u0[3] = pk[3];
                u1[0] = xpk[6]; u1[1] = xpk[7]; u1[2] = pk[6]; u1[3] = pk[7];
            }
            short8 vf0, vf1;
            if (l32 < 16) {
                vf0 = *(const short8*)&Vt[l32][nt * 32 + half * 8];
                vf1 = *(const short8*)&Vt[l32][nt * 32 + 16 + half * 8];
            } else if (l32 == 16) {
                vf0 = vones; vf1 = vones;
            } else {
                vf0 = vzero; vf1 = vzero;
            }
            o_acc = __builtin_amdgcn_mfma_f32_32x32x16_bf16(vf0, *(short8*)u0, o_acc, 0, 0, 0);
            o_acc = __builtin_amdgcn_mfma_f32_32x32x16_bf16(vf1, *(short8*)u1, o_acc, 0, 0, 0);
        }
        // row 16 of PV output = sum_t P[t][col]  (half-0 lanes, r=8)
        float rs = o_acc[8];
        rs += __shfl_xor(rs, 32, 64);
        float rinv = 1.f / rs;
        // d = (r&3) + 8*(r>>2) + 4*half  ->  two contiguous float4 runs
        float* dst = a_out + (base + qp) * 128 + hc + 4 * half;
        float4 s0 = make_float4(o_acc[0] * rinv, o_acc[1] * rinv,
                                o_acc[2] * rinv, o_acc[3] * rinv);
        float4 s1 = make_float4(o_acc[4] * rinv, o_acc[5] * rinv,
                                o_acc[6] * rinv, o_acc[7] * rinv);
        *(float4*)dst = s0;
        *(float4*)(dst + 8) = s1;
    }
}

// ---------------- m_t = bf16((a0 + a1 + cpe(v0)) * act_res)  (all NHWC) ----------------
__global__ __launch_bounds__(256) void mul3_cpe_kernel(const float* __restrict__ a0,
                                                       const float* __restrict__ a1,
                                                       const unsigned short* __restrict__ act,
                                                       const unsigned short* __restrict__ t_t,
                                                       const float* __restrict__ wT,
                                                       const float* __restrict__ bsum,
                                                       unsigned short* __restrict__ dst) {
    int b = blockIdx.y;
    int tx = threadIdx.x;
    int cg = tx & 15, pp = tx >> 4;
    int p = blockIdx.x * 16 + pp;
    int xx = p & 63, yy = p >> 6;
    int c0 = cg * 8;
    float acc[8];
#pragma unroll
    for (int j = 0; j < 8; ++j) acc[j] = bsum[c0 + j];
#pragma unroll
    for (int dy = -1; dy <= 1; ++dy) {
        int y2 = yy + dy;
        if (y2 < 0 || y2 >= 64) continue;
#pragma unroll
        for (int dx = -1; dx <= 1; ++dx) {
            int x2 = xx + dx;
            if (x2 < 0 || x2 >= 64) continue;
            int pn = y2 * 64 + x2;
            unsigned short v[8];
            *(uint4*)v = *(const uint4*)&t_t[((size_t)b * NPIX + pn) * 640 + 256 + c0];
            const float* wr = wT + ((dy + 1) * 3 + dx + 1) * 128 + c0;
#pragma unroll
            for (int j = 0; j < 8; ++j) acc[j] += b2f(v[j]) * wr[j];
        }
    }
    size_t base = ((size_t)b * NPIX + p) * 128 + c0;
    float4 x0 = *(const float4*)&a0[base];
    float4 x1 = *(const float4*)&a0[base + 4];
    float4 y0 = *(const float4*)&a1[base];
    float4 y1 = *(const float4*)&a1[base + 4];
    unsigned short t[8];
    *(uint4*)t = *(const uint4*)&act[base];
    unsigned short r[8];
    r[0] = f2b((x0.x + y0.x + acc[0]) * b2f(t[0]));
    r[1] = f2b((x0.y + y0.y + acc[1]) * b2f(t[1]));
    r[2] = f2b((x0.z + y0.z + acc[2]) * b2f(t[2]));
    r[3] = f2b((x0.w + y0.w + acc[3]) * b2f(t[3]));
    r[4] = f2b((x1.x + y1.x + acc[4]) * b2f(t[4]));
    r[5] = f2b((x1.y + y1.y + acc[5]) * b2f(t[5]));
    r[6] = f2b((x1.z + y1.z + acc[6]) * b2f(t[6]));
    r[7] = f2b((x1.w + y1.w + acc[7]) * b2f(t[7]));
    *(uint4*)&dst[base] = *(uint4*)r;
}

extern "C" void kernel_launch(void* const* d_in, const int* in_sizes, int n_in,
                              void* d_out, int out_size, void* d_ws, size_t ws_size,
                              hipStream_t stream) {
    const float* x       = (const float*)d_in[0];
    const float* eca_w   = (const float*)d_in[1];
    const float* esa_al  = (const float*)d_in[2];
    const float* cpe1_w  = (const float*)d_in[3];  const float* cpe1_b = (const float*)d_in[4];
    const float* g1      = (const float*)d_in[5];  const float* b1     = (const float*)d_in[6];
    const float* actp_w  = (const float*)d_in[7];  const float* actp_b = (const float*)d_in[8];
    const float* inp_w   = (const float*)d_in[9];  const float* inp_b  = (const float*)d_in[10];
    const float* dwc_w   = (const float*)d_in[11]; const float* dwc_b  = (const float*)d_in[12];
    const float* qkv_w   = (const float*)d_in[13]; const float* qkv_b  = (const float*)d_in[14];
    const float* eaax_w  = (const float*)d_in[15]; const float* eaax_b = (const float*)d_in[16];
    const float* eaay_w  = (const float*)d_in[17]; const float* eaay_b = (const float*)d_in[18];
    const float* outp_w  = (const float*)d_in[19]; const float* outp_b = (const float*)d_in[20];
    const float* cpe2_w  = (const float*)d_in[21]; const float* cpe2_b = (const float*)d_in[22];
    const float* g2      = (const float*)d_in[23]; const float* b2     = (const float*)d_in[24];
    const float* mlp1_w  = (const float*)d_in[25]; const float* mlp1_b = (const float*)d_in[26];
    const float* mlp2_w  = (const float*)d_in[27]; const float* mlp2_b = (const float*)d_in[28];

    float* ws = (float*)d_ws;
    unsigned short* U = (unsigned short*)d_ws;
    const size_t E = (size_t)BATCH * CDIM * NPIX;  // 4,194,304

    float* y_nhwc  = ws;                // [0,E)  esa out; later a0
    float* a0      = ws;
    float* sc_nhwc = ws + E;            // [E,2E) shortcut (live to outp)
    unsigned short* act_t = U + 5 * E;  // [2.5E,3E)
    unsigned short* it_t  = U + 6 * E;  // [3E,3.5E)
    unsigned short* tin_t = U + 7 * E;  // [3.5E,4E)
    float* a1      = ws + 4 * E;        // [4E,5E)
    unsigned short* t_t   = U + 10 * E; // [5E,7.5E)
    unsigned short* m_t   = U + 15 * E; // [7.5E,8E)
    float* out_nhwc = ws + 8 * E;       // [8E,9E)
    float* out2    = ws + 2 * E;        // [2E,3E)  (act_t dead by then)
    unsigned short* hid_t = U + 10 * E; // [5E,7E)  (t_t dead after mul3_cpe)
    unsigned short* wpool = U + 20 * E; // 262144 bf16
    unsigned short* wq  = wpool;
    unsigned short* wm1 = wpool + 81920;
    unsigned short* wm2 = wpool + 147456;
    unsigned short* wai = wpool + 212992;   // actp rows 0-127, inp rows 128-255 (contiguous)
    unsigned short* wo  = wpool + 245760;
    float* fb     = ws + 10 * E + 131072;
    float* meanb  = fb;            // 1024
    float* gstats = fb + 2048;     // 2048: gn1 [0,1024), gn2 [1024,2048)
    float* qb_r   = fb + 4096;     // 640
    float* wsT    = fb + 4736;     // 1152
    float* bsum   = fb + 5888;     // 128
    float* cpe1T  = fb + 6016;     // 1152
    float* dwcT   = fb + 7168;     // 1152
    float* cpe2T  = fb + 8320;     // 1152
    float* abi    = fb + 9472;     // 256

    convert_w_kernel<<<1054, 256, 0, stream>>>(qkv_w, mlp1_w, mlp2_w, actp_w, inp_w, outp_w,
                                               qkv_b, eaax_w, eaax_b, eaay_w, eaay_b,
                                               cpe1_w, dwc_w, cpe2_w, actp_b, inp_b,
                                               wpool, qb_r, wsT, bsum, cpe1T, dwcT, cpe2T, abi,
                                               gstats);

    // 1) ECA + ESA (gate inline) with transpose -> y (f32 NHWC)
    mean_bc_kernel<<<BATCH * CDIM, 256, 0, stream>>>(x, meanb);
    esa_tr_kernel<<<dim3(64, BATCH), 256, 0, stream>>>(x, meanb, eca_w, esa_al, y_nhwc);
    // 2) shortcut = y + cpe1(y), fused GN1 stats
    cpe_f32_kernel<<<dim3(256, BATCH), 256, 0, stream>>>(y_nhwc, cpe1T, cpe1_b, sc_nhwc, gstats);
    // 3+4+5a) merged actp+inp conv with fused GN1 apply: sc_nhwc -> act_t (relu), it_t
    conv_mfma_kernel<<<dim3(64, 2, BATCH), 256, 0, stream>>>(nullptr, sc_nhwc, gstats, g1, b1,
                                                             wai, abi, nullptr, nullptr,
                                                             act_t, it_t, 128, 128, 2, 0);
    // 5b) tin = relu(dwc(it))
    dwc_bf16_kernel<<<dim3(256, BATCH), 256, 0, stream>>>(it_t, dwcT, dwc_b, tin_t);
    // 6) qkv -> t_t (bf16 NHWC, 640 grouped; q groups pre-scaled by log2e)
    conv_mfma_kernel<<<dim3(64, 5, BATCH), 256, 0, stream>>>(tin_t, nullptr, nullptr, nullptr,
                                                             nullptr, wq, qb_r, nullptr, nullptr,
                                                             t_t, nullptr, 128, 640, 0, 0);
    // 7) both attentions -> a0, a1
    attn_dual_kernel<<<dim3(16, 8, 2 * BATCH), 256, 0, stream>>>(t_t, a0, a1);
    // 8) m_t = bf16((a0+a1+cpe(v0))*act) ; out = outp(m) + shortcut -> out_nhwc
    mul3_cpe_kernel<<<dim3(256, BATCH), 256, 0, stream>>>(a0, a1, act_t, t_t, wsT, bsum, m_t);
    conv_mfma_kernel<<<dim3(64, 1, BATCH), 256, 0, stream>>>(m_t, nullptr, nullptr, nullptr,
                                                             nullptr, wo, outp_b, sc_nhwc,
                                                             out_nhwc, nullptr, nullptr,
                                                             128, 128, 0, 0);
    // 9) out2 = out + cpe2(out), fused GN2 stats
    cpe_f32_kernel<<<dim3(256, BATCH), 256, 0, stream>>>(out_nhwc, cpe2T, cpe2_b, out2,
                                                         gstats + 1024);
    // 10+11) mlp1 with fused GN2 apply -> hid_t ; mlp2 + out2 residual -> d_out (NCHW)
    conv_mfma_kernel<<<dim3(64, 4, BATCH), 256, 0, stream>>>(nullptr, out2, gstats + 1024, g2, b2,
                                                             wm1, mlp1_b, nullptr, nullptr,
                                                             hid_t, nullptr, 128, 512, 1, 0);
    conv_mfma_kernel<<<dim3(64, 1, BATCH), 256, 0, stream>>>(hid_t, nullptr, nullptr, nullptr,
                                                             nullptr, wm2, mlp2_b, out2,
                                                             (float*)d_out, nullptr, nullptr,
                                                             512, 128, 0, 1);
}

// Round 12
// 310.157 us; speedup vs baseline: 4.1782x; 1.0044x over previous
//
#include <hip/hip_runtime.h>

#define NPIX 4096
#define CDIM 128
#define BATCH 8
#define EPSN 1e-5f
#define LOG2E 1.44269504088896340736f

typedef __attribute__((ext_vector_type(8))) short short8;
typedef __attribute__((ext_vector_type(4))) float f32x4;
typedef __attribute__((ext_vector_type(16))) float f32x16;

__device__ __forceinline__ float sigmoidf_(float x) { return 1.f / (1.f + __expf(-x)); }

__device__ __forceinline__ unsigned short f2b(float f) {
    unsigned int u = __float_as_uint(f);
    unsigned int r = (u + 0x7FFF + ((u >> 16) & 1)) >> 16;  // RNE
    return (unsigned short)r;
}
__device__ __forceinline__ float b2f(unsigned short u) {
    return __uint_as_float((unsigned int)u << 16);
}

// window token -> pixel index
__device__ __forceinline__ int tok2pix(int mode, int wi, int l) {
    return (mode == 0) ? ((l >> 2) * 64 + wi * 4 + (l & 3))
                       : ((wi * 4 + (l >> 6)) * 64 + (l & 63));
}

// ---------------- weight conversion / reorder / transposes / gstats zeroing ----------------
// q0/q1 weight+bias groups pre-scaled by log2(e) so attention can use native exp2.
__global__ __launch_bounds__(256) void convert_w_kernel(const float* __restrict__ qkv_w,
                                                        const float* __restrict__ mlp1_w,
                                                        const float* __restrict__ mlp2_w,
                                                        const float* __restrict__ actp_w,
                                                        const float* __restrict__ inp_w,
                                                        const float* __restrict__ outp_w,
                                                        const float* __restrict__ qkv_b,
                                                        const float* __restrict__ eaax_w,
                                                        const float* __restrict__ eaax_b,
                                                        const float* __restrict__ eaay_w,
                                                        const float* __restrict__ eaay_b,
                                                        const float* __restrict__ cpe1_w,
                                                        const float* __restrict__ dwc_w,
                                                        const float* __restrict__ cpe2_w,
                                                        const float* __restrict__ actp_b,
                                                        const float* __restrict__ inp_b,
                                                        unsigned short* __restrict__ dst,
                                                        float* __restrict__ qb_r,
                                                        float* __restrict__ wsT,
                                                        float* __restrict__ bsum,
                                                        float* __restrict__ cpe1T,
                                                        float* __restrict__ dwcT,
                                                        float* __restrict__ cpe2T,
                                                        float* __restrict__ abi,
                                                        float* __restrict__ gstats) {
    int i = blockIdx.x * 256 + threadIdx.x;
    if (i >= 267776) {
        if (i < 269824) gstats[i - 267776] = 0.f;
        return;
    }
    if (i < 262144) {
        float v;
        if (i < 81920) {
            int o = i >> 7, c = i & 127;              // reordered: o_new = g*128+cc
            int g = o >> 7;
            v = qkv_w[(size_t)(5 * (o & 127) + g) * 128 + c];
            if (g == 0 || g == 3) v *= LOG2E;         // q0/q1 pre-scale for exp2
        } else if (i < 147456) v = mlp1_w[i - 81920];
        else if (i < 212992)   v = mlp2_w[i - 147456];
        else if (i < 229376)   v = actp_w[i - 212992];
        else if (i < 245760)   v = inp_w[i - 229376];
        else                   v = outp_w[i - 245760];
        dst[i] = f2b(v);
    } else {
        int j = i - 262144;
        if (j < 640) {
            int g = j >> 7;
            float v = qkv_b[5 * (j & 127) + g];
            if (g == 0 || g == 3) v *= LOG2E;
            qb_r[j] = v;
        }
        else if (j < 1792) {
            int idx = j - 640; int k = idx >> 7, c = idx & 127;
            wsT[idx] = eaax_w[c * 9 + k] + eaay_w[c * 9 + k];
        } else if (j < 1920) bsum[j - 1792] = eaax_b[j - 1792] + eaay_b[j - 1792];
        else if (j < 3072) {
            int idx = j - 1920; int k = idx >> 7, c = idx & 127;
            cpe1T[idx] = cpe1_w[c * 9 + k];
        } else if (j < 4224) {
            int idx = j - 3072; int k = idx >> 7, c = idx & 127;
            dwcT[idx] = dwc_w[c * 9 + k];
        } else if (j < 5376) {
            int idx = j - 4224; int k = idx >> 7, c = idx & 127;
            cpe2T[idx] = cpe2_w[c * 9 + k];
        } else {
            int idx = j - 5376;
            abi[idx] = (idx < 128) ? actp_b[idx] : inp_b[idx - 128];
        }
    }
}

// ---------------- per-(b,c) mean over HW (x is NCHW input) ----------------
__global__ __launch_bounds__(256) void mean_bc_kernel(const float* __restrict__ x,
                                                      float* __restrict__ mean) {
    __shared__ float sb[4];
    int bc = blockIdx.x;
    const float* p = x + (size_t)bc * NPIX;
    float s = 0.f;
    for (int i = threadIdx.x; i < NPIX; i += 256) s += p[i];
#pragma unroll
    for (int off = 32; off > 0; off >>= 1) s += __shfl_down(s, off, 64);
    if ((threadIdx.x & 63) == 0) sb[threadIdx.x >> 6] = s;
    __syncthreads();
    if (threadIdx.x == 0) mean[bc] = (sb[0] + sb[1] + sb[2] + sb[3]) * (1.f / (float)NPIX);
}

// ---------------- ESA+ECA fused (gate computed inline) with NCHW->NHWC transpose ----------------
__global__ __launch_bounds__(256) void esa_tr_kernel(const float* __restrict__ x,
                                                     const float* __restrict__ mean,
                                                     const float* __restrict__ w5,
                                                     const float* __restrict__ alpha_p,
                                                     float* __restrict__ y) {
    __shared__ float tile[128][65];
    __shared__ float smx[4][64], smn[4][64], ssc[64], gat[128];
    int b = blockIdx.y, p0 = blockIdx.x * 64;
    int tx = threadIdx.x, pl = tx & 63, part = tx >> 6;
    const float* xb = x + (size_t)b * CDIM * NPIX;
    const float* mb = mean + b * CDIM;
    for (int c = part; c < CDIM; c += 4)
        tile[c][pl] = xb[(size_t)c * NPIX + p0 + pl];
    __syncthreads();
    float mx = -1e30f, mn = 1e30f;
#pragma unroll
    for (int cc = 0; cc < 32; ++cc) {
        int c = part * 32 + cc;
        float v = tile[c][pl] - mb[c];
        mx = fmaxf(mx, v); mn = fminf(mn, v);
    }
    smx[part][pl] = mx; smn[part][pl] = mn;
    __syncthreads();
    if (tx < 128) {
        float s = 0.f;
#pragma unroll
        for (int k = 0; k < 5; ++k) {
            int cc = tx + k - 2;
            if (cc >= 0 && cc < CDIM) s += w5[k] * mb[cc];
        }
        gat[tx] = sigmoidf_(s);
    }
    if (part == 0) {
        float m1 = fmaxf(fmaxf(smx[0][pl], smx[1][pl]), fmaxf(smx[2][pl], smx[3][pl]));
        float m2 = fminf(fminf(smn[0][pl], smn[1][pl]), fminf(smn[2][pl], smn[3][pl]));
        float a = alpha_p[0];
        ssc[pl] = sigmoidf_(m1) * a + sigmoidf_(m2) * (1.f - a);
    }
    __syncthreads();
    int c2 = tx & 127, pr = tx >> 7;
    float* yb = y + ((size_t)b * NPIX + p0) * CDIM;
    float gv = gat[c2];
    for (int p = pr; p < 64; p += 2)
        yb[(size_t)p * CDIM + c2] = tile[c2][p] * (gv + ssc[p]);
}

// ---------------- NHWC f32 dwconv3 + residual + fused PER-BATCH GN stats (8 spread slots) ----------------
__global__ __launch_bounds__(256) void cpe_f32_kernel(const float* __restrict__ in,
                                                      const float* __restrict__ wT,
                                                      const float* __restrict__ bias,
                                                      float* __restrict__ out,
                                                      float* __restrict__ stats) {
    __shared__ float sb[8];
    int b = blockIdx.y, tx = threadIdx.x;
    int cg = tx & 15, pp = tx >> 4;
    int p = blockIdx.x * 16 + pp;
    int xx = p & 63, yy = p >> 6;
    int c0 = cg * 8;
    float acc[8], ctr[8];
#pragma unroll
    for (int j = 0; j < 8; ++j) acc[j] = bias[c0 + j];
#pragma unroll
    for (int dy = -1; dy <= 1; ++dy) {
        int y2 = yy + dy;
        if (y2 < 0 || y2 >= 64) continue;
#pragma unroll
        for (int dx = -1; dx <= 1; ++dx) {
            int x2 = xx + dx;
            if (x2 < 0 || x2 >= 64) continue;
            const float* ip = &in[((size_t)b * NPIX + y2 * 64 + x2) * 128 + c0];
            float4 v0 = *(const float4*)ip;
            float4 v1 = *(const float4*)(ip + 4);
            const float* wr = wT + ((dy + 1) * 3 + dx + 1) * 128 + c0;
            acc[0] += v0.x * wr[0]; acc[1] += v0.y * wr[1];
            acc[2] += v0.z * wr[2]; acc[3] += v0.w * wr[3];
            acc[4] += v1.x * wr[4]; acc[5] += v1.y * wr[5];
            acc[6] += v1.z * wr[6]; acc[7] += v1.w * wr[7];
            if (dy == 0 && dx == 0) {
                ctr[0] = v0.x; ctr[1] = v0.y; ctr[2] = v0.z; ctr[3] = v0.w;
                ctr[4] = v1.x; ctr[5] = v1.y; ctr[6] = v1.z; ctr[7] = v1.w;
            }
        }
    }
    float s = 0.f, s2 = 0.f;
    float r[8];
#pragma unroll
    for (int j = 0; j < 8; ++j) {
        r[j] = ctr[j] + acc[j];
        s += r[j]; s2 += r[j] * r[j];
    }
    float* op = &out[((size_t)b * NPIX + p) * 128 + c0];
    *(float4*)op = make_float4(r[0], r[1], r[2], r[3]);
    *(float4*)(op + 4) = make_float4(r[4], r[5], r[6], r[7]);
#pragma unroll
    for (int off = 32; off > 0; off >>= 1) {
        s += __shfl_down(s, off, 64);
        s2 += __shfl_down(s2, off, 64);
    }
    int wv = tx >> 6;
    if ((tx & 63) == 0) { sb[wv] = s; sb[4 + wv] = s2; }
    __syncthreads();
    if (tx == 0) {
        int slot = (b * 8 + (blockIdx.x & 7)) * 16;
        atomicAdd(&stats[slot], sb[0] + sb[1] + sb[2] + sb[3]);
        atomicAdd(&stats[slot + 1], sb[4] + sb[5] + sb[6] + sb[7]);
    }
}

// ---------------- NHWC bf16 dwconv3 + bias + relu -> bf16 ----------------
__global__ __launch_bounds__(256) void dwc_bf16_kernel(const unsigned short* __restrict__ in,
                                                       const float* __restrict__ wT,
                                                       const float* __restrict__ bias,
                                                       unsigned short* __restrict__ out) {
    int b = blockIdx.y, tx = threadIdx.x;
    int cg = tx & 15, pp = tx >> 4;
    int p = blockIdx.x * 16 + pp;
    int xx = p & 63, yy = p >> 6;
    int c0 = cg * 8;
    float acc[8];
#pragma unroll
    for (int j = 0; j < 8; ++j) acc[j] = bias[c0 + j];
#pragma unroll
    for (int dy = -1; dy <= 1; ++dy) {
        int y2 = yy + dy;
        if (y2 < 0 || y2 >= 64) continue;
#pragma unroll
        for (int dx = -1; dx <= 1; ++dx) {
            int x2 = xx + dx;
            if (x2 < 0 || x2 >= 64) continue;
            unsigned short v[8];
            *(uint4*)v = *(const uint4*)&in[((size_t)b * NPIX + y2 * 64 + x2) * 128 + c0];
            const float* wr = wT + ((dy + 1) * 3 + dx + 1) * 128 + c0;
#pragma unroll
            for (int j = 0; j < 8; ++j) acc[j] += b2f(v[j]) * wr[j];
        }
    }
    unsigned short o[8];
#pragma unroll
    for (int j = 0; j < 8; ++j) o[j] = f2b(fmaxf(acc[j], 0.f));
    *(uint4*)&out[((size_t)b * NPIX + p) * 128 + c0] = *(uint4*)o;
}

// ---------------- conv1x1 via bf16 MFMA, 128out x 64px tile ----------------
__global__ __launch_bounds__(256) void conv_mfma_kernel(const unsigned short* __restrict__ in_t,
                                                        const float* __restrict__ in_f32,
                                                        const float* __restrict__ gst,
                                                        const float* __restrict__ gg,
                                                        const float* __restrict__ gbta,
                                                        const unsigned short* __restrict__ w,
                                                        const float* __restrict__ bias,
                                                        const float* __restrict__ res,
                                                        float* __restrict__ out,
                                                        unsigned short* __restrict__ out_t,
                                                        unsigned short* __restrict__ out_t2,
                                                        int Cin, int Cout, int relu, int nchw) {
    __shared__ __align__(16) unsigned short A_s[128][136];
    __shared__ __align__(16) unsigned short B_s[64][136];
    int b = blockIdx.z, p0 = blockIdx.x * 64, o0 = blockIdx.y * 128;
    int tx = threadIdx.x;
    int wave = tx >> 6, lane = tx & 63;
    int wm = wave & 1, wn = wave >> 1;
    int quad = lane >> 4, l16 = lane & 15;

    float mu = 0.f, rr = 1.f;
    if (in_f32) {
        float su = 0.f, sq = 0.f;
#pragma unroll
        for (int sl = 0; sl < 8; ++sl) {
            su += gst[(b * 8 + sl) * 16];
            sq += gst[(b * 8 + sl) * 16 + 1];
        }
        const float n = 1.f / (float)(CDIM * NPIX);
        mu = su * n;
        float var = sq * n - mu * mu;
        rr = rsqrtf(var + EPSN);
    }

    f32x4 acc[4][2];
#pragma unroll
    for (int mt = 0; mt < 4; ++mt) {
#pragma unroll
        for (int r = 0; r < 4; ++r) {
            float bv = bias[o0 + wm * 64 + mt * 16 + quad * 4 + r];
#pragma unroll
            for (int nt = 0; nt < 2; ++nt) acc[mt][nt][r] = bv;
        }
    }

    for (int k0 = 0; k0 < Cin; k0 += 128) {
#pragma unroll
        for (int j = 0; j < 8; ++j) {
            int idx = tx + 256 * j;
            int row = idx >> 4, c16 = idx & 15;
            *(uint4*)&A_s[row][c16 * 8] =
                *(const uint4*)&w[(size_t)(o0 + row) * Cin + k0 + c16 * 8];
        }
        if (in_f32) {
#pragma unroll
            for (int j = 0; j < 4; ++j) {
                int idx = tx + 256 * j;
                int row = idx >> 4, c16 = idx & 15;
                int ch = c16 * 8;  // Cin==128
                const float* ip = &in_f32[((size_t)b * NPIX + p0 + row) * 128 + ch];
                float4 v0 = *(const float4*)ip;
                float4 v1 = *(const float4*)(ip + 4);
                unsigned short o[8];
                o[0] = f2b((v0.x - mu) * rr * gg[ch + 0] + gbta[ch + 0]);
                o[1] = f2b((v0.y - mu) * rr * gg[ch + 1] + gbta[ch + 1]);
                o[2] = f2b((v0.z - mu) * rr * gg[ch + 2] + gbta[ch + 2]);
                o[3] = f2b((v0.w - mu) * rr * gg[ch + 3] + gbta[ch + 3]);
                o[4] = f2b((v1.x - mu) * rr * gg[ch + 4] + gbta[ch + 4]);
                o[5] = f2b((v1.y - mu) * rr * gg[ch + 5] + gbta[ch + 5]);
                o[6] = f2b((v1.z - mu) * rr * gg[ch + 6] + gbta[ch + 6]);
                o[7] = f2b((v1.w - mu) * rr * gg[ch + 7] + gbta[ch + 7]);
                *(uint4*)&B_s[row][c16 * 8] = *(uint4*)o;
            }
        } else {
#pragma unroll
            for (int j = 0; j < 4; ++j) {
                int idx = tx + 256 * j;
                int row = idx >> 4, c16 = idx & 15;
                *(uint4*)&B_s[row][c16 * 8] =
                    *(const uint4*)&in_t[((size_t)b * NPIX + p0 + row) * Cin + k0 + c16 * 8];
            }
        }
        __syncthreads();
#pragma unroll
        for (int ks = 0; ks < 128; ks += 32) {
            short8 af[4], bf[2];
#pragma unroll
            for (int mt = 0; mt < 4; ++mt)
                af[mt] = *(const short8*)&A_s[wm * 64 + mt * 16 + l16][ks + quad * 8];
#pragma unroll
            for (int nt = 0; nt < 2; ++nt)
                bf[nt] = *(const short8*)&B_s[wn * 32 + nt * 16 + l16][ks + quad * 8];
#pragma unroll
            for (int mt = 0; mt < 4; ++mt)
#pragma unroll
                for (int nt = 0; nt < 2; ++nt)
                    acc[mt][nt] = __builtin_amdgcn_mfma_f32_16x16x32_bf16(
                        af[mt], bf[nt], acc[mt][nt], 0, 0, 0);
        }
        __syncthreads();
    }

    int dorelu = (relu == 1) || (relu == 2 && blockIdx.y == 0);
    if (out_t) {
#pragma unroll
        for (int mt = 0; mt < 4; ++mt) {
#pragma unroll
            for (int nt = 0; nt < 2; ++nt) {
                int p = p0 + wn * 32 + nt * 16 + l16;
                int ob = o0 + wm * 64 + mt * 16 + quad * 4;
                unsigned short* dbuf = out_t;
                int oc = ob;
                if (out_t2 && o0 >= 128) { dbuf = out_t2; oc = ob - 128; }
                ushort4 u;
                float v0 = acc[mt][nt][0], v1 = acc[mt][nt][1];
                float v2 = acc[mt][nt][2], v3 = acc[mt][nt][3];
                if (dorelu) { v0 = fmaxf(v0, 0.f); v1 = fmaxf(v1, 0.f);
                              v2 = fmaxf(v2, 0.f); v3 = fmaxf(v3, 0.f); }
                u.x = f2b(v0); u.y = f2b(v1); u.z = f2b(v2); u.w = f2b(v3);
                *(ushort4*)&dbuf[((size_t)b * NPIX + p) * Cout + oc] = u;
            }
        }
    } else if (!nchw) {
#pragma unroll
        for (int mt = 0; mt < 4; ++mt) {
#pragma unroll
            for (int nt = 0; nt < 2; ++nt) {
                int p = p0 + wn * 32 + nt * 16 + l16;
                int ob = o0 + wm * 64 + mt * 16 + quad * 4;
                size_t ix = ((size_t)b * NPIX + p) * Cout + ob;
                float4 v = make_float4(acc[mt][nt][0], acc[mt][nt][1],
                                       acc[mt][nt][2], acc[mt][nt][3]);
                if (dorelu) { v.x = fmaxf(v.x, 0.f); v.y = fmaxf(v.y, 0.f);
                              v.z = fmaxf(v.z, 0.f); v.w = fmaxf(v.w, 0.f); }
                if (res) {
                    float4 rv = *(const float4*)&res[ix];
                    v.x += rv.x; v.y += rv.y; v.z += rv.z; v.w += rv.w;
                }
                *(float4*)&out[ix] = v;
            }
        }
    } else {
        float* outb = out + (size_t)b * Cout * NPIX;
#pragma unroll
        for (int mt = 0; mt < 4; ++mt) {
#pragma unroll
            for (int nt = 0; nt < 2; ++nt) {
                int p = p0 + wn * 32 + nt * 16 + l16;
                int ob = o0 + wm * 64 + mt * 16 + quad * 4;
                float4 rv = make_float4(0.f, 0.f, 0.f, 0.f);
                if (res) rv = *(const float4*)&res[((size_t)b * NPIX + p) * 128 + ob];
#pragma unroll
                for (int r = 0; r < 4; ++r) {
                    float v = acc[mt][nt][r];
                    if (dorelu) v = fmaxf(v, 0.f);
                    v += (r == 0 ? rv.x : r == 1 ? rv.y : r == 2 ? rv.z : rv.w);
                    outb[(size_t)(ob + r) * NPIX + p] = v;
                }
            }
        }
    }
}

// ---------------- MFMA window attention, both orientations in one launch ----------------
// q pre-scaled by log2(e) -> native exp2; row-sum via ones-row at PV A row 16 (o_acc[8]).
// k addresses computed independently per nt (tok2pix) for max memory-level parallelism
// (serial pointer-increment form measured 10 us slower — round 11).
__global__ __launch_bounds__(256) void attn_dual_kernel(const unsigned short* __restrict__ t_t,
                                                        float* __restrict__ a0,
                                                        float* __restrict__ a1) {
    __shared__ __align__(16) unsigned short Vt[16][264];
    int wi = blockIdx.x, head = blockIdx.y;
    int z = blockIdx.z;
    int b = z >> 1, which = z & 1;
    int qoff = which ? 384 : 0;
    int koff = which ? 512 : 128;
    int mode = which;
    float* a_out = which ? a1 : a0;
    int tx = threadIdx.x;
    int wave = tx >> 6, l = tx & 63;
    int l32 = l & 31, half = l >> 5;
    const size_t base = (size_t)b * NPIX;
    const int hc = head * 16;

    {
        int p = tok2pix(mode, wi, tx);
        const unsigned short* vp = &t_t[(base + p) * 640 + 256 + hc];
        unsigned short tmp[16];
        *(uint4*)&tmp[0] = *(const uint4*)vp;
        *(uint4*)&tmp[8] = *(const uint4*)(vp + 8);
#pragma unroll
        for (int d = 0; d < 16; ++d) Vt[d][tx] = tmp[d];
    }
    __syncthreads();

    f32x16 zzero;
#pragma unroll
    for (int r = 0; r < 16; ++r) zzero[r] = 0.f;
    short8 vones, vzero;
#pragma unroll
    for (int r = 0; r < 8; ++r) { vones[r] = (short)0x3F80; vzero[r] = 0; }

    for (int qi = 0; qi < 2; ++qi) {
        int qs = qi * 4 + wave;
        int qp = tok2pix(mode, wi, qs * 32 + l32);
        short8 qf = *(const short8*)&t_t[(base + qp) * 640 + qoff + hc + half * 8];
        f32x16 o_acc = zzero;
#pragma unroll
        for (int nt = 0; nt < 8; ++nt) {
            int kp = tok2pix(mode, wi, nt * 32 + l32);
            short8 kf = *(const short8*)&t_t[(base + kp) * 640 + koff + hc + half * 8];
            f32x16 s = __builtin_amdgcn_mfma_f32_32x32x16_bf16(kf, qf, zzero, 0, 0, 0);
            unsigned int pk[8];
#pragma unroll
            for (int i = 0; i < 8; ++i) {
                float e0 = exp2f(s[2 * i]);
                float e1 = exp2f(s[2 * i + 1]);
                pk[i] = __builtin_amdgcn_perm(__float_as_uint(e1), __float_as_uint(e0),
                                              0x07060302u);
            }
            unsigned int xpk[8];
#pragma unroll
            for (int i = 0; i < 8; ++i)
                xpk[i] = (unsigned int)__shfl_xor((int)pk[i], 32, 64);
            unsigned int u0[4], u1[4];
            if (half == 0) {
                u0[0] = pk[0]; u0[1] = pk[1]; u0[2] = xpk[0]; u0[3] = xpk[1];
                u1[0] = pk[4]; u1[1] = pk[5]; u1[2] = xpk[4]; u1[3] = xpk[5];
            } else {
                u0[0] = xpk[2]; u0[1] = xpk[3]; u0[2] = pk[2]; u0[3] = pk[3];
                u1[0] = xpk[6]; u1[1] = xpk[7]; u1[2] = pk[6]; u1[3] = pk[7];
            }
            short8 vf0, vf1;
            if (l32 < 16) {
                vf0 = *(const short8*)&Vt[l32][nt * 32 + half * 8];
                vf1 = *(const short8*)&Vt[l32][nt * 32 + 16 + half * 8];
            } else if (l32 == 16) {
                vf0 = vones; vf1 = vones;
            } else {
                vf0 = vzero; vf1 = vzero;
            }
            o_acc = __builtin_amdgcn_mfma_f32_32x32x16_bf16(vf0, *(short8*)u0, o_acc, 0, 0, 0);
            o_acc = __builtin_amdgcn_mfma_f32_32x32x16_bf16(vf1, *(short8*)u1, o_acc, 0, 0, 0);
        }
        // row 16 of PV output = sum_t P[t][col]  (half-0 lanes, r=8)
        float rs = o_acc[8];
        rs += __shfl_xor(rs, 32, 64);
        float rinv = 1.f / rs;
        // d = (r&3) + 8*(r>>2) + 4*half  ->  two contiguous float4 runs
        float* dst = a_out + (base + qp) * 128 + hc + 4 * half;
        float4 s0 = make_float4(o_acc[0] * rinv, o_acc[1] * rinv,
                                o_acc[2] * rinv, o_acc[3] * rinv);
        float4 s1 = make_float4(o_acc[4] * rinv, o_acc[5] * rinv,
                                o_acc[6] * rinv, o_acc[7] * rinv);
        *(float4*)dst = s0;
        *(float4*)(dst + 8) = s1;
    }
}

// ---------------- m_t = bf16((a0 + a1 + cpe(v0)) * act_res)  (all NHWC) ----------------
__global__ __launch_bounds__(256) void mul3_cpe_kernel(const float* __restrict__ a0,
                                                       const float* __restrict__ a1,
                                                       const unsigned short* __restrict__ act,
                                                       const unsigned short* __restrict__ t_t,
                                                       const float* __restrict__ wT,
                                                       const float* __restrict__ bsum,
                                                       unsigned short* __restrict__ dst) {
    int b = blockIdx.y;
    int tx = threadIdx.x;
    int cg = tx & 15, pp = tx >> 4;
    int p = blockIdx.x * 16 + pp;
    int xx = p & 63, yy = p >> 6;
    int c0 = cg * 8;
    float acc[8];
#pragma unroll
    for (int j = 0; j < 8; ++j) acc[j] = bsum[c0 + j];
#pragma unroll
    for (int dy = -1; dy <= 1; ++dy) {
        int y2 = yy + dy;
        if (y2 < 0 || y2 >= 64) continue;
#pragma unroll
        for (int dx = -1; dx <= 1; ++dx) {
            int x2 = xx + dx;
            if (x2 < 0 || x2 >= 64) continue;
            int pn = y2 * 64 + x2;
            unsigned short v[8];
            *(uint4*)v = *(const uint4*)&t_t[((size_t)b * NPIX + pn) * 640 + 256 + c0];
            const float* wr = wT + ((dy + 1) * 3 + dx + 1) * 128 + c0;
#pragma unroll
            for (int j = 0; j < 8; ++j) acc[j] += b2f(v[j]) * wr[j];
        }
    }
    size_t base = ((size_t)b * NPIX + p) * 128 + c0;
    float4 x0 = *(const float4*)&a0[base];
    float4 x1 = *(const float4*)&a0[base + 4];
    float4 y0 = *(const float4*)&a1[base];
    float4 y1 = *(const float4*)&a1[base + 4];
    unsigned short t[8];
    *(uint4*)t = *(const uint4*)&act[base];
    unsigned short r[8];
    r[0] = f2b((x0.x + y0.x + acc[0]) * b2f(t[0]));
    r[1] = f2b((x0.y + y0.y + acc[1]) * b2f(t[1]));
    r[2] = f2b((x0.z + y0.z + acc[2]) * b2f(t[2]));
    r[3] = f2b((x0.w + y0.w + acc[3]) * b2f(t[3]));
    r[4] = f2b((x1.x + y1.x + acc[4]) * b2f(t[4]));
    r[5] = f2b((x1.y + y1.y + acc[5]) * b2f(t[5]));
    r[6] = f2b((x1.z + y1.z + acc[6]) * b2f(t[6]));
    r[7] = f2b((x1.w + y1.w + acc[7]) * b2f(t[7]));
    *(uint4*)&dst[base] = *(uint4*)r;
}

extern "C" void kernel_launch(void* const* d_in, const int* in_sizes, int n_in,
                              void* d_out, int out_size, void* d_ws, size_t ws_size,
                              hipStream_t stream) {
    const float* x       = (const float*)d_in[0];
    const float* eca_w   = (const float*)d_in[1];
    const float* esa_al  = (const float*)d_in[2];
    const float* cpe1_w  = (const float*)d_in[3];  const float* cpe1_b = (const float*)d_in[4];
    const float* g1      = (const float*)d_in[5];  const float* b1     = (const float*)d_in[6];
    const float* actp_w  = (const float*)d_in[7];  const float* actp_b = (const float*)d_in[8];
    const float* inp_w   = (const float*)d_in[9];  const float* inp_b  = (const float*)d_in[10];
    const float* dwc_w   = (const float*)d_in[11]; const float* dwc_b  = (const float*)d_in[12];
    const float* qkv_w   = (const float*)d_in[13]; const float* qkv_b  = (const float*)d_in[14];
    const float* eaax_w  = (const float*)d_in[15]; const float* eaax_b = (const float*)d_in[16];
    const float* eaay_w  = (const float*)d_in[17]; const float* eaay_b = (const float*)d_in[18];
    const float* outp_w  = (const float*)d_in[19]; const float* outp_b = (const float*)d_in[20];
    const float* cpe2_w  = (const float*)d_in[21]; const float* cpe2_b = (const float*)d_in[22];
    const float* g2      = (const float*)d_in[23]; const float* b2     = (const float*)d_in[24];
    const float* mlp1_w  = (const float*)d_in[25]; const float* mlp1_b = (const float*)d_in[26];
    const float* mlp2_w  = (const float*)d_in[27]; const float* mlp2_b = (const float*)d_in[28];

    float* ws = (float*)d_ws;
    unsigned short* U = (unsigned short*)d_ws;
    const size_t E = (size_t)BATCH * CDIM * NPIX;  // 4,194,304

    float* y_nhwc  = ws;                // [0,E)  esa out; later a0
    float* a0      = ws;
    float* sc_nhwc = ws + E;            // [E,2E) shortcut (live to outp)
    unsigned short* act_t = U + 5 * E;  // [2.5E,3E)
    unsigned short* it_t  = U + 6 * E;  // [3E,3.5E)
    unsigned short* tin_t = U + 7 * E;  // [3.5E,4E)
    float* a1      = ws + 4 * E;        // [4E,5E)
    unsigned short* t_t   = U + 10 * E; // [5E,7.5E)
    unsigned short* m_t   = U + 15 * E; // [7.5E,8E)
    float* out_nhwc = ws + 8 * E;       // [8E,9E)
    float* out2    = ws + 2 * E;        // [2E,3E)  (act_t dead by then)
    unsigned short* hid_t = U + 10 * E; // [5E,7E)  (t_t dead after mul3_cpe)
    unsigned short* wpool = U + 20 * E; // 262144 bf16
    unsigned short* wq  = wpool;
    unsigned short* wm1 = wpool + 81920;
    unsigned short* wm2 = wpool + 147456;
    unsigned short* wai = wpool + 212992;   // actp rows 0-127, inp rows 128-255 (contiguous)
    unsigned short* wo  = wpool + 245760;
    float* fb     = ws + 10 * E + 131072;
    float* meanb  = fb;            // 1024
    float* gstats = fb + 2048;     // 2048: gn1 [0,1024), gn2 [1024,2048)
    float* qb_r   = fb + 4096;     // 640
    float* wsT    = fb + 4736;     // 1152
    float* bsum   = fb + 5888;     // 128
    float* cpe1T  = fb + 6016;     // 1152
    float* dwcT   = fb + 7168;     // 1152
    float* cpe2T  = fb + 8320;     // 1152
    float* abi    = fb + 9472;     // 256

    convert_w_kernel<<<1054, 256, 0, stream>>>(qkv_w, mlp1_w, mlp2_w, actp_w, inp_w, outp_w,
                                               qkv_b, eaax_w, eaax_b, eaay_w, eaay_b,
                                               cpe1_w, dwc_w, cpe2_w, actp_b, inp_b,
                                               wpool, qb_r, wsT, bsum, cpe1T, dwcT, cpe2T, abi,
                                               gstats);

    // 1) ECA + ESA (gate inline) with transpose -> y (f32 NHWC)
    mean_bc_kernel<<<BATCH * CDIM, 256, 0, stream>>>(x, meanb);
    esa_tr_kernel<<<dim3(64, BATCH), 256, 0, stream>>>(x, meanb, eca_w, esa_al, y_nhwc);
    // 2) shortcut = y + cpe1(y), fused GN1 stats
    cpe_f32_kernel<<<dim3(256, BATCH), 256, 0, stream>>>(y_nhwc, cpe1T, cpe1_b, sc_nhwc, gstats);
    // 3+4+5a) merged actp+inp conv with fused GN1 apply: sc_nhwc -> act_t (relu), it_t
    conv_mfma_kernel<<<dim3(64, 2, BATCH), 256, 0, stream>>>(nullptr, sc_nhwc, gstats, g1, b1,
                                                             wai, abi, nullptr, nullptr,
                                                             act_t, it_t, 128, 128, 2, 0);
    // 5b) tin = relu(dwc(it))
    dwc_bf16_kernel<<<dim3(256, BATCH), 256, 0, stream>>>(it_t, dwcT, dwc_b, tin_t);
    // 6) qkv -> t_t (bf16 NHWC, 640 grouped; q groups pre-scaled by log2e)
    conv_mfma_kernel<<<dim3(64, 5, BATCH), 256, 0, stream>>>(tin_t, nullptr, nullptr, nullptr,
                                                             nullptr, wq, qb_r, nullptr, nullptr,
                                                             t_t, nullptr, 128, 640, 0, 0);
    // 7) both attentions -> a0, a1
    attn_dual_kernel<<<dim3(16, 8, 2 * BATCH), 256, 0, stream>>>(t_t, a0, a1);
    // 8) m_t = bf16((a0+a1+cpe(v0))*act) ; out = outp(m) + shortcut -> out_nhwc
    mul3_cpe_kernel<<<dim3(256, BATCH), 256, 0, stream>>>(a0, a1, act_t, t_t, wsT, bsum, m_t);
    conv_mfma_kernel<<<dim3(64, 1, BATCH), 256, 0, stream>>>(m_t, nullptr, nullptr, nullptr,
                                                             nullptr, wo, outp_b, sc_nhwc,
                                                             out_nhwc, nullptr, nullptr,
                                                             128, 128, 0, 0);
    // 9) out2 = out + cpe2(out), fused GN2 stats
    cpe_f32_kernel<<<dim3(256, BATCH), 256, 0, stream>>>(out_nhwc, cpe2T, cpe2_b, out2,
                                                         gstats + 1024);
    // 10+11) mlp1 with fused GN2 apply -> hid_t ; mlp2 + out2 residual -> d_out (NCHW)
    conv_mfma_kernel<<<dim3(64, 4, BATCH), 256, 0, stream>>>(nullptr, out2, gstats + 1024, g2, b2,
                                                             wm1, mlp1_b, nullptr, nullptr,
                                                             hid_t, nullptr, 128, 512, 1, 0);
    conv_mfma_kernel<<<dim3(64, 1, BATCH), 256, 0, stream>>>(hid_t, nullptr, nullptr, nullptr,
                                                             nullptr, wm2, mlp2_b, out2,
                                                             (float*)d_out, nullptr, nullptr,
                                                             512, 128, 0, 1);
}